// Round 1
// baseline (493.565 us; speedup 1.0000x reference)
//
#include <hip/hip_runtime.h>
#include <math.h>

#define HW_ 9216
#define IH 96
#define IW 96
#define NB 2
#define ST (NB*HW_)   // 18432 pixels total

__device__ __forceinline__ float gelu_f(float v){
  return 0.5f*v*(1.0f+erff(v*0.70710678118654752440f));
}

// ---------------------------------------------------------------------------
// K1: NCHW -> NHWC transpose (x (B,192,HW) -> xcl (B,HW,192))
// ---------------------------------------------------------------------------
__global__ __launch_bounds__(256) void transpose_in_k(const float* __restrict__ x,
                                                      float* __restrict__ xcl){
  __shared__ float t[32][33];
  int b  = blockIdx.z;
  int c0 = blockIdx.y << 5;
  int p0 = blockIdx.x << 5;
  int tx = threadIdx.x & 31;
  int ty = threadIdx.x >> 5;   // 0..7
  const float* xb = x + (size_t)b*192*HW_;
  #pragma unroll
  for (int k=0;k<4;k++){
    int c = ty + k*8;
    t[c][tx] = xb[(size_t)(c0+c)*HW_ + p0 + tx];
  }
  __syncthreads();
  float* ob = xcl + (size_t)b*HW_*192;
  #pragma unroll
  for (int k=0;k<4;k++){
    int p = ty + k*8;
    ob[(size_t)(p0+p)*192 + c0 + tx] = t[tx][p];
  }
}

// ---------------------------------------------------------------------------
// K2: LayerNorm over 96 channels (1 wave per pixel). Optionally also copies the
// raw (pre-LN) row to `raw` (used to init the transformer residual stream xt).
// ---------------------------------------------------------------------------
__global__ __launch_bounds__(256) void ln_k(const float* __restrict__ in, int istride, int ioff,
                                            const float* __restrict__ gam, const float* __restrict__ bet,
                                            float* __restrict__ out, float* __restrict__ raw){
  int lane = threadIdx.x & 63;
  int wv   = threadIdx.x >> 6;
  int p    = (blockIdx.x << 2) + wv;
  const float* row = in + (size_t)p*istride + ioff;
  float v0 = row[lane];
  float v1 = (lane < 32) ? row[64+lane] : 0.0f;
  float s = v0 + v1;
  #pragma unroll
  for (int o=32;o;o>>=1) s += __shfl_xor(s,o);
  float mu = s * (1.0f/96.0f);
  float d0 = v0 - mu;
  float d1 = v1 - mu;
  float qv = d0*d0 + ((lane<32)? d1*d1 : 0.0f);
  #pragma unroll
  for (int o=32;o;o>>=1) qv += __shfl_xor(qv,o);
  float rstd = rsqrtf(qv*(1.0f/96.0f) + 1e-5f);
  float* orow = out + (size_t)p*96;
  orow[lane] = d0*rstd*gam[lane] + bet[lane];
  if (lane < 32) orow[64+lane] = d1*rstd*gam[64+lane] + bet[64+lane];
  if (raw){
    float* rrow = raw + (size_t)p*96;
    rrow[lane] = v0;
    if (lane < 32) rrow[64+lane] = v1;
  }
}

// ---------------------------------------------------------------------------
// K3: generic conv1x1 (pixel-major GEMM).  128 pixels x 32 couts per block.
// ACT: 0 none, 1 relu. PROD: input = in1*in2 elementwise (for b1*b2).
// CONCAT: Cin=192 = [in1 (96) | in2 (96)].  FINAL: channel-first out with
// residual from NCHW x (the last kernel).
// ---------------------------------------------------------------------------
template<int ACT, bool PROD, bool CONCAT, bool FINAL>
__global__ __launch_bounds__(256) void conv1x1_k(
    const float* __restrict__ in1, const float* __restrict__ in2, int istride,
    const float* __restrict__ w, const float* __restrict__ bias,
    const float* __restrict__ res, int rstride,
    float* __restrict__ out, int ostride,
    int Cin, int Cout)
{
  __shared__ float smem[128*97 + 32*96];
  float (*lin)[97] = (float(*)[97])smem;
  float (*lw)[96]  = (float(*)[96])(smem + 128*97);

  const int tid  = threadIdx.x;
  const int lane = tid & 63, wv = tid >> 6;
  const int p0   = blockIdx.x << 7;
  const int co0  = blockIdx.y << 5;

  float acc[2][8];
  #pragma unroll
  for (int j=0;j<2;j++)
    #pragma unroll
    for (int k=0;k<8;k++) acc[j][k]=0.0f;

  for (int kc = 0; kc < Cin; kc += 96){
    {
      const float* src = (CONCAT && kc) ? in2 : in1;
      const int strd = CONCAT ? 96 : istride;
      const int boff = CONCAT ? 0 : kc;
      #pragma unroll
      for (int it=0; it<12; ++it){
        int idx = (tid<<2) + (it<<10);
        int rrow = idx / 96, col = idx - rrow*96;
        float4 v = *(const float4*)(src + (size_t)(p0+rrow)*strd + boff + col);
        if (PROD){
          const float4 v2 = *(const float4*)(in2 + (size_t)(p0+rrow)*strd + boff + col);
          v.x*=v2.x; v.y*=v2.y; v.z*=v2.z; v.w*=v2.w;
        }
        lin[rrow][col]=v.x; lin[rrow][col+1]=v.y; lin[rrow][col+2]=v.z; lin[rrow][col+3]=v.w;
      }
      #pragma unroll
      for (int it=0; it<3; ++it){
        int idx = (tid<<2) + (it<<10);
        int rrow = idx / 96, col = idx - rrow*96;
        int co = co0 + rrow;
        float4 v = make_float4(0.f,0.f,0.f,0.f);
        if (co < Cout) v = *(const float4*)(w + (size_t)co*Cin + kc + col);
        *(float4*)&lw[rrow][col] = v;
      }
    }
    __syncthreads();
    #pragma unroll 2
    for (int c=0;c<96;c+=4){
      float a0x=lin[lane][c],    a0y=lin[lane][c+1],    a0z=lin[lane][c+2],    a0w=lin[lane][c+3];
      float a1x=lin[lane+64][c], a1y=lin[lane+64][c+1], a1z=lin[lane+64][c+2], a1w=lin[lane+64][c+3];
      #pragma unroll
      for (int k=0;k<8;k++){
        const float4 wv4 = *(const float4*)&lw[(wv<<3)+k][c];
        acc[0][k] += a0x*wv4.x + a0y*wv4.y + a0z*wv4.z + a0w*wv4.w;
        acc[1][k] += a1x*wv4.x + a1y*wv4.y + a1z*wv4.z + a1w*wv4.w;
      }
    }
    __syncthreads();
  }

  if (FINAL){
    // channel-first write: out[b,co,hw] = acc + bias[co] + x[b,co,hw]
    #pragma unroll
    for (int k=0;k<8;k++){
      int co = co0 + (wv<<3) + k;
      float bv = bias ? bias[co] : 0.0f;
      #pragma unroll
      for (int j=0;j<2;j++){
        int p = p0 + lane + (j<<6);
        int bb = p / HW_, hw = p - bb*HW_;
        size_t oi = ((size_t)bb*192 + co)*HW_ + hw;
        out[oi] = acc[j][k] + bv + res[oi];
      }
    }
    return;
  }

  // transpose through LDS, then coalesced channel-last row writes
  float (*lt)[33] = (float(*)[33])smem;
  #pragma unroll
  for (int k=0;k<8;k++){
    int col = (wv<<3)+k;
    lt[lane][col]    = acc[0][k];
    lt[lane+64][col] = acc[1][k];
  }
  __syncthreads();
  const int pix = tid >> 1, half = tid & 1;
  const int p = p0 + pix;
  #pragma unroll
  for (int m=0;m<4;m++){
    int col = (half<<4) + (m<<2);
    int co = co0 + col;
    if (co >= Cout) continue;
    float4 v = make_float4(lt[pix][col], lt[pix][col+1], lt[pix][col+2], lt[pix][col+3]);
    if (bias){ v.x += bias[co]; v.y += bias[co+1]; v.z += bias[co+2]; v.w += bias[co+3]; }
    if (ACT==1){
      v.x=fmaxf(v.x,0.f); v.y=fmaxf(v.y,0.f); v.z=fmaxf(v.z,0.f); v.w=fmaxf(v.w,0.f);
    }
    if (res){
      const float4 rv = *(const float4*)(res + (size_t)p*rstride + co);
      v.x+=rv.x; v.y+=rv.y; v.z+=rv.z; v.w+=rv.w;
    }
    *(float4*)(out + (size_t)p*ostride + co) = v;
  }
}

// ---------------------------------------------------------------------------
// K4: depthwise 3x3 (channel-last), optional bias + exact gelu
// ---------------------------------------------------------------------------
template<bool HASB, bool DOGELU>
__global__ __launch_bounds__(256) void dw3x3_k(const float* __restrict__ in, const float* __restrict__ w,
                                               const float* __restrict__ bias, float* __restrict__ out, int C){
  int t = blockIdx.x*256 + threadIdx.x;
  int cg = C >> 2;
  int p = t / cg;
  if (p >= ST) return;
  int c4 = (t - p*cg) << 2;
  int bb = p / HW_, hw = p - bb*HW_;
  int hy = hw / IW, wx = hw - hy*IW;
  float w0[9], w1[9], w2[9], w3[9];
  #pragma unroll
  for (int tp=0;tp<9;tp++){
    w0[tp]=w[(c4+0)*9+tp]; w1[tp]=w[(c4+1)*9+tp]; w2[tp]=w[(c4+2)*9+tp]; w3[tp]=w[(c4+3)*9+tp];
  }
  float ax=0.f, ay=0.f, az=0.f, aw=0.f;
  #pragma unroll
  for (int i=0;i<3;i++){
    int y = hy+i-1;
    if ((unsigned)y >= IH) continue;
    #pragma unroll
    for (int j=0;j<3;j++){
      int x2 = wx+j-1;
      if ((unsigned)x2 >= IW) continue;
      const float4 v = *(const float4*)(in + ((size_t)bb*HW_ + y*IW + x2)*C + c4);
      int tp=i*3+j;
      ax += v.x*w0[tp]; ay += v.y*w1[tp]; az += v.z*w2[tp]; aw += v.w*w3[tp];
    }
  }
  if (HASB){ ax+=bias[c4]; ay+=bias[c4+1]; az+=bias[c4+2]; aw+=bias[c4+3]; }
  if (DOGELU){ ax=gelu_f(ax); ay=gelu_f(ay); az=gelu_f(az); aw=gelu_f(aw); }
  *(float4*)(out + (size_t)p*C + c4) = make_float4(ax,ay,az,aw);
}

// ---------------------------------------------------------------------------
// K5: full 3x3 conv 16->16 for the adaconv "para" branch (weights in LDS)
// ---------------------------------------------------------------------------
__global__ __launch_bounds__(256) void p2conv_k(const float* __restrict__ in, const float* __restrict__ w,
                                                const float* __restrict__ bias, float* __restrict__ out){
  __shared__ float ws[2304];
  int tid = threadIdx.x;
  for (int i=tid;i<2304;i+=256) ws[i]=w[i];
  __syncthreads();
  int p = blockIdx.x*256 + tid;
  int bb = p / HW_, hw = p - bb*HW_;
  int hy = hw / IW, wx = hw - hy*IW;
  float acc[16];
  #pragma unroll
  for (int co=0;co<16;co++) acc[co]=bias[co];
  #pragma unroll
  for (int i=0;i<3;i++){
    int y=hy+i-1; if ((unsigned)y>=IH) continue;
    #pragma unroll
    for (int j=0;j<3;j++){
      int x2=wx+j-1; if ((unsigned)x2>=IW) continue;
      int tap=i*3+j;
      const float* prow = in + ((size_t)bb*HW_ + y*IW + x2)*16;
      #pragma unroll
      for (int ci=0;ci<16;ci++){
        float v = prow[ci];
        #pragma unroll
        for (int co=0;co<16;co++) acc[co] += ws[co*144 + ci*9 + tap]*v;
      }
    }
  }
  float* orow = out + (size_t)p*16;
  #pragma unroll
  for (int co=0;co<16;co++) orow[co]=acc[co];
}

// ---------------------------------------------------------------------------
// K6: adaconv main: per (b, g, 8x8 pixel tile).  t[o,r] = sum_d A[g,o,d,r]*xu[d,p];
// out[o] = gelu(sum_r t[o,r]*para[r,p]).  A rows read wave-uniform (s_loads).
// ---------------------------------------------------------------------------
__global__ __launch_bounds__(256) void adaconv_k(
    const float* __restrict__ x2, const float* __restrict__ para,
    const float* __restrict__ aw, float* __restrict__ outb2)
{
  __shared__ float xt_s[10][10][13];
  __shared__ float para_s[64][17];
  int b = blockIdx.z;
  int g = blockIdx.y;
  int tileid = blockIdx.x;
  int th = (tileid/12)*8, tw = (tileid%12)*8;
  int tid = threadIdx.x;
  for (int idx=tid; idx<1200; idx+=256){
    int cl = idx % 12; int r2 = idx/12; int xx = r2%10, yy=r2/10;
    int gy = th+yy-1, gx = tw+xx-1;
    float v = 0.f;
    if (gy>=0 && gy<IH && gx>=0 && gx<IW)
      v = x2[((size_t)b*HW_ + gy*IW + gx)*192 + g*12 + cl];
    xt_s[yy][xx][cl] = v;
  }
  for (int idx=tid; idx<1024; idx+=256){
    int r2 = idx & 15, pl = idx >> 4;
    int gy = th + (pl>>3), gx = tw + (pl&7);
    para_s[pl][r2] = para[((size_t)b*HW_ + gy*IW + gx)*16 + r2];
  }
  __syncthreads();
  int lane = tid&63, wv = tid>>6;
  int py = lane>>3, px = lane&7;
  size_t outbase = ((size_t)b*HW_ + (th+py)*IW + tw+px)*192 + g*12;
  #pragma unroll 1
  for (int cc=0; cc<3; cc++){
    int o = cc*4 + wv;
    int aoff = ((g*12 + o)*108)*16;
    aoff = __builtin_amdgcn_readfirstlane(aoff);
    const float* A = aw + aoff;
    float tr[16];
    #pragma unroll
    for (int r2=0;r2<16;r2++) tr[r2]=0.f;
    #pragma unroll 1
    for (int cl=0; cl<12; ++cl){
      #pragma unroll
      for (int tap=0; tap<9; ++tap){
        float xv = xt_s[py + tap/3][px + tap%3][cl];
        const float* ar = A + (cl*9+tap)*16;
        #pragma unroll
        for (int r2=0;r2<16;++r2) tr[r2] = fmaf(ar[r2], xv, tr[r2]);
      }
    }
    float oacc = 0.f;
    #pragma unroll
    for (int r2=0;r2<16;r2++) oacc += tr[r2]*para_s[lane][r2];
    outb2[outbase + o] = gelu_f(oacc);
  }
}

// ---------------------------------------------------------------------------
// K7: shifted-window attention, 1 wave per (window, head). Roll folded into
// the pixel index: gather and scatter both at ((hr+4)%96, (wr+4)%96).
// ---------------------------------------------------------------------------
__global__ __launch_bounds__(64) void attn_k(const float* __restrict__ qkv,
                                             const float* __restrict__ relpos,
                                             float* __restrict__ outa){
  __shared__ float k_s[2048];
  __shared__ float v_s[2048];
  __shared__ float rel_s[225];
  const int win = blockIdx.x, head = blockIdx.y, b = blockIdx.z;
  const int wi = win/12, wj = win%12;
  const int lane = threadIdx.x;
  for (int i=lane;i<225;i+=64) rel_s[i] = relpos[i*3+head];
  const int pi = lane>>3, pj = lane&7;
  const int hr = wi*8+pi, wr = wj*8+pj;
  const int sh = (hr+4)%96, sw = (wr+4)%96;
  const size_t pix = (size_t)b*HW_ + sh*96 + sw;
  const float* qrow = qkv + pix*288 + head*32;
  const float* krow = qkv + pix*288 + 96 + head*32;
  const float* vrow = qkv + pix*288 + 192 + head*32;
  const float SC = 0.17677669529663687f; // 1/sqrt(32)
  float q[32];
  #pragma unroll
  for (int i=0;i<32;i+=4){
    const float4 t4 = *(const float4*)(qrow+i);
    q[i]=t4.x*SC; q[i+1]=t4.y*SC; q[i+2]=t4.z*SC; q[i+3]=t4.w*SC;
  }
  #pragma unroll
  for (int i=0;i<32;i+=4){
    *(float4*)&k_s[(lane<<5)+i] = *(const float4*)(krow+i);
    *(float4*)&v_s[(lane<<5)+i] = *(const float4*)(vrow+i);
  }
  __syncthreads();
  const bool mi = (wi==11), mj = (wj==11);
  float sc[64];
  #pragma unroll
  for (int qq=0; qq<64; qq++){
    const float4* kr4 = (const float4*)&k_s[qq<<5];
    float s = 0.f;
    #pragma unroll
    for (int i=0;i<8;i++){
      const float4 kv = kr4[i];
      s += q[4*i]*kv.x + q[4*i+1]*kv.y + q[4*i+2]*kv.z + q[4*i+3]*kv.w;
    }
    const int qi = qq>>3, qj = qq&7;
    s += rel_s[(pi-qi+7)*15 + (pj-qj+7)];
    const bool msk = (mi && ((pi<4)!=(qi<4))) || (mj && ((pj<4)!=(qj<4)));
    sc[qq] = msk ? -1e30f : s;
  }
  float m = sc[0];
  #pragma unroll
  for (int qq=1;qq<64;qq++) m = fmaxf(m, sc[qq]);
  float sum = 0.f;
  #pragma unroll
  for (int qq=0;qq<64;qq++){ float e = __expf(sc[qq]-m); sc[qq]=e; sum+=e; }
  const float inv = 1.f/sum;
  float acc[32];
  #pragma unroll
  for (int i=0;i<32;i++) acc[i]=0.f;
  #pragma unroll
  for (int qq=0;qq<64;qq++){
    const float a = sc[qq]*inv;
    const float4* vr4 = (const float4*)&v_s[qq<<5];
    #pragma unroll
    for (int i=0;i<8;i++){
      const float4 vv = vr4[i];
      acc[4*i]+=a*vv.x; acc[4*i+1]+=a*vv.y; acc[4*i+2]+=a*vv.z; acc[4*i+3]+=a*vv.w;
    }
  }
  float* orow = outa + pix*96 + head*32;
  #pragma unroll
  for (int i=0;i<32;i+=4)
    *(float4*)(orow+i) = make_float4(acc[i],acc[i+1],acc[i+2],acc[i+3]);
}

// ---------------------------------------------------------------------------
extern "C" void kernel_launch(void* const* d_in, const int* in_sizes, int n_in,
                              void* d_out, int out_size, void* d_ws, size_t ws_size,
                              hipStream_t stream)
{
  (void)in_sizes; (void)n_in; (void)out_size; (void)ws_size;
  const float* x        = (const float*)d_in[0];
  const float* cb_ln_g  = (const float*)d_in[1];
  const float* cb_ln_b  = (const float*)d_in[2];
  const float* cb_c1_pw = (const float*)d_in[3];
  const float* cb_c1_dw = (const float*)d_in[4];
  const float* cb_c2_pw = (const float*)d_in[5];
  const float* ada_w    = (const float*)d_in[6];
  const float* ada_p1_w = (const float*)d_in[7];
  const float* ada_p1_b = (const float*)d_in[8];
  const float* ada_p2_w = (const float*)d_in[9];
  const float* ada_p2_b = (const float*)d_in[10];
  const float* cb_c3_w  = (const float*)d_in[11];
  const float* ln1_g    = (const float*)d_in[12];
  const float* ln1_b    = (const float*)d_in[13];
  const float* qkv_w    = (const float*)d_in[14];
  const float* qkv_b    = (const float*)d_in[15];
  const float* rel_pos  = (const float*)d_in[16];
  const float* proj_w   = (const float*)d_in[17];
  const float* proj_b   = (const float*)d_in[18];
  const float* ln2_g    = (const float*)d_in[19];
  const float* ln2_b    = (const float*)d_in[20];
  const float* ffn_w1   = (const float*)d_in[21];
  const float* ffn_b1   = (const float*)d_in[22];
  const float* ffn_dw   = (const float*)d_in[23];
  const float* ffn_db   = (const float*)d_in[24];
  const float* ffn_w2   = (const float*)d_in[25];
  const float* ffn_b2   = (const float*)d_in[26];
  const float* out_w    = (const float*)d_in[27];
  const float* out_b    = (const float*)d_in[28];

  float* ws = (float*)d_ws;
  const size_t C192S = (size_t)ST*192;
  const size_t C96S  = (size_t)ST*96;
  const size_t C16S  = (size_t)ST*16;
  float* xcl = ws;                 // (B,HW,192) input channel-last
  float* R1  = ws + C192S;         // x1 -> x2 -> (qkv lower) -> y1
  float* R2  = ws + 2*C192S;       // b1 -> (qkv upper) -> y2
  float* B2b = ws + 3*C192S;       // b2 (adaconv+gelu out)
  float* R4  = ws + 4*C192S;       // r -> convout (96 ch)
  float* XT  = R4 + C96S;          // transformer residual stream (96 ch)
  float* R6  = XT + C96S;          // ln outs / attn out (96 ch)
  float* PA1 = R6 + C96S;          // para1 (16 ch)
  float* PA2 = PA1 + C16S;         // para2 (16 ch)
  float* QKV = R1;                 // spans R1..R1+ST*288 (R1+part of R2)

  // conv branch
  transpose_in_k<<<dim3(HW_/32, 6, NB), 256, 0, stream>>>(x, xcl);
  ln_k<<<ST/4, 256, 0, stream>>>(xcl, 192, 0, cb_ln_g, cb_ln_b, R4, nullptr);
  conv1x1_k<0,false,false,false><<<dim3(ST/128, 6), 256, 0, stream>>>(R4, nullptr, 96, cb_c1_pw, nullptr, nullptr, 0, R1, 192, 96, 192);
  dw3x3_k<false,false><<<(ST*48)/256, 256, 0, stream>>>(R1, cb_c1_dw, nullptr, R2, 192);
  conv1x1_k<0,false,false,false><<<dim3(ST/128, 6), 256, 0, stream>>>(R4, nullptr, 96, cb_c2_pw, nullptr, nullptr, 0, R1, 192, 96, 192);
  conv1x1_k<1,false,false,false><<<dim3(ST/128, 1), 256, 0, stream>>>(R1, nullptr, 192, ada_p1_w, ada_p1_b, nullptr, 0, PA1, 16, 192, 16);
  p2conv_k<<<ST/256, 256, 0, stream>>>(PA1, ada_p2_w, ada_p2_b, PA2);
  adaconv_k<<<dim3(144, 16, NB), 256, 0, stream>>>(R1, PA2, ada_w, B2b);
  conv1x1_k<0,true,false,false><<<dim3(ST/128, 3), 256, 0, stream>>>(R2, B2b, 192, cb_c3_w, nullptr, xcl, 192, R4, 96, 192, 96);

  // transformer branch
  ln_k<<<ST/4, 256, 0, stream>>>(xcl, 192, 96, ln1_g, ln1_b, R6, XT);
  conv1x1_k<0,false,false,false><<<dim3(ST/128, 9), 256, 0, stream>>>(R6, nullptr, 96, qkv_w, qkv_b, nullptr, 0, QKV, 288, 96, 288);
  attn_k<<<dim3(144, 3, NB), 64, 0, stream>>>(QKV, rel_pos, R6);
  conv1x1_k<0,false,false,false><<<dim3(ST/128, 3), 256, 0, stream>>>(R6, nullptr, 96, proj_w, proj_b, XT, 96, XT, 96, 96, 96);
  ln_k<<<ST/4, 256, 0, stream>>>(XT, 96, 0, ln2_g, ln2_b, R6, nullptr);
  conv1x1_k<0,false,false,false><<<dim3(ST/128, 6), 256, 0, stream>>>(R6, nullptr, 96, ffn_w1, ffn_b1, nullptr, 0, R1, 192, 96, 192);
  dw3x3_k<true,true><<<(ST*48)/256, 256, 0, stream>>>(R1, ffn_dw, ffn_db, R2, 192);
  conv1x1_k<0,false,false,false><<<dim3(ST/128, 3), 256, 0, stream>>>(R2, nullptr, 192, ffn_w2, ffn_b2, XT, 96, XT, 96, 192, 96);

  // fuse: out = x + conv1x1(concat(convout, xt), out_w) + out_b  (channel-first)
  conv1x1_k<0,false,true,true><<<dim3(ST/128, 6), 256, 0, stream>>>(R4, XT, 96, out_w, out_b, x, 0, (float*)d_out, 0, 192, 192);
}

// Round 2
// 400.389 us; speedup vs baseline: 1.2327x; 1.2327x over previous
//
#include <hip/hip_runtime.h>
#include <math.h>

#define HW_ 9216
#define IH 96
#define IW 96
#define NB 2
#define ST (NB*HW_)   // 18432 pixels total

typedef __attribute__((ext_vector_type(8))) short bf16x8;
typedef __attribute__((ext_vector_type(4))) float f32x4;

__device__ __forceinline__ float gelu_f(float v){
  return 0.5f*v*(1.0f+erff(v*0.70710678118654752440f));
}

__device__ __forceinline__ unsigned short f2bf(float f){
  unsigned u = __float_as_uint(f);
  unsigned r = (u + 0x7FFF + ((u>>16)&1)) >> 16;
  return (unsigned short)r;
}

// ---------------------------------------------------------------------------
// K1: NCHW -> NHWC transpose (x (B,192,HW) -> xcl (B,HW,192))
// ---------------------------------------------------------------------------
__global__ __launch_bounds__(256) void transpose_in_k(const float* __restrict__ x,
                                                      float* __restrict__ xcl){
  __shared__ float t[32][33];
  int b  = blockIdx.z;
  int c0 = blockIdx.y << 5;
  int p0 = blockIdx.x << 5;
  int tx = threadIdx.x & 31;
  int ty = threadIdx.x >> 5;   // 0..7
  const float* xb = x + (size_t)b*192*HW_;
  #pragma unroll
  for (int k=0;k<4;k++){
    int c = ty + k*8;
    t[c][tx] = xb[(size_t)(c0+c)*HW_ + p0 + tx];
  }
  __syncthreads();
  float* ob = xcl + (size_t)b*HW_*192;
  #pragma unroll
  for (int k=0;k<4;k++){
    int p = ty + k*8;
    ob[(size_t)(p0+p)*192 + c0 + tx] = t[tx][p];
  }
}

// ---------------------------------------------------------------------------
// K2: LayerNorm over 96 channels (1 wave per pixel).
// ---------------------------------------------------------------------------
__global__ __launch_bounds__(256) void ln_k(const float* __restrict__ in, int istride, int ioff,
                                            const float* __restrict__ gam, const float* __restrict__ bet,
                                            float* __restrict__ out, float* __restrict__ raw){
  int lane = threadIdx.x & 63;
  int wv   = threadIdx.x >> 6;
  int p    = (blockIdx.x << 2) + wv;
  const float* row = in + (size_t)p*istride + ioff;
  float v0 = row[lane];
  float v1 = (lane < 32) ? row[64+lane] : 0.0f;
  float s = v0 + v1;
  #pragma unroll
  for (int o=32;o;o>>=1) s += __shfl_xor(s,o);
  float mu = s * (1.0f/96.0f);
  float d0 = v0 - mu;
  float d1 = v1 - mu;
  float qv = d0*d0 + ((lane<32)? d1*d1 : 0.0f);
  #pragma unroll
  for (int o=32;o;o>>=1) qv += __shfl_xor(qv,o);
  float rstd = rsqrtf(qv*(1.0f/96.0f) + 1e-5f);
  float* orow = out + (size_t)p*96;
  orow[lane] = d0*rstd*gam[lane] + bet[lane];
  if (lane < 32) orow[64+lane] = d1*rstd*gam[64+lane] + bet[64+lane];
  if (raw){
    float* rrow = raw + (size_t)p*96;
    rrow[lane] = v0;
    if (lane < 32) rrow[64+lane] = v1;
  }
}

// ---------------------------------------------------------------------------
// K3: generic conv1x1 (pixel-major GEMM), fp32 VALU.
// ---------------------------------------------------------------------------
template<int ACT, bool PROD, bool CONCAT, bool FINAL>
__global__ __launch_bounds__(256) void conv1x1_k(
    const float* __restrict__ in1, const float* __restrict__ in2, int istride,
    const float* __restrict__ w, const float* __restrict__ bias,
    const float* __restrict__ res, int rstride,
    float* __restrict__ out, int ostride,
    int Cin, int Cout)
{
  __shared__ float smem[128*97 + 32*96];
  float (*lin)[97] = (float(*)[97])smem;
  float (*lw)[96]  = (float(*)[96])(smem + 128*97);

  const int tid  = threadIdx.x;
  const int lane = tid & 63, wv = tid >> 6;
  const int p0   = blockIdx.x << 7;
  const int co0  = blockIdx.y << 5;

  float acc[2][8];
  #pragma unroll
  for (int j=0;j<2;j++)
    #pragma unroll
    for (int k=0;k<8;k++) acc[j][k]=0.0f;

  for (int kc = 0; kc < Cin; kc += 96){
    {
      const float* src = (CONCAT && kc) ? in2 : in1;
      const int strd = CONCAT ? 96 : istride;
      const int boff = CONCAT ? 0 : kc;
      #pragma unroll
      for (int it=0; it<12; ++it){
        int idx = (tid<<2) + (it<<10);
        int rrow = idx / 96, col = idx - rrow*96;
        float4 v = *(const float4*)(src + (size_t)(p0+rrow)*strd + boff + col);
        if (PROD){
          const float4 v2 = *(const float4*)(in2 + (size_t)(p0+rrow)*strd + boff + col);
          v.x*=v2.x; v.y*=v2.y; v.z*=v2.z; v.w*=v2.w;
        }
        lin[rrow][col]=v.x; lin[rrow][col+1]=v.y; lin[rrow][col+2]=v.z; lin[rrow][col+3]=v.w;
      }
      #pragma unroll
      for (int it=0; it<3; ++it){
        int idx = (tid<<2) + (it<<10);
        int rrow = idx / 96, col = idx - rrow*96;
        int co = co0 + rrow;
        float4 v = make_float4(0.f,0.f,0.f,0.f);
        if (co < Cout) v = *(const float4*)(w + (size_t)co*Cin + kc + col);
        *(float4*)&lw[rrow][col] = v;
      }
    }
    __syncthreads();
    #pragma unroll 2
    for (int c=0;c<96;c+=4){
      float a0x=lin[lane][c],    a0y=lin[lane][c+1],    a0z=lin[lane][c+2],    a0w=lin[lane][c+3];
      float a1x=lin[lane+64][c], a1y=lin[lane+64][c+1], a1z=lin[lane+64][c+2], a1w=lin[lane+64][c+3];
      #pragma unroll
      for (int k=0;k<8;k++){
        const float4 wv4 = *(const float4*)&lw[(wv<<3)+k][c];
        acc[0][k] += a0x*wv4.x + a0y*wv4.y + a0z*wv4.z + a0w*wv4.w;
        acc[1][k] += a1x*wv4.x + a1y*wv4.y + a1z*wv4.z + a1w*wv4.w;
      }
    }
    __syncthreads();
  }

  if (FINAL){
    #pragma unroll
    for (int k=0;k<8;k++){
      int co = co0 + (wv<<3) + k;
      float bv = bias ? bias[co] : 0.0f;
      #pragma unroll
      for (int j=0;j<2;j++){
        int p = p0 + lane + (j<<6);
        int bb = p / HW_, hw = p - bb*HW_;
        size_t oi = ((size_t)bb*192 + co)*HW_ + hw;
        out[oi] = acc[j][k] + bv + res[oi];
      }
    }
    return;
  }

  float (*lt)[33] = (float(*)[33])smem;
  #pragma unroll
  for (int k=0;k<8;k++){
    int col = (wv<<3)+k;
    lt[lane][col]    = acc[0][k];
    lt[lane+64][col] = acc[1][k];
  }
  __syncthreads();
  const int pix = tid >> 1, half = tid & 1;
  const int p = p0 + pix;
  #pragma unroll
  for (int m=0;m<4;m++){
    int col = (half<<4) + (m<<2);
    int co = co0 + col;
    if (co >= Cout) continue;
    float4 v = make_float4(lt[pix][col], lt[pix][col+1], lt[pix][col+2], lt[pix][col+3]);
    if (bias){ v.x += bias[co]; v.y += bias[co+1]; v.z += bias[co+2]; v.w += bias[co+3]; }
    if (ACT==1){
      v.x=fmaxf(v.x,0.f); v.y=fmaxf(v.y,0.f); v.z=fmaxf(v.z,0.f); v.w=fmaxf(v.w,0.f);
    }
    if (res){
      const float4 rv = *(const float4*)(res + (size_t)p*rstride + co);
      v.x+=rv.x; v.y+=rv.y; v.z+=rv.z; v.w+=rv.w;
    }
    *(float4*)(out + (size_t)p*ostride + co) = v;
  }
}

// ---------------------------------------------------------------------------
// K4: depthwise 3x3 (channel-last), optional bias + exact gelu
// ---------------------------------------------------------------------------
template<bool HASB, bool DOGELU>
__global__ __launch_bounds__(256) void dw3x3_k(const float* __restrict__ in, const float* __restrict__ w,
                                               const float* __restrict__ bias, float* __restrict__ out, int C){
  int t = blockIdx.x*256 + threadIdx.x;
  int cg = C >> 2;
  int p = t / cg;
  if (p >= ST) return;
  int c4 = (t - p*cg) << 2;
  int bb = p / HW_, hw = p - bb*HW_;
  int hy = hw / IW, wx = hw - hy*IW;
  float w0[9], w1[9], w2[9], w3[9];
  #pragma unroll
  for (int tp=0;tp<9;tp++){
    w0[tp]=w[(c4+0)*9+tp]; w1[tp]=w[(c4+1)*9+tp]; w2[tp]=w[(c4+2)*9+tp]; w3[tp]=w[(c4+3)*9+tp];
  }
  float ax=0.f, ay=0.f, az=0.f, aw=0.f;
  #pragma unroll
  for (int i=0;i<3;i++){
    int y = hy+i-1;
    if ((unsigned)y >= IH) continue;
    #pragma unroll
    for (int j=0;j<3;j++){
      int x2 = wx+j-1;
      if ((unsigned)x2 >= IW) continue;
      const float4 v = *(const float4*)(in + ((size_t)bb*HW_ + y*IW + x2)*C + c4);
      int tp=i*3+j;
      ax += v.x*w0[tp]; ay += v.y*w1[tp]; az += v.z*w2[tp]; aw += v.w*w3[tp];
    }
  }
  if (HASB){ ax+=bias[c4]; ay+=bias[c4+1]; az+=bias[c4+2]; aw+=bias[c4+3]; }
  if (DOGELU){ ax=gelu_f(ax); ay=gelu_f(ay); az=gelu_f(az); aw=gelu_f(aw); }
  *(float4*)(out + (size_t)p*C + c4) = make_float4(ax,ay,az,aw);
}

// ---------------------------------------------------------------------------
// K5: full 3x3 conv 16->16 for the adaconv "para" branch (weights in LDS)
// ---------------------------------------------------------------------------
__global__ __launch_bounds__(256) void p2conv_k(const float* __restrict__ in, const float* __restrict__ w,
                                                const float* __restrict__ bias, float* __restrict__ out){
  __shared__ float ws[2304];
  int tid = threadIdx.x;
  for (int i=tid;i<2304;i+=256) ws[i]=w[i];
  __syncthreads();
  int p = blockIdx.x*256 + tid;
  int bb = p / HW_, hw = p - bb*HW_;
  int hy = hw / IW, wx = hw - hy*IW;
  float acc[16];
  #pragma unroll
  for (int co=0;co<16;co++) acc[co]=bias[co];
  #pragma unroll
  for (int i=0;i<3;i++){
    int y=hy+i-1; if ((unsigned)y>=IH) continue;
    #pragma unroll
    for (int j=0;j<3;j++){
      int x2=wx+j-1; if ((unsigned)x2>=IW) continue;
      int tap=i*3+j;
      const float* prow = in + ((size_t)bb*HW_ + y*IW + x2)*16;
      #pragma unroll
      for (int ci=0;ci<16;ci++){
        float v = prow[ci];
        #pragma unroll
        for (int co=0;co<16;co++) acc[co] += ws[co*144 + ci*9 + tap]*v;
      }
    }
  }
  float* orow = out + (size_t)p*16;
  #pragma unroll
  for (int co=0;co<16;co++) orow[co]=acc[co];
}

// ---------------------------------------------------------------------------
// K6a: prep ada_w -> bf16 Amat[g][row=o*16+r][k=d padded to 128], row-major.
// ---------------------------------------------------------------------------
__global__ __launch_bounds__(256) void ada_prep_k(const float* __restrict__ aw,
                                                  unsigned short* __restrict__ apre){
  int g = blockIdx.y;
  int e = blockIdx.x*256 + threadIdx.x;    // 0..24575
  int row = e >> 7, k = e & 127;
  int o = row >> 4, r = row & 15;
  float v = (k < 108) ? aw[(((size_t)(g*12+o)*108)+k)*16 + r] : 0.f;
  apre[(size_t)g*24576 + e] = f2bf(v);
}

// ---------------------------------------------------------------------------
// K6b: adaconv via MFMA. Per block: one (b, g, 8x8 px tile).
// Step1 GEMM (bf16 MFMA): t[(o,r),p] = sum_d A[(o,r),d] * xu[d,p], K padded 128.
// Step2 (fp32 epilogue): out[o,p] = gelu(sum_r t[(o,r),p] * para[r,p]).
// LDS XOR-swizzle (slot ^= row&7) on A and XU for conflict-free ds_read_b128.
// ---------------------------------------------------------------------------
__global__ __launch_bounds__(256) void adaconv_mfma_k(
    const float* __restrict__ x2, const float* __restrict__ para,
    const unsigned short* __restrict__ apre, float* __restrict__ outb2)
{
  __shared__ __align__(16) unsigned char smem[75456];
  unsigned char* A_l = smem;                    // [192][128] bf16 swizzled, 49152 B
  unsigned char* XU  = smem + 49152;            // [64][128] bf16 swizzled,  16384 B
  float* xs = (float*)(smem + 65536);           // [10][10][12] f32, 4800 B
  float* ps = (float*)(smem + 70336);           // [64][20] f32 (stride 20), 5120 B

  const int tid = threadIdx.x;
  const int b = blockIdx.z, g = blockIdx.y, tile = blockIdx.x;
  const int th = (tile/12)<<3, tw = (tile%12)<<3;

  // --- stage A (48 KB, L2-resident) into swizzled LDS ---
  const uint4* ag = (const uint4*)(apre + (size_t)g*24576);
  #pragma unroll
  for (int it=0; it<12; ++it){
    int idx = tid + (it<<8);          // 0..3071 slots
    int row = idx >> 4, sl = idx & 15;
    uint4 v = ag[idx];
    *(uint4*)(A_l + row*256 + ((sl ^ (row&7))<<4)) = v;
  }
  // --- stage x halo tile (10x10 px, 12 ch) fp32 ---
  for (int idx = tid; idx < 300; idx += 256){
    int hp = idx/3, q = idx - hp*3;
    int yy = hp/10, xx = hp - yy*10;
    int gy = th + yy - 1, gx = tw + xx - 1;
    float4 v = make_float4(0.f,0.f,0.f,0.f);
    if ((unsigned)gy < IH && (unsigned)gx < IW)
      v = *(const float4*)(x2 + ((size_t)b*HW_ + gy*IW + gx)*192 + g*12 + q*4);
    *(float4*)&xs[(yy*10+xx)*12 + q*4] = v;
  }
  // --- stage para tile (64 px x 16 r) fp32, stride 20 ---
  {
    int p = tid >> 2, q = tid & 3;
    int gy = th + (p>>3), gx = tw + (p&7);
    float4 v = *(const float4*)(para + ((size_t)b*HW_ + gy*IW + gx)*16 + q*4);
    *(float4*)&ps[p*20 + q*4] = v;
  }
  __syncthreads();
  // --- build XU[p][k] bf16 (k = cl*9+tap, zero-padded >=108), swizzled ---
  #pragma unroll
  for (int it=0; it<4; ++it){
    int task = tid + (it<<8);          // 0..1023 (64 px x 16 slots)
    int p = task >> 4, sl = task & 15;
    int py = p >> 3, px = p & 7;
    unsigned short h[8];
    #pragma unroll
    for (int dd=0; dd<8; ++dd){
      int d = (sl<<3) + dd;
      float v = 0.f;
      if (d < 108){
        int cl = d / 9, tap = d - cl*9;
        int ti = tap/3, tj = tap - ti*3;
        v = xs[((py+ti)*10 + (px+tj))*12 + cl];
      }
      h[dd] = f2bf(v);
    }
    uint4 pk;
    pk.x = (unsigned)h[0] | ((unsigned)h[1]<<16);
    pk.y = (unsigned)h[2] | ((unsigned)h[3]<<16);
    pk.z = (unsigned)h[4] | ((unsigned)h[5]<<16);
    pk.w = (unsigned)h[6] | ((unsigned)h[7]<<16);
    *(uint4*)(XU + p*256 + ((sl ^ (p&7))<<4)) = pk;
  }
  __syncthreads();

  // --- MFMA main loop: wave wv owns M-tiles o = 3wv..3wv+2 ---
  const int lane = tid & 63, wv = tid >> 6;
  const int lr = lane & 15, g4 = lane >> 4;
  f32x4 acc[3][4];
  #pragma unroll
  for (int oo=0;oo<3;oo++)
    #pragma unroll
    for (int n=0;n<4;n++) acc[oo][n] = (f32x4){0.f,0.f,0.f,0.f};

  #pragma unroll
  for (int ks=0; ks<4; ++ks){
    const int sl = (ks<<2) + g4;
    bf16x8 af[3], bfr[4];
    #pragma unroll
    for (int oo=0;oo<3;oo++){
      int row = (wv*3+oo)*16 + lr;
      af[oo] = *(const bf16x8*)(A_l + row*256 + ((sl ^ (row&7))<<4));
    }
    #pragma unroll
    for (int n=0;n<4;n++){
      int p = (n<<4) + lr;
      bfr[n] = *(const bf16x8*)(XU + p*256 + ((sl ^ (p&7))<<4));
    }
    #pragma unroll
    for (int oo=0;oo<3;oo++)
      #pragma unroll
      for (int n=0;n<4;n++)
        acc[oo][n] = __builtin_amdgcn_mfma_f32_16x16x32_bf16(af[oo], bfr[n], acc[oo][n], 0,0,0);
  }

  // --- step2 epilogue: r-reduction with para, gelu, scatter write ---
  #pragma unroll
  for (int oo=0;oo<3;oo++){
    const int o = wv*3 + oo;
    #pragma unroll
    for (int n=0;n<4;n++){
      const int p = (n<<4) + lr;
      const float* pr = &ps[p*20 + (g4<<2)];
      float s = acc[oo][n].x*pr[0] + acc[oo][n].y*pr[1]
              + acc[oo][n].z*pr[2] + acc[oo][n].w*pr[3];
      s += __shfl_xor(s, 16);
      s += __shfl_xor(s, 32);
      if (g4 == ((oo*4+n)&3)){
        int py = p>>3, px = p&7;
        outb2[((size_t)b*HW_ + (th+py)*IW + (tw+px))*192 + g*12 + o] = gelu_f(s);
      }
    }
  }
}

// ---------------------------------------------------------------------------
// K7: shifted-window attention, 1 wave per (window, head).
// ---------------------------------------------------------------------------
__global__ __launch_bounds__(64) void attn_k(const float* __restrict__ qkv,
                                             const float* __restrict__ relpos,
                                             float* __restrict__ outa){
  __shared__ float k_s[2048];
  __shared__ float v_s[2048];
  __shared__ float rel_s[225];
  const int win = blockIdx.x, head = blockIdx.y, b = blockIdx.z;
  const int wi = win/12, wj = win%12;
  const int lane = threadIdx.x;
  for (int i=lane;i<225;i+=64) rel_s[i] = relpos[i*3+head];
  const int pi = lane>>3, pj = lane&7;
  const int hr = wi*8+pi, wr = wj*8+pj;
  const int sh = (hr+4)%96, sw = (wr+4)%96;
  const size_t pix = (size_t)b*HW_ + sh*96 + sw;
  const float* qrow = qkv + pix*288 + head*32;
  const float* krow = qkv + pix*288 + 96 + head*32;
  const float* vrow = qkv + pix*288 + 192 + head*32;
  const float SC = 0.17677669529663687f; // 1/sqrt(32)
  float q[32];
  #pragma unroll
  for (int i=0;i<32;i+=4){
    const float4 t4 = *(const float4*)(qrow+i);
    q[i]=t4.x*SC; q[i+1]=t4.y*SC; q[i+2]=t4.z*SC; q[i+3]=t4.w*SC;
  }
  #pragma unroll
  for (int i=0;i<32;i+=4){
    *(float4*)&k_s[(lane<<5)+i] = *(const float4*)(krow+i);
    *(float4*)&v_s[(lane<<5)+i] = *(const float4*)(vrow+i);
  }
  __syncthreads();
  const bool mi = (wi==11), mj = (wj==11);
  float sc[64];
  #pragma unroll
  for (int qq=0; qq<64; qq++){
    const float4* kr4 = (const float4*)&k_s[qq<<5];
    float s = 0.f;
    #pragma unroll
    for (int i=0;i<8;i++){
      const float4 kv = kr4[i];
      s += q[4*i]*kv.x + q[4*i+1]*kv.y + q[4*i+2]*kv.z + q[4*i+3]*kv.w;
    }
    const int qi = qq>>3, qj = qq&7;
    s += rel_s[(pi-qi+7)*15 + (pj-qj+7)];
    const bool msk = (mi && ((pi<4)!=(qi<4))) || (mj && ((pj<4)!=(qj<4)));
    sc[qq] = msk ? -1e30f : s;
  }
  float m = sc[0];
  #pragma unroll
  for (int qq=1;qq<64;qq++) m = fmaxf(m, sc[qq]);
  float sum = 0.f;
  #pragma unroll
  for (int qq=0;qq<64;qq++){ float e = __expf(sc[qq]-m); sc[qq]=e; sum+=e; }
  const float inv = 1.f/sum;
  float acc[32];
  #pragma unroll
  for (int i=0;i<32;i++) acc[i]=0.f;
  #pragma unroll
  for (int qq=0;qq<64;qq++){
    const float a = sc[qq]*inv;
    const float4* vr4 = (const float4*)&v_s[qq<<5];
    #pragma unroll
    for (int i=0;i<8;i++){
      const float4 vv = vr4[i];
      acc[4*i]+=a*vv.x; acc[4*i+1]+=a*vv.y; acc[4*i+2]+=a*vv.z; acc[4*i+3]+=a*vv.w;
    }
  }
  float* orow = outa + pix*96 + head*32;
  #pragma unroll
  for (int i=0;i<32;i+=4)
    *(float4*)(orow+i) = make_float4(acc[i],acc[i+1],acc[i+2],acc[i+3]);
}

// ---------------------------------------------------------------------------
extern "C" void kernel_launch(void* const* d_in, const int* in_sizes, int n_in,
                              void* d_out, int out_size, void* d_ws, size_t ws_size,
                              hipStream_t stream)
{
  (void)in_sizes; (void)n_in; (void)out_size; (void)ws_size;
  const float* x        = (const float*)d_in[0];
  const float* cb_ln_g  = (const float*)d_in[1];
  const float* cb_ln_b  = (const float*)d_in[2];
  const float* cb_c1_pw = (const float*)d_in[3];
  const float* cb_c1_dw = (const float*)d_in[4];
  const float* cb_c2_pw = (const float*)d_in[5];
  const float* ada_w    = (const float*)d_in[6];
  const float* ada_p1_w = (const float*)d_in[7];
  const float* ada_p1_b = (const float*)d_in[8];
  const float* ada_p2_w = (const float*)d_in[9];
  const float* ada_p2_b = (const float*)d_in[10];
  const float* cb_c3_w  = (const float*)d_in[11];
  const float* ln1_g    = (const float*)d_in[12];
  const float* ln1_b    = (const float*)d_in[13];
  const float* qkv_w    = (const float*)d_in[14];
  const float* qkv_b    = (const float*)d_in[15];
  const float* rel_pos  = (const float*)d_in[16];
  const float* proj_w   = (const float*)d_in[17];
  const float* proj_b   = (const float*)d_in[18];
  const float* ln2_g    = (const float*)d_in[19];
  const float* ln2_b    = (const float*)d_in[20];
  const float* ffn_w1   = (const float*)d_in[21];
  const float* ffn_b1   = (const float*)d_in[22];
  const float* ffn_dw   = (const float*)d_in[23];
  const float* ffn_db   = (const float*)d_in[24];
  const float* ffn_w2   = (const float*)d_in[25];
  const float* ffn_b2   = (const float*)d_in[26];
  const float* out_w    = (const float*)d_in[27];
  const float* out_b    = (const float*)d_in[28];

  float* ws = (float*)d_ws;
  const size_t C192S = (size_t)ST*192;
  const size_t C96S  = (size_t)ST*96;
  const size_t C16S  = (size_t)ST*16;
  float* xcl = ws;                 // (B,HW,192) input channel-last
  float* R1  = ws + C192S;         // x1 -> x2 -> (qkv lower) -> y1
  float* R2  = ws + 2*C192S;       // b1 -> (qkv upper) -> y2
  float* B2b = ws + 3*C192S;       // b2 (adaconv+gelu out)
  float* R4  = ws + 4*C192S;       // r -> convout (96 ch)
  float* XT  = R4 + C96S;          // transformer residual stream (96 ch)
  float* R6  = XT + C96S;          // Apre (bf16) then ln outs / attn out
  float* PA1 = R6 + C96S;          // para1 (16 ch)
  float* PA2 = PA1 + C16S;         // para2 (16 ch)
  float* QKV = R1;                 // spans R1..R1+ST*288
  unsigned short* Apre = (unsigned short*)R6;  // 786 KB, freed before ln1 writes R6

  // adaconv weight prep (bf16, padded K=128)
  ada_prep_k<<<dim3(96, 16), 256, 0, stream>>>(ada_w, Apre);

  // conv branch
  transpose_in_k<<<dim3(HW_/32, 6, NB), 256, 0, stream>>>(x, xcl);
  ln_k<<<ST/4, 256, 0, stream>>>(xcl, 192, 0, cb_ln_g, cb_ln_b, R4, nullptr);
  conv1x1_k<0,false,false,false><<<dim3(ST/128, 6), 256, 0, stream>>>(R4, nullptr, 96, cb_c1_pw, nullptr, nullptr, 0, R1, 192, 96, 192);
  dw3x3_k<false,false><<<(ST*48)/256, 256, 0, stream>>>(R1, cb_c1_dw, nullptr, R2, 192);
  conv1x1_k<0,false,false,false><<<dim3(ST/128, 6), 256, 0, stream>>>(R4, nullptr, 96, cb_c2_pw, nullptr, nullptr, 0, R1, 192, 96, 192);
  conv1x1_k<1,false,false,false><<<dim3(ST/128, 1), 256, 0, stream>>>(R1, nullptr, 192, ada_p1_w, ada_p1_b, nullptr, 0, PA1, 16, 192, 16);
  p2conv_k<<<ST/256, 256, 0, stream>>>(PA1, ada_p2_w, ada_p2_b, PA2);
  adaconv_mfma_k<<<dim3(144, 16, NB), 256, 0, stream>>>(R1, PA2, Apre, B2b);
  conv1x1_k<0,true,false,false><<<dim3(ST/128, 3), 256, 0, stream>>>(R2, B2b, 192, cb_c3_w, nullptr, xcl, 192, R4, 96, 192, 96);

  // transformer branch
  ln_k<<<ST/4, 256, 0, stream>>>(xcl, 192, 96, ln1_g, ln1_b, R6, XT);
  conv1x1_k<0,false,false,false><<<dim3(ST/128, 9), 256, 0, stream>>>(R6, nullptr, 96, qkv_w, qkv_b, nullptr, 0, QKV, 288, 96, 288);
  attn_k<<<dim3(144, 3, NB), 64, 0, stream>>>(QKV, rel_pos, R6);
  conv1x1_k<0,false,false,false><<<dim3(ST/128, 3), 256, 0, stream>>>(R6, nullptr, 96, proj_w, proj_b, XT, 96, XT, 96, 96, 96);
  ln_k<<<ST/4, 256, 0, stream>>>(XT, 96, 0, ln2_g, ln2_b, R6, nullptr);
  conv1x1_k<0,false,false,false><<<dim3(ST/128, 6), 256, 0, stream>>>(R6, nullptr, 96, ffn_w1, ffn_b1, nullptr, 0, R1, 192, 96, 192);
  dw3x3_k<true,true><<<(ST*48)/256, 256, 0, stream>>>(R1, ffn_dw, ffn_db, R2, 192);
  conv1x1_k<0,false,false,false><<<dim3(ST/128, 3), 256, 0, stream>>>(R2, nullptr, 192, ffn_w2, ffn_b2, XT, 96, XT, 96, 192, 96);

  // fuse: out = x + conv1x1(concat(convout, xt), out_w) + out_b  (channel-first)
  conv1x1_k<0,false,true,true><<<dim3(ST/128, 6), 256, 0, stream>>>(R4, XT, 96, out_w, out_b, x, 0, (float*)d_out, 0, 192, 192);
}

// Round 3
// 297.419 us; speedup vs baseline: 1.6595x; 1.3462x over previous
//
#include <hip/hip_runtime.h>
#include <math.h>

#define HW_ 9216
#define IH 96
#define IW 96
#define NB 2
#define ST (NB*HW_)   // 18432 pixels total

typedef __attribute__((ext_vector_type(8))) short bf16x8;
typedef __attribute__((ext_vector_type(4))) float f32x4;

__device__ __forceinline__ float gelu_f(float v){
  return 0.5f*v*(1.0f+erff(v*0.70710678118654752440f));
}

__device__ __forceinline__ unsigned short f2bf(float f){
  unsigned u = __float_as_uint(f);
  unsigned r = (u + 0x7FFF + ((u>>16)&1)) >> 16;
  return (unsigned short)r;
}

// ---------------------------------------------------------------------------
// K1: NCHW -> NHWC transpose (x (B,192,HW) -> xcl (B,HW,192))
// ---------------------------------------------------------------------------
__global__ __launch_bounds__(256) void transpose_in_k(const float* __restrict__ x,
                                                      float* __restrict__ xcl){
  __shared__ float t[32][33];
  int b  = blockIdx.z;
  int c0 = blockIdx.y << 5;
  int p0 = blockIdx.x << 5;
  int tx = threadIdx.x & 31;
  int ty = threadIdx.x >> 5;   // 0..7
  const float* xb = x + (size_t)b*192*HW_;
  #pragma unroll
  for (int k=0;k<4;k++){
    int c = ty + k*8;
    t[c][tx] = xb[(size_t)(c0+c)*HW_ + p0 + tx];
  }
  __syncthreads();
  float* ob = xcl + (size_t)b*HW_*192;
  #pragma unroll
  for (int k=0;k<4;k++){
    int p = ty + k*8;
    ob[(size_t)(p0+p)*192 + c0 + tx] = t[tx][p];
  }
}

// ---------------------------------------------------------------------------
// K2: LayerNorm over 96 channels (1 wave per pixel).
// ---------------------------------------------------------------------------
__global__ __launch_bounds__(256) void ln_k(const float* __restrict__ in, int istride, int ioff,
                                            const float* __restrict__ gam, const float* __restrict__ bet,
                                            float* __restrict__ out, float* __restrict__ raw){
  int lane = threadIdx.x & 63;
  int wv   = threadIdx.x >> 6;
  int p    = (blockIdx.x << 2) + wv;
  const float* row = in + (size_t)p*istride + ioff;
  float v0 = row[lane];
  float v1 = (lane < 32) ? row[64+lane] : 0.0f;
  float s = v0 + v1;
  #pragma unroll
  for (int o=32;o;o>>=1) s += __shfl_xor(s,o);
  float mu = s * (1.0f/96.0f);
  float d0 = v0 - mu;
  float d1 = v1 - mu;
  float qv = d0*d0 + ((lane<32)? d1*d1 : 0.0f);
  #pragma unroll
  for (int o=32;o;o>>=1) qv += __shfl_xor(qv,o);
  float rstd = rsqrtf(qv*(1.0f/96.0f) + 1e-5f);
  float* orow = out + (size_t)p*96;
  orow[lane] = d0*rstd*gam[lane] + bet[lane];
  if (lane < 32) orow[64+lane] = d1*rstd*gam[64+lane] + bet[64+lane];
  if (raw){
    float* rrow = raw + (size_t)p*96;
    rrow[lane] = v0;
    if (lane < 32) rrow[64+lane] = v1;
  }
}

// ---------------------------------------------------------------------------
// K3 (fp32, only for the tiny p1 conv 192->16 + relu)
// ---------------------------------------------------------------------------
template<int ACT, bool PROD, bool CONCAT, bool FINAL>
__global__ __launch_bounds__(256) void conv1x1_k(
    const float* __restrict__ in1, const float* __restrict__ in2, int istride,
    const float* __restrict__ w, const float* __restrict__ bias,
    const float* __restrict__ res, int rstride,
    float* __restrict__ out, int ostride,
    int Cin, int Cout)
{
  __shared__ float smem[128*97 + 32*96];
  float (*lin)[97] = (float(*)[97])smem;
  float (*lw)[96]  = (float(*)[96])(smem + 128*97);

  const int tid  = threadIdx.x;
  const int lane = tid & 63, wv = tid >> 6;
  const int p0   = blockIdx.x << 7;
  const int co0  = blockIdx.y << 5;

  float acc[2][8];
  #pragma unroll
  for (int j=0;j<2;j++)
    #pragma unroll
    for (int k=0;k<8;k++) acc[j][k]=0.0f;

  for (int kc = 0; kc < Cin; kc += 96){
    {
      const float* src = (CONCAT && kc) ? in2 : in1;
      const int strd = CONCAT ? 96 : istride;
      const int boff = CONCAT ? 0 : kc;
      #pragma unroll
      for (int it=0; it<12; ++it){
        int idx = (tid<<2) + (it<<10);
        int rrow = idx / 96, col = idx - rrow*96;
        float4 v = *(const float4*)(src + (size_t)(p0+rrow)*strd + boff + col);
        if (PROD){
          const float4 v2 = *(const float4*)(in2 + (size_t)(p0+rrow)*strd + boff + col);
          v.x*=v2.x; v.y*=v2.y; v.z*=v2.z; v.w*=v2.w;
        }
        lin[rrow][col]=v.x; lin[rrow][col+1]=v.y; lin[rrow][col+2]=v.z; lin[rrow][col+3]=v.w;
      }
      #pragma unroll
      for (int it=0; it<3; ++it){
        int idx = (tid<<2) + (it<<10);
        int rrow = idx / 96, col = idx - rrow*96;
        int co = co0 + rrow;
        float4 v = make_float4(0.f,0.f,0.f,0.f);
        if (co < Cout) v = *(const float4*)(w + (size_t)co*Cin + kc + col);
        *(float4*)&lw[rrow][col] = v;
      }
    }
    __syncthreads();
    #pragma unroll 2
    for (int c=0;c<96;c+=4){
      float a0x=lin[lane][c],    a0y=lin[lane][c+1],    a0z=lin[lane][c+2],    a0w=lin[lane][c+3];
      float a1x=lin[lane+64][c], a1y=lin[lane+64][c+1], a1z=lin[lane+64][c+2], a1w=lin[lane+64][c+3];
      #pragma unroll
      for (int k=0;k<8;k++){
        const float4 wv4 = *(const float4*)&lw[(wv<<3)+k][c];
        acc[0][k] += a0x*wv4.x + a0y*wv4.y + a0z*wv4.z + a0w*wv4.w;
        acc[1][k] += a1x*wv4.x + a1y*wv4.y + a1z*wv4.z + a1w*wv4.w;
      }
    }
    __syncthreads();
  }

  float (*lt)[33] = (float(*)[33])smem;
  #pragma unroll
  for (int k=0;k<8;k++){
    int col = (wv<<3)+k;
    lt[lane][col]    = acc[0][k];
    lt[lane+64][col] = acc[1][k];
  }
  __syncthreads();
  const int pix = tid >> 1, half = tid & 1;
  const int p = p0 + pix;
  #pragma unroll
  for (int m=0;m<4;m++){
    int col = (half<<4) + (m<<2);
    int co = co0 + col;
    if (co >= Cout) continue;
    float4 v = make_float4(lt[pix][col], lt[pix][col+1], lt[pix][col+2], lt[pix][col+3]);
    if (bias){ v.x += bias[co]; v.y += bias[co+1]; v.z += bias[co+2]; v.w += bias[co+3]; }
    if (ACT==1){
      v.x=fmaxf(v.x,0.f); v.y=fmaxf(v.y,0.f); v.z=fmaxf(v.z,0.f); v.w=fmaxf(v.w,0.f);
    }
    if (res){
      const float4 rv = *(const float4*)(res + (size_t)p*rstride + co);
      v.x+=rv.x; v.y+=rv.y; v.z+=rv.z; v.w+=rv.w;
    }
    *(float4*)(out + (size_t)p*ostride + co) = v;
  }
}

// ---------------------------------------------------------------------------
// K3b: bf16-MFMA conv1x1.  Block: 128 px x 64 couts, 4 waves (2M x 2N).
// A = weights bf16 [Cout][Cin] row-major; B = activations converted to bf16
// during LDS staging. K-chunks of 96. fp32 accum; LDS-transpose epilogue.
// ---------------------------------------------------------------------------
template<bool PROD, bool CONCAT, bool FINAL, bool HASB, bool HASR>
__global__ __launch_bounds__(256) void conv_mfma_k(
    const float* __restrict__ in1, const float* __restrict__ in2, int istride,
    const unsigned short* __restrict__ wbf, const float* __restrict__ bias,
    const float* __restrict__ res, int rstride,
    float* __restrict__ out, int ostride, int Cin, int Cout)
{
  __shared__ __align__(16) unsigned char smem[39936];
  unsigned char* actl = smem;          // [128][208B]  (96 bf16 + pad -> 2-way free)
  unsigned char* wl   = smem + 26624;  // [64][208B]
  const int tid=threadIdx.x, lane=tid&63, wv=tid>>6;
  const int lr=lane&15, g4=lane>>4, wm=wv>>1, wn=wv&1;
  const int p0=blockIdx.x<<7, co0=blockIdx.y<<6;

  f32x4 acc[2][4];
  #pragma unroll
  for (int m=0;m<2;m++)
    #pragma unroll
    for (int n=0;n<4;n++) acc[m][n]=(f32x4){0.f,0.f,0.f,0.f};

  for (int kc=0; kc<Cin; kc+=96){
    // stage act: thread -> (row=tid>>1, half=tid&1), 6 slots of 8ch each
    {
      const int row=tid>>1, half=tid&1;
      const float* src = (CONCAT && kc) ? in2 : in1;
      const int koff = CONCAT ? 0 : kc;
      const float* rp = src + (size_t)(p0+row)*istride + koff + half*48;
      const float* rp2 = PROD ? (in2 + (size_t)(p0+row)*istride + koff + half*48) : nullptr;
      #pragma unroll
      for (int s=0;s<6;s++){
        float4 a=*(const float4*)(rp+s*8), b=*(const float4*)(rp+s*8+4);
        if (PROD){
          const float4 c=*(const float4*)(rp2+s*8), d=*(const float4*)(rp2+s*8+4);
          a.x*=c.x; a.y*=c.y; a.z*=c.z; a.w*=c.w;
          b.x*=d.x; b.y*=d.y; b.z*=d.z; b.w*=d.w;
        }
        uint4 pk;
        pk.x=(unsigned)f2bf(a.x)|((unsigned)f2bf(a.y)<<16);
        pk.y=(unsigned)f2bf(a.z)|((unsigned)f2bf(a.w)<<16);
        pk.z=(unsigned)f2bf(b.x)|((unsigned)f2bf(b.y)<<16);
        pk.w=(unsigned)f2bf(b.z)|((unsigned)f2bf(b.w)<<16);
        *(uint4*)(actl + row*208 + (half*6+s)*16) = pk;
      }
    }
    // stage weights (already bf16): thread -> (row=tid&63, grp=tid>>6), 3 slots
    {
      const int row=tid&63, grp=tid>>6;
      const int co=co0+row;
      const unsigned short* wr = wbf + (size_t)co*Cin + kc;
      #pragma unroll
      for (int s=0;s<3;s++){
        int sl=grp*3+s;
        uint4 v={0,0,0,0};
        if (co<Cout) v=*(const uint4*)(wr + sl*8);
        *(uint4*)(wl + row*208 + sl*16)=v;
      }
    }
    __syncthreads();
    #pragma unroll
    for (int ks=0;ks<3;ks++){
      const int sl=ks*4+g4;
      bf16x8 afr[2], bfr[4];
      #pragma unroll
      for (int m=0;m<2;m++) afr[m]=*(const bf16x8*)(wl + ((wm*2+m)*16+lr)*208 + sl*16);
      #pragma unroll
      for (int n=0;n<4;n++) bfr[n]=*(const bf16x8*)(actl + (wn*64+n*16+lr)*208 + sl*16);
      #pragma unroll
      for (int m=0;m<2;m++)
        #pragma unroll
        for (int n=0;n<4;n++)
          acc[m][n]=__builtin_amdgcn_mfma_f32_16x16x32_bf16(afr[m], bfr[n], acc[m][n],0,0,0);
    }
    __syncthreads();
  }

  if (FINAL){
    // channel-first out with NCHW residual
    #pragma unroll
    for (int m=0;m<2;m++){
      const int cb=co0+(wm*2+m)*16+(g4<<2);
      float4 bv = make_float4(0.f,0.f,0.f,0.f);
      if (HASB) bv = *(const float4*)(bias+cb);
      #pragma unroll
      for (int n=0;n<4;n++){
        const int p=p0+wn*64+n*16+lr;
        const int bb=p/HW_, hw=p-bb*HW_;
        const float av[4]={acc[m][n].x,acc[m][n].y,acc[m][n].z,acc[m][n].w};
        const float bvv[4]={bv.x,bv.y,bv.z,bv.w};
        #pragma unroll
        for (int j=0;j<4;j++){
          size_t oi=((size_t)bb*192+cb+j)*HW_+hw;
          out[oi]=av[j]+bvv[j]+res[oi];
        }
      }
    }
    return;
  }
  // transpose epilogue through LDS (stride 68 floats -> 2-way free)
  float* lt=(float*)smem;
  #pragma unroll
  for (int m=0;m<2;m++)
    #pragma unroll
    for (int n=0;n<4;n++){
      int px=wn*64+n*16+lr;
      int c=(wm*2+m)*16+(g4<<2);
      *(f32x4*)&lt[px*68+c]=acc[m][n];
    }
  __syncthreads();
  {
    const int pr=tid>>1, half=tid&1;
    const int p=p0+pr;
    #pragma unroll
    for (int s=0;s<8;s++){
      int cl=half*32+s*4;
      int co=co0+cl;
      if (co<Cout){
        float4 v=*(float4*)&lt[pr*68+cl];
        if (HASB){ const float4 bv=*(const float4*)(bias+co); v.x+=bv.x;v.y+=bv.y;v.z+=bv.z;v.w+=bv.w; }
        if (HASR){ const float4 rv=*(const float4*)(res+(size_t)p*rstride+co); v.x+=rv.x;v.y+=rv.y;v.z+=rv.z;v.w+=rv.w; }
        *(float4*)(out+(size_t)p*ostride+co)=v;
      }
    }
  }
}

// ---------------------------------------------------------------------------
// K4: depthwise 3x3 (channel-last), optional bias + exact gelu
// ---------------------------------------------------------------------------
template<bool HASB, bool DOGELU>
__global__ __launch_bounds__(256) void dw3x3_k(const float* __restrict__ in, const float* __restrict__ w,
                                               const float* __restrict__ bias, float* __restrict__ out, int C){
  int t = blockIdx.x*256 + threadIdx.x;
  int cg = C >> 2;
  int p = t / cg;
  if (p >= ST) return;
  int c4 = (t - p*cg) << 2;
  int bb = p / HW_, hw = p - bb*HW_;
  int hy = hw / IW, wx = hw - hy*IW;
  float w0[9], w1[9], w2[9], w3[9];
  #pragma unroll
  for (int tp=0;tp<9;tp++){
    w0[tp]=w[(c4+0)*9+tp]; w1[tp]=w[(c4+1)*9+tp]; w2[tp]=w[(c4+2)*9+tp]; w3[tp]=w[(c4+3)*9+tp];
  }
  float ax=0.f, ay=0.f, az=0.f, aw=0.f;
  #pragma unroll
  for (int i=0;i<3;i++){
    int y = hy+i-1;
    if ((unsigned)y >= IH) continue;
    #pragma unroll
    for (int j=0;j<3;j++){
      int x2 = wx+j-1;
      if ((unsigned)x2 >= IW) continue;
      const float4 v = *(const float4*)(in + ((size_t)bb*HW_ + y*IW + x2)*C + c4);
      int tp=i*3+j;
      ax += v.x*w0[tp]; ay += v.y*w1[tp]; az += v.z*w2[tp]; aw += v.w*w3[tp];
    }
  }
  if (HASB){ ax+=bias[c4]; ay+=bias[c4+1]; az+=bias[c4+2]; aw+=bias[c4+3]; }
  if (DOGELU){ ax=gelu_f(ax); ay=gelu_f(ay); az=gelu_f(az); aw=gelu_f(aw); }
  *(float4*)(out + (size_t)p*C + c4) = make_float4(ax,ay,az,aw);
}

// ---------------------------------------------------------------------------
// K5: full 3x3 conv 16->16 for the adaconv "para" branch (weights in LDS)
// ---------------------------------------------------------------------------
__global__ __launch_bounds__(256) void p2conv_k(const float* __restrict__ in, const float* __restrict__ w,
                                                const float* __restrict__ bias, float* __restrict__ out){
  __shared__ float ws[2304];
  int tid = threadIdx.x;
  for (int i=tid;i<2304;i+=256) ws[i]=w[i];
  __syncthreads();
  int p = blockIdx.x*256 + tid;
  int bb = p / HW_, hw = p - bb*HW_;
  int hy = hw / IW, wx = hw - hy*IW;
  float acc[16];
  #pragma unroll
  for (int co=0;co<16;co++) acc[co]=bias[co];
  #pragma unroll
  for (int i=0;i<3;i++){
    int y=hy+i-1; if ((unsigned)y>=IH) continue;
    #pragma unroll
    for (int j=0;j<3;j++){
      int x2=wx+j-1; if ((unsigned)x2>=IW) continue;
      int tap=i*3+j;
      const float* prow = in + ((size_t)bb*HW_ + y*IW + x2)*16;
      #pragma unroll
      for (int ci=0;ci<16;ci++){
        float v = prow[ci];
        #pragma unroll
        for (int co=0;co<16;co++) acc[co] += ws[co*144 + ci*9 + tap]*v;
      }
    }
  }
  float* orow = out + (size_t)p*16;
  #pragma unroll
  for (int co=0;co<16;co++) orow[co]=acc[co];
}

// ---------------------------------------------------------------------------
// K6a: prep ada_w -> bf16 Amat[g][row=o*16+r][k=d padded to 128], row-major.
// ---------------------------------------------------------------------------
__global__ __launch_bounds__(256) void ada_prep_k(const float* __restrict__ aw,
                                                  unsigned short* __restrict__ apre){
  int g = blockIdx.y;
  int e = blockIdx.x*256 + threadIdx.x;    // 0..24575
  int row = e >> 7, k = e & 127;
  int o = row >> 4, r = row & 15;
  float v = (k < 108) ? aw[(((size_t)(g*12+o)*108)+k)*16 + r] : 0.f;
  apre[(size_t)g*24576 + e] = f2bf(v);
}

// ---------------------------------------------------------------------------
// K6c: generic fp32 -> bf16 weight prep for all conv1x1 weights (one launch)
// order: qkv, c1, c2, c3, proj, ffn1, ffn2, final
// ---------------------------------------------------------------------------
__global__ __launch_bounds__(256) void wprep_k(
    const float* __restrict__ s0, const float* __restrict__ s1,
    const float* __restrict__ s2, const float* __restrict__ s3,
    const float* __restrict__ s4, const float* __restrict__ s5,
    const float* __restrict__ s6, const float* __restrict__ s7,
    unsigned short* __restrict__ dst)
{
  const int sz[8]  = {27648,18432,18432,18432,9216,18432,18432,36864};
  const int off[8] = {0,27648,46080,64512,82944,92160,110592,129024};
  int m = blockIdx.y;
  int i = blockIdx.x*256 + threadIdx.x;
  const float* s = (m==0)?s0:(m==1)?s1:(m==2)?s2:(m==3)?s3:(m==4)?s4:(m==5)?s5:(m==6)?s6:s7;
  if (i < sz[m]) dst[off[m]+i] = f2bf(s[i]);
}

// ---------------------------------------------------------------------------
// K6b v2: adaconv via MFMA. Block: (b, g, 16x16-px region) = 1152 blocks.
// A fragments in registers (loaded once from L2). 4 subtiles of 8x8 px.
// XU build uses wave-static k-quarters so all idx math folds at compile time.
// ---------------------------------------------------------------------------
template<int Q>
__device__ __forceinline__ void buildq(const float* hb, unsigned* pk){
  #pragma unroll
  for (int jj=0;jj<16;jj++){
    float v0=0.f, v1=0.f;
    const int d0=Q*32+jj*2, d1=d0+1;
    if (d0<108){ const int cl=d0/9, tap=d0%9; v0=hb[((tap/3)*18+(tap%3))*13+cl]; }
    if (d1<108){ const int cl=d1/9, tap=d1%9; v1=hb[((tap/3)*18+(tap%3))*13+cl]; }
    pk[jj]=(unsigned)f2bf(v0)|((unsigned)f2bf(v1)<<16);
  }
}

__global__ __launch_bounds__(256) void adaconv_mfma_k(
    const float* __restrict__ x2, const float* __restrict__ para,
    const unsigned short* __restrict__ apre, float* __restrict__ outb2)
{
  __shared__ __align__(16) unsigned char smem[38352];
  unsigned char* XU = smem;                     // [64][256B] bf16, swizzle ^(p&15)
  float* xs = (float*)(smem + 16384);           // [18*18][13] f32 halo
  float* ps = (float*)(smem + 33232);           // [64][20] f32 para

  const int tid=threadIdx.x, lane=tid&63, wv=tid>>6;
  const int lr=lane&15, g4=lane>>4;
  const int b=blockIdx.z, g=blockIdx.y, reg=blockIdx.x;
  const int rh=(reg/6)<<4, rw=(reg%6)<<4;       // 16x16 region origin

  // A fragments from global (L2-hot, 48 rows per wave)
  bf16x8 af[3][4];
  {
    const unsigned short* ag = apre + (size_t)g*24576;
    #pragma unroll
    for (int oo=0;oo<3;oo++){
      const int row=(wv*3+oo)*16+lr;
      #pragma unroll
      for (int ks=0;ks<4;ks++)
        af[oo][ks] = *(const bf16x8*)(ag + row*128 + (ks*4+g4)*8);
    }
  }
  // halo staging: 18x18 px x 12 ch (stride 13 to spread banks)
  for (int idx=tid; idx<972; idx+=256){
    int hp = idx/3, q = idx - hp*3;
    int yy = hp/18, xx = hp - yy*18;
    int gy = rh+yy-1, gx = rw+xx-1;
    float4 v = make_float4(0.f,0.f,0.f,0.f);
    if ((unsigned)gy<IH && (unsigned)gx<IW)
      v = *(const float4*)(x2 + ((size_t)b*HW_ + gy*IW+gx)*192 + g*12 + q*4);
    float* dst = xs + hp*13 + q*4;
    dst[0]=v.x; dst[1]=v.y; dst[2]=v.z; dst[3]=v.w;
  }

  #pragma unroll 1
  for (int sub=0; sub<4; ++sub){
    const int sy=(sub>>1)*8, sx=(sub&1)*8;
    __syncthreads();   // halo ready (iter 0) / previous subtile consumers done
    // stage para subtile
    {
      int p=tid>>2, q=tid&3;
      int gy=rh+sy+(p>>3), gx=rw+sx+(p&7);
      float4 v = *(const float4*)(para + ((size_t)b*HW_+gy*IW+gx)*16 + q*4);
      *(float4*)&ps[p*20+q*4] = v;
    }
    // build XU: each wave owns one 32-k quarter (uniform branch, static idx)
    {
      const int p = tid&63;
      const int py = p>>3, px = p&7;
      const float* hb = xs + ((sy+py)*18 + (sx+px))*13;
      unsigned pk[16];
      if      (wv==0) buildq<0>(hb, pk);
      else if (wv==1) buildq<1>(hb, pk);
      else if (wv==2) buildq<2>(hb, pk);
      else            buildq<3>(hb, pk);
      #pragma unroll
      for (int s=0;s<4;s++){
        const int sl = wv*4+s;
        *(uint4*)(XU + p*256 + ((sl^(p&15))<<4)) = ((const uint4*)pk)[s];
      }
    }
    __syncthreads();
    // MFMA: 3 M-frags x 4 N-frags x 4 K-steps
    f32x4 acc[3][4];
    #pragma unroll
    for (int oo=0;oo<3;oo++)
      #pragma unroll
      for (int n=0;n<4;n++) acc[oo][n]=(f32x4){0.f,0.f,0.f,0.f};
    #pragma unroll
    for (int ks=0;ks<4;ks++){
      const int sl=ks*4+g4;
      bf16x8 bfr[4];
      #pragma unroll
      for (int n=0;n<4;n++){
        const int p=(n<<4)+lr;
        bfr[n]=*(const bf16x8*)(XU + p*256 + ((sl^(p&15))<<4));
      }
      #pragma unroll
      for (int oo=0;oo<3;oo++)
        #pragma unroll
        for (int n=0;n<4;n++)
          acc[oo][n]=__builtin_amdgcn_mfma_f32_16x16x32_bf16(af[oo][ks], bfr[n], acc[oo][n],0,0,0);
    }
    // epilogue: r-reduction with para, gelu, scatter write
    #pragma unroll
    for (int oo=0;oo<3;oo++){
      const int o=wv*3+oo;
      #pragma unroll
      for (int n=0;n<4;n++){
        const int p=(n<<4)+lr;
        const f32x4 prv = *(const f32x4*)&ps[p*20+(g4<<2)];
        float s=acc[oo][n].x*prv.x+acc[oo][n].y*prv.y+acc[oo][n].z*prv.z+acc[oo][n].w*prv.w;
        s += __shfl_xor(s,16); s += __shfl_xor(s,32);
        if (g4==((oo*4+n)&3)){
          const int py=p>>3, px=p&7;
          outb2[((size_t)b*HW_+(rh+sy+py)*IW+(rw+sx+px))*192+g*12+o]=gelu_f(s);
        }
      }
    }
  }
}

// ---------------------------------------------------------------------------
// K7: shifted-window attention, 1 wave per (window, head).
// ---------------------------------------------------------------------------
__global__ __launch_bounds__(64) void attn_k(const float* __restrict__ qkv,
                                             const float* __restrict__ relpos,
                                             float* __restrict__ outa){
  __shared__ float k_s[2048];
  __shared__ float v_s[2048];
  __shared__ float rel_s[225];
  const int win = blockIdx.x, head = blockIdx.y, b = blockIdx.z;
  const int wi = win/12, wj = win%12;
  const int lane = threadIdx.x;
  for (int i=lane;i<225;i+=64) rel_s[i] = relpos[i*3+head];
  const int pi = lane>>3, pj = lane&7;
  const int hr = wi*8+pi, wr = wj*8+pj;
  const int sh = (hr+4)%96, sw = (wr+4)%96;
  const size_t pix = (size_t)b*HW_ + sh*96 + sw;
  const float* qrow = qkv + pix*288 + head*32;
  const float* krow = qkv + pix*288 + 96 + head*32;
  const float* vrow = qkv + pix*288 + 192 + head*32;
  const float SC = 0.17677669529663687f; // 1/sqrt(32)
  float q[32];
  #pragma unroll
  for (int i=0;i<32;i+=4){
    const float4 t4 = *(const float4*)(qrow+i);
    q[i]=t4.x*SC; q[i+1]=t4.y*SC; q[i+2]=t4.z*SC; q[i+3]=t4.w*SC;
  }
  #pragma unroll
  for (int i=0;i<32;i+=4){
    *(float4*)&k_s[(lane<<5)+i] = *(const float4*)(krow+i);
    *(float4*)&v_s[(lane<<5)+i] = *(const float4*)(vrow+i);
  }
  __syncthreads();
  const bool mi = (wi==11), mj = (wj==11);
  float sc[64];
  #pragma unroll
  for (int qq=0; qq<64; qq++){
    const float4* kr4 = (const float4*)&k_s[qq<<5];
    float s = 0.f;
    #pragma unroll
    for (int i=0;i<8;i++){
      const float4 kv = kr4[i];
      s += q[4*i]*kv.x + q[4*i+1]*kv.y + q[4*i+2]*kv.z + q[4*i+3]*kv.w;
    }
    const int qi = qq>>3, qj = qq&7;
    s += rel_s[(pi-qi+7)*15 + (pj-qj+7)];
    const bool msk = (mi && ((pi<4)!=(qi<4))) || (mj && ((pj<4)!=(qj<4)));
    sc[qq] = msk ? -1e30f : s;
  }
  float m = sc[0];
  #pragma unroll
  for (int qq=1;qq<64;qq++) m = fmaxf(m, sc[qq]);
  float sum = 0.f;
  #pragma unroll
  for (int qq=0;qq<64;qq++){ float e = __expf(sc[qq]-m); sc[qq]=e; sum+=e; }
  const float inv = 1.f/sum;
  float acc[32];
  #pragma unroll
  for (int i=0;i<32;i++) acc[i]=0.f;
  #pragma unroll
  for (int qq=0;qq<64;qq++){
    const float a = sc[qq]*inv;
    const float4* vr4 = (const float4*)&v_s[qq<<5];
    #pragma unroll
    for (int i=0;i<8;i++){
      const float4 vv = vr4[i];
      acc[4*i]+=a*vv.x; acc[4*i+1]+=a*vv.y; acc[4*i+2]+=a*vv.z; acc[4*i+3]+=a*vv.w;
    }
  }
  float* orow = outa + pix*96 + head*32;
  #pragma unroll
  for (int i=0;i<32;i+=4)
    *(float4*)(orow+i) = make_float4(acc[i],acc[i+1],acc[i+2],acc[i+3]);
}

// ---------------------------------------------------------------------------
extern "C" void kernel_launch(void* const* d_in, const int* in_sizes, int n_in,
                              void* d_out, int out_size, void* d_ws, size_t ws_size,
                              hipStream_t stream)
{
  (void)in_sizes; (void)n_in; (void)out_size; (void)ws_size;
  const float* x        = (const float*)d_in[0];
  const float* cb_ln_g  = (const float*)d_in[1];
  const float* cb_ln_b  = (const float*)d_in[2];
  const float* cb_c1_pw = (const float*)d_in[3];
  const float* cb_c1_dw = (const float*)d_in[4];
  const float* cb_c2_pw = (const float*)d_in[5];
  const float* ada_w    = (const float*)d_in[6];
  const float* ada_p1_w = (const float*)d_in[7];
  const float* ada_p1_b = (const float*)d_in[8];
  const float* ada_p2_w = (const float*)d_in[9];
  const float* ada_p2_b = (const float*)d_in[10];
  const float* cb_c3_w  = (const float*)d_in[11];
  const float* ln1_g    = (const float*)d_in[12];
  const float* ln1_b    = (const float*)d_in[13];
  const float* qkv_w    = (const float*)d_in[14];
  const float* qkv_b    = (const float*)d_in[15];
  const float* rel_pos  = (const float*)d_in[16];
  const float* proj_w   = (const float*)d_in[17];
  const float* proj_b   = (const float*)d_in[18];
  const float* ln2_g    = (const float*)d_in[19];
  const float* ln2_b    = (const float*)d_in[20];
  const float* ffn_w1   = (const float*)d_in[21];
  const float* ffn_b1   = (const float*)d_in[22];
  const float* ffn_dw   = (const float*)d_in[23];
  const float* ffn_db   = (const float*)d_in[24];
  const float* ffn_w2   = (const float*)d_in[25];
  const float* ffn_b2   = (const float*)d_in[26];
  const float* out_w    = (const float*)d_in[27];
  const float* out_b    = (const float*)d_in[28];

  float* ws = (float*)d_ws;
  const size_t C192S = (size_t)ST*192;
  const size_t C96S  = (size_t)ST*96;
  const size_t C16S  = (size_t)ST*16;
  float* xcl = ws;                 // (B,HW,192) input channel-last
  float* R1  = ws + C192S;         // x1 -> x2 -> (qkv lower) -> y1
  float* R2  = ws + 2*C192S;       // b1 -> (qkv upper) -> y2
  float* B2b = ws + 3*C192S;       // b2 (adaconv+gelu out)
  float* R4  = ws + 4*C192S;       // r -> convout (96 ch)
  float* XT  = R4 + C96S;          // transformer residual stream (96 ch)
  float* R6  = XT + C96S;          // Apre (bf16) then ln outs / attn out
  float* PA1 = R6 + C96S;          // para1 (16 ch)
  float* PA2 = PA1 + C16S;         // para2 (16 ch)
  float* QKV = R1;                 // spans R1..R1+ST*288
  unsigned short* Apre = (unsigned short*)R6;      // consumed before ln1 writes R6
  unsigned short* Wbf  = (unsigned short*)(PA2 + C16S);  // 166K bf16 elems (332KB)
  const unsigned short* W_qkv  = Wbf + 0;
  const unsigned short* W_c1   = Wbf + 27648;
  const unsigned short* W_c2   = Wbf + 46080;
  const unsigned short* W_c3   = Wbf + 64512;
  const unsigned short* W_proj = Wbf + 82944;
  const unsigned short* W_ffn1 = Wbf + 92160;
  const unsigned short* W_ffn2 = Wbf + 110592;
  const unsigned short* W_fin  = Wbf + 129024;

  // weight preps
  wprep_k<<<dim3(144, 8), 256, 0, stream>>>(qkv_w, cb_c1_pw, cb_c2_pw, cb_c3_w,
                                            proj_w, ffn_w1, ffn_w2, out_w, Wbf);
  ada_prep_k<<<dim3(96, 16), 256, 0, stream>>>(ada_w, Apre);

  // conv branch
  transpose_in_k<<<dim3(HW_/32, 6, NB), 256, 0, stream>>>(x, xcl);
  ln_k<<<ST/4, 256, 0, stream>>>(xcl, 192, 0, cb_ln_g, cb_ln_b, R4, nullptr);
  conv_mfma_k<false,false,false,false,false><<<dim3(ST/128, 3), 256, 0, stream>>>(R4, nullptr, 96, W_c1, nullptr, nullptr, 0, R1, 192, 96, 192);
  dw3x3_k<false,false><<<(ST*48)/256, 256, 0, stream>>>(R1, cb_c1_dw, nullptr, R2, 192);
  conv_mfma_k<false,false,false,false,false><<<dim3(ST/128, 3), 256, 0, stream>>>(R4, nullptr, 96, W_c2, nullptr, nullptr, 0, R1, 192, 96, 192);
  conv1x1_k<1,false,false,false><<<dim3(ST/128, 1), 256, 0, stream>>>(R1, nullptr, 192, ada_p1_w, ada_p1_b, nullptr, 0, PA1, 16, 192, 16);
  p2conv_k<<<ST/256, 256, 0, stream>>>(PA1, ada_p2_w, ada_p2_b, PA2);
  adaconv_mfma_k<<<dim3(36, 16, NB), 256, 0, stream>>>(R1, PA2, Apre, B2b);
  conv_mfma_k<true,false,false,false,true><<<dim3(ST/128, 2), 256, 0, stream>>>(R2, B2b, 192, W_c3, nullptr, xcl, 192, R4, 96, 192, 96);

  // transformer branch
  ln_k<<<ST/4, 256, 0, stream>>>(xcl, 192, 96, ln1_g, ln1_b, R6, XT);
  conv_mfma_k<false,false,false,true,false><<<dim3(ST/128, 5), 256, 0, stream>>>(R6, nullptr, 96, W_qkv, qkv_b, nullptr, 0, QKV, 288, 96, 288);
  attn_k<<<dim3(144, 3, NB), 64, 0, stream>>>(QKV, rel_pos, R6);
  conv_mfma_k<false,false,false,true,true><<<dim3(ST/128, 2), 256, 0, stream>>>(R6, nullptr, 96, W_proj, proj_b, XT, 96, XT, 96, 96, 96);
  ln_k<<<ST/4, 256, 0, stream>>>(XT, 96, 0, ln2_g, ln2_b, R6, nullptr);
  conv_mfma_k<false,false,false,true,false><<<dim3(ST/128, 3), 256, 0, stream>>>(R6, nullptr, 96, W_ffn1, ffn_b1, nullptr, 0, R1, 192, 96, 192);
  dw3x3_k<true,true><<<(ST*48)/256, 256, 0, stream>>>(R1, ffn_dw, ffn_db, R2, 192);
  conv_mfma_k<false,false,false,true,true><<<dim3(ST/128, 2), 256, 0, stream>>>(R2, nullptr, 192, W_ffn2, ffn_b2, XT, 96, XT, 96, 192, 96);

  // fuse: out = x + conv1x1(concat(convout, xt), out_w) + out_b  (channel-first)
  conv_mfma_k<false,true,true,true,true><<<dim3(ST/128, 3), 256, 0, stream>>>(R4, XT, 96, W_fin, out_b, x, 0, (float*)d_out, 0, 192, 192);
}

// Round 4
// 292.627 us; speedup vs baseline: 1.6867x; 1.0164x over previous
//
#include <hip/hip_runtime.h>
#include <math.h>

#define HW_ 9216
#define IH 96
#define IW 96
#define NB 2
#define ST (NB*HW_)   // 18432 pixels total

typedef __attribute__((ext_vector_type(8))) short bf16x8;
typedef __attribute__((ext_vector_type(4))) float f32x4;

__device__ __forceinline__ float gelu_f(float v){
  return 0.5f*v*(1.0f+erff(v*0.70710678118654752440f));
}

__device__ __forceinline__ unsigned short f2bf(float f){
  unsigned u = __float_as_uint(f);
  unsigned r = (u + 0x7FFF + ((u>>16)&1)) >> 16;
  return (unsigned short)r;
}

// ---------------------------------------------------------------------------
// K1: NCHW -> NHWC transpose (x (B,192,HW) -> xcl (B,HW,192))
// ---------------------------------------------------------------------------
__global__ __launch_bounds__(256) void transpose_in_k(const float* __restrict__ x,
                                                      float* __restrict__ xcl){
  __shared__ float t[32][33];
  int b  = blockIdx.z;
  int c0 = blockIdx.y << 5;
  int p0 = blockIdx.x << 5;
  int tx = threadIdx.x & 31;
  int ty = threadIdx.x >> 5;   // 0..7
  const float* xb = x + (size_t)b*192*HW_;
  #pragma unroll
  for (int k=0;k<4;k++){
    int c = ty + k*8;
    t[c][tx] = xb[(size_t)(c0+c)*HW_ + p0 + tx];
  }
  __syncthreads();
  float* ob = xcl + (size_t)b*HW_*192;
  #pragma unroll
  for (int k=0;k<4;k++){
    int p = ty + k*8;
    ob[(size_t)(p0+p)*192 + c0 + tx] = t[tx][p];
  }
}

// ---------------------------------------------------------------------------
// K2: LayerNorm over 96 channels (1 wave per pixel).
// ---------------------------------------------------------------------------
__global__ __launch_bounds__(256) void ln_k(const float* __restrict__ in, int istride, int ioff,
                                            const float* __restrict__ gam, const float* __restrict__ bet,
                                            float* __restrict__ out, float* __restrict__ raw){
  int lane = threadIdx.x & 63;
  int wv   = threadIdx.x >> 6;
  int p    = (blockIdx.x << 2) + wv;
  const float* row = in + (size_t)p*istride + ioff;
  float v0 = row[lane];
  float v1 = (lane < 32) ? row[64+lane] : 0.0f;
  float s = v0 + v1;
  #pragma unroll
  for (int o=32;o;o>>=1) s += __shfl_xor(s,o);
  float mu = s * (1.0f/96.0f);
  float d0 = v0 - mu;
  float d1 = v1 - mu;
  float qv = d0*d0 + ((lane<32)? d1*d1 : 0.0f);
  #pragma unroll
  for (int o=32;o;o>>=1) qv += __shfl_xor(qv,o);
  float rstd = rsqrtf(qv*(1.0f/96.0f) + 1e-5f);
  float* orow = out + (size_t)p*96;
  orow[lane] = d0*rstd*gam[lane] + bet[lane];
  if (lane < 32) orow[64+lane] = d1*rstd*gam[64+lane] + bet[64+lane];
  if (raw){
    float* rrow = raw + (size_t)p*96;
    rrow[lane] = v0;
    if (lane < 32) rrow[64+lane] = v1;
  }
}

// ---------------------------------------------------------------------------
// K3 (fp32, only for the tiny p1 conv 192->16 + relu)
// ---------------------------------------------------------------------------
template<int ACT, bool PROD, bool CONCAT, bool FINAL>
__global__ __launch_bounds__(256) void conv1x1_k(
    const float* __restrict__ in1, const float* __restrict__ in2, int istride,
    const float* __restrict__ w, const float* __restrict__ bias,
    const float* __restrict__ res, int rstride,
    float* __restrict__ out, int ostride,
    int Cin, int Cout)
{
  __shared__ float smem[128*97 + 32*96];
  float (*lin)[97] = (float(*)[97])smem;
  float (*lw)[96]  = (float(*)[96])(smem + 128*97);

  const int tid  = threadIdx.x;
  const int lane = tid & 63, wv = tid >> 6;
  const int p0   = blockIdx.x << 7;
  const int co0  = blockIdx.y << 5;

  float acc[2][8];
  #pragma unroll
  for (int j=0;j<2;j++)
    #pragma unroll
    for (int k=0;k<8;k++) acc[j][k]=0.0f;

  for (int kc = 0; kc < Cin; kc += 96){
    {
      const float* src = (CONCAT && kc) ? in2 : in1;
      const int strd = CONCAT ? 96 : istride;
      const int boff = CONCAT ? 0 : kc;
      #pragma unroll
      for (int it=0; it<12; ++it){
        int idx = (tid<<2) + (it<<10);
        int rrow = idx / 96, col = idx - rrow*96;
        float4 v = *(const float4*)(src + (size_t)(p0+rrow)*strd + boff + col);
        if (PROD){
          const float4 v2 = *(const float4*)(in2 + (size_t)(p0+rrow)*strd + boff + col);
          v.x*=v2.x; v.y*=v2.y; v.z*=v2.z; v.w*=v2.w;
        }
        lin[rrow][col]=v.x; lin[rrow][col+1]=v.y; lin[rrow][col+2]=v.z; lin[rrow][col+3]=v.w;
      }
      #pragma unroll
      for (int it=0; it<3; ++it){
        int idx = (tid<<2) + (it<<10);
        int rrow = idx / 96, col = idx - rrow*96;
        int co = co0 + rrow;
        float4 v = make_float4(0.f,0.f,0.f,0.f);
        if (co < Cout) v = *(const float4*)(w + (size_t)co*Cin + kc + col);
        *(float4*)&lw[rrow][col] = v;
      }
    }
    __syncthreads();
    #pragma unroll 2
    for (int c=0;c<96;c+=4){
      float a0x=lin[lane][c],    a0y=lin[lane][c+1],    a0z=lin[lane][c+2],    a0w=lin[lane][c+3];
      float a1x=lin[lane+64][c], a1y=lin[lane+64][c+1], a1z=lin[lane+64][c+2], a1w=lin[lane+64][c+3];
      #pragma unroll
      for (int k=0;k<8;k++){
        const float4 wv4 = *(const float4*)&lw[(wv<<3)+k][c];
        acc[0][k] += a0x*wv4.x + a0y*wv4.y + a0z*wv4.z + a0w*wv4.w;
        acc[1][k] += a1x*wv4.x + a1y*wv4.y + a1z*wv4.z + a1w*wv4.w;
      }
    }
    __syncthreads();
  }

  float (*lt)[33] = (float(*)[33])smem;
  #pragma unroll
  for (int k=0;k<8;k++){
    int col = (wv<<3)+k;
    lt[lane][col]    = acc[0][k];
    lt[lane+64][col] = acc[1][k];
  }
  __syncthreads();
  const int pix = tid >> 1, half = tid & 1;
  const int p = p0 + pix;
  #pragma unroll
  for (int m=0;m<4;m++){
    int col = (half<<4) + (m<<2);
    int co = co0 + col;
    if (co >= Cout) continue;
    float4 v = make_float4(lt[pix][col], lt[pix][col+1], lt[pix][col+2], lt[pix][col+3]);
    if (bias){ v.x += bias[co]; v.y += bias[co+1]; v.z += bias[co+2]; v.w += bias[co+3]; }
    if (ACT==1){
      v.x=fmaxf(v.x,0.f); v.y=fmaxf(v.y,0.f); v.z=fmaxf(v.z,0.f); v.w=fmaxf(v.w,0.f);
    }
    if (res){
      const float4 rv = *(const float4*)(res + (size_t)p*rstride + co);
      v.x+=rv.x; v.y+=rv.y; v.z+=rv.z; v.w+=rv.w;
    }
    *(float4*)(out + (size_t)p*ostride + co) = v;
  }
}

// ---------------------------------------------------------------------------
// K3b: bf16-MFMA conv1x1.  Block: 128 px x 64 couts, 4 waves (2M x 2N).
// ---------------------------------------------------------------------------
template<bool PROD, bool CONCAT, bool FINAL, bool HASB, bool HASR>
__global__ __launch_bounds__(256) void conv_mfma_k(
    const float* __restrict__ in1, const float* __restrict__ in2, int istride,
    const unsigned short* __restrict__ wbf, const float* __restrict__ bias,
    const float* __restrict__ res, int rstride,
    float* __restrict__ out, int ostride, int Cin, int Cout)
{
  __shared__ __align__(16) unsigned char smem[39936];
  unsigned char* actl = smem;          // [128][208B]  (96 bf16 + pad -> 2-way free)
  unsigned char* wl   = smem + 26624;  // [64][208B]
  const int tid=threadIdx.x, lane=tid&63, wv=tid>>6;
  const int lr=lane&15, g4=lane>>4, wm=wv>>1, wn=wv&1;
  const int p0=blockIdx.x<<7, co0=blockIdx.y<<6;

  f32x4 acc[2][4];
  #pragma unroll
  for (int m=0;m<2;m++)
    #pragma unroll
    for (int n=0;n<4;n++) acc[m][n]=(f32x4){0.f,0.f,0.f,0.f};

  for (int kc=0; kc<Cin; kc+=96){
    {
      const int row=tid>>1, half=tid&1;
      const float* src = (CONCAT && kc) ? in2 : in1;
      const int koff = CONCAT ? 0 : kc;
      const float* rp = src + (size_t)(p0+row)*istride + koff + half*48;
      const float* rp2 = PROD ? (in2 + (size_t)(p0+row)*istride + koff + half*48) : nullptr;
      #pragma unroll
      for (int s=0;s<6;s++){
        float4 a=*(const float4*)(rp+s*8), b=*(const float4*)(rp+s*8+4);
        if (PROD){
          const float4 c=*(const float4*)(rp2+s*8), d=*(const float4*)(rp2+s*8+4);
          a.x*=c.x; a.y*=c.y; a.z*=c.z; a.w*=c.w;
          b.x*=d.x; b.y*=d.y; b.z*=d.z; b.w*=d.w;
        }
        uint4 pk;
        pk.x=(unsigned)f2bf(a.x)|((unsigned)f2bf(a.y)<<16);
        pk.y=(unsigned)f2bf(a.z)|((unsigned)f2bf(a.w)<<16);
        pk.z=(unsigned)f2bf(b.x)|((unsigned)f2bf(b.y)<<16);
        pk.w=(unsigned)f2bf(b.z)|((unsigned)f2bf(b.w)<<16);
        *(uint4*)(actl + row*208 + (half*6+s)*16) = pk;
      }
    }
    {
      const int row=tid&63, grp=tid>>6;
      const int co=co0+row;
      const unsigned short* wr = wbf + (size_t)co*Cin + kc;
      #pragma unroll
      for (int s=0;s<3;s++){
        int sl=grp*3+s;
        uint4 v={0,0,0,0};
        if (co<Cout) v=*(const uint4*)(wr + sl*8);
        *(uint4*)(wl + row*208 + sl*16)=v;
      }
    }
    __syncthreads();
    #pragma unroll
    for (int ks=0;ks<3;ks++){
      const int sl=ks*4+g4;
      bf16x8 afr[2], bfr[4];
      #pragma unroll
      for (int m=0;m<2;m++) afr[m]=*(const bf16x8*)(wl + ((wm*2+m)*16+lr)*208 + sl*16);
      #pragma unroll
      for (int n=0;n<4;n++) bfr[n]=*(const bf16x8*)(actl + (wn*64+n*16+lr)*208 + sl*16);
      #pragma unroll
      for (int m=0;m<2;m++)
        #pragma unroll
        for (int n=0;n<4;n++)
          acc[m][n]=__builtin_amdgcn_mfma_f32_16x16x32_bf16(afr[m], bfr[n], acc[m][n],0,0,0);
    }
    __syncthreads();
  }

  if (FINAL){
    #pragma unroll
    for (int m=0;m<2;m++){
      const int cb=co0+(wm*2+m)*16+(g4<<2);
      float4 bv = make_float4(0.f,0.f,0.f,0.f);
      if (HASB) bv = *(const float4*)(bias+cb);
      #pragma unroll
      for (int n=0;n<4;n++){
        const int p=p0+wn*64+n*16+lr;
        const int bb=p/HW_, hw=p-bb*HW_;
        const float av[4]={acc[m][n].x,acc[m][n].y,acc[m][n].z,acc[m][n].w};
        const float bvv[4]={bv.x,bv.y,bv.z,bv.w};
        #pragma unroll
        for (int j=0;j<4;j++){
          size_t oi=((size_t)bb*192+cb+j)*HW_+hw;
          out[oi]=av[j]+bvv[j]+res[oi];
        }
      }
    }
    return;
  }
  float* lt=(float*)smem;
  #pragma unroll
  for (int m=0;m<2;m++)
    #pragma unroll
    for (int n=0;n<4;n++){
      int px=wn*64+n*16+lr;
      int c=(wm*2+m)*16+(g4<<2);
      *(f32x4*)&lt[px*68+c]=acc[m][n];
    }
  __syncthreads();
  {
    const int pr=tid>>1, half=tid&1;
    const int p=p0+pr;
    #pragma unroll
    for (int s=0;s<8;s++){
      int cl=half*32+s*4;
      int co=co0+cl;
      if (co<Cout){
        float4 v=*(float4*)&lt[pr*68+cl];
        if (HASB){ const float4 bv=*(const float4*)(bias+co); v.x+=bv.x;v.y+=bv.y;v.z+=bv.z;v.w+=bv.w; }
        if (HASR){ const float4 rv=*(const float4*)(res+(size_t)p*rstride+co); v.x+=rv.x;v.y+=rv.y;v.z+=rv.z;v.w+=rv.w; }
        *(float4*)(out+(size_t)p*ostride+co)=v;
      }
    }
  }
}

// ---------------------------------------------------------------------------
// K4: depthwise 3x3 (channel-last), optional bias + exact gelu
// ---------------------------------------------------------------------------
template<bool HASB, bool DOGELU>
__global__ __launch_bounds__(256) void dw3x3_k(const float* __restrict__ in, const float* __restrict__ w,
                                               const float* __restrict__ bias, float* __restrict__ out, int C){
  int t = blockIdx.x*256 + threadIdx.x;
  int cg = C >> 2;
  int p = t / cg;
  if (p >= ST) return;
  int c4 = (t - p*cg) << 2;
  int bb = p / HW_, hw = p - bb*HW_;
  int hy = hw / IW, wx = hw - hy*IW;
  float w0[9], w1[9], w2[9], w3[9];
  #pragma unroll
  for (int tp=0;tp<9;tp++){
    w0[tp]=w[(c4+0)*9+tp]; w1[tp]=w[(c4+1)*9+tp]; w2[tp]=w[(c4+2)*9+tp]; w3[tp]=w[(c4+3)*9+tp];
  }
  float ax=0.f, ay=0.f, az=0.f, aw=0.f;
  #pragma unroll
  for (int i=0;i<3;i++){
    int y = hy+i-1;
    if ((unsigned)y >= IH) continue;
    #pragma unroll
    for (int j=0;j<3;j++){
      int x2 = wx+j-1;
      if ((unsigned)x2 >= IW) continue;
      const float4 v = *(const float4*)(in + ((size_t)bb*HW_ + y*IW + x2)*C + c4);
      int tp=i*3+j;
      ax += v.x*w0[tp]; ay += v.y*w1[tp]; az += v.z*w2[tp]; aw += v.w*w3[tp];
    }
  }
  if (HASB){ ax+=bias[c4]; ay+=bias[c4+1]; az+=bias[c4+2]; aw+=bias[c4+3]; }
  if (DOGELU){ ax=gelu_f(ax); ay=gelu_f(ay); az=gelu_f(az); aw=gelu_f(aw); }
  *(float4*)(out + (size_t)p*C + c4) = make_float4(ax,ay,az,aw);
}

// ---------------------------------------------------------------------------
// K5: full 3x3 conv 16->16 for the adaconv "para" branch (weights in LDS)
// ---------------------------------------------------------------------------
__global__ __launch_bounds__(256) void p2conv_k(const float* __restrict__ in, const float* __restrict__ w,
                                                const float* __restrict__ bias, float* __restrict__ out){
  __shared__ float ws[2304];
  int tid = threadIdx.x;
  for (int i=tid;i<2304;i+=256) ws[i]=w[i];
  __syncthreads();
  int p = blockIdx.x*256 + tid;
  int bb = p / HW_, hw = p - bb*HW_;
  int hy = hw / IW, wx = hw - hy*IW;
  float acc[16];
  #pragma unroll
  for (int co=0;co<16;co++) acc[co]=bias[co];
  #pragma unroll
  for (int i=0;i<3;i++){
    int y=hy+i-1; if ((unsigned)y>=IH) continue;
    #pragma unroll
    for (int j=0;j<3;j++){
      int x2=wx+j-1; if ((unsigned)x2>=IW) continue;
      int tap=i*3+j;
      const float* prow = in + ((size_t)bb*HW_ + y*IW + x2)*16;
      #pragma unroll
      for (int ci=0;ci<16;ci++){
        float v = prow[ci];
        #pragma unroll
        for (int co=0;co<16;co++) acc[co] += ws[co*144 + ci*9 + tap]*v;
      }
    }
  }
  float* orow = out + (size_t)p*16;
  #pragma unroll
  for (int co=0;co<16;co++) orow[co]=acc[co];
}

// ---------------------------------------------------------------------------
// K6a: prep ada_w -> bf16 Amat[g][row=o*16+r][k'=tap*16+cl], K'=160.
// cl>=12 or tap>=9 -> 0.  (tap-major K so B-frags are contiguous channels)
// ---------------------------------------------------------------------------
__global__ __launch_bounds__(256) void ada_prep_k(const float* __restrict__ aw,
                                                  unsigned short* __restrict__ apre){
  int g = blockIdx.y;
  int e = blockIdx.x*256 + threadIdx.x;    // 0..30719
  int row = e / 160, kp = e - row*160;
  int tap = kp >> 4, cl = kp & 15;
  int o = row >> 4, r = row & 15;
  float v = 0.f;
  if (tap < 9 && cl < 12)
    v = aw[(((size_t)(g*12+o)*108) + cl*9 + tap)*16 + r];
  apre[(size_t)g*30720 + e] = f2bf(v);
}

// ---------------------------------------------------------------------------
// K6c: generic fp32 -> bf16 weight prep for all conv1x1 weights (one launch)
// ---------------------------------------------------------------------------
__global__ __launch_bounds__(256) void wprep_k(
    const float* __restrict__ s0, const float* __restrict__ s1,
    const float* __restrict__ s2, const float* __restrict__ s3,
    const float* __restrict__ s4, const float* __restrict__ s5,
    const float* __restrict__ s6, const float* __restrict__ s7,
    unsigned short* __restrict__ dst)
{
  const int sz[8]  = {27648,18432,18432,18432,9216,18432,18432,36864};
  const int off[8] = {0,27648,46080,64512,82944,92160,110592,129024};
  int m = blockIdx.y;
  int i = blockIdx.x*256 + threadIdx.x;
  const float* s = (m==0)?s0:(m==1)?s1:(m==2)?s2:(m==3)?s3:(m==4)?s4:(m==5)?s5:(m==6)?s6:s7;
  if (i < sz[m]) dst[off[m]+i] = f2bf(s[i]);
}

// ---------------------------------------------------------------------------
// K6b v3: adaconv via MFMA, no XU build.  Block: (b, g, 16x16 region).
// K' = tap*16+cl (160): a B-fragment = 8 contiguous bf16 channels of one
// halo pixel -> single ds_read_b128 from the bf16 halo (48B row stride).
// A fragments in registers.  One barrier for staging, then pure MFMA loops.
// ---------------------------------------------------------------------------
__global__ __launch_bounds__(256) void adaconv_mfma_k(
    const float* __restrict__ x2, const float* __restrict__ para,
    const unsigned short* __restrict__ apre, float* __restrict__ outb2)
{
  __shared__ __align__(16) unsigned char smem[39104];
  unsigned char* HB = smem;                 // 18x18 halo px * 48B (16 bf16 ch) = 15552
  float* PS = (float*)(smem + 15552);       // [4 sub][64 px][20] f32 = 20480
  float* OS = (float*)(smem + 36032);       // [64 px][12 o] f32 = 3072

  const int tid=threadIdx.x, lane=tid&63, wv=tid>>6;
  const int lr=lane&15, g4=lane>>4;
  const int hi=(lane>>5)&1, lo16=(lane>>4)&1;
  const int b=blockIdx.z, g=blockIdx.y, reg=blockIdx.x;
  const int rh=(reg/6)<<4, rw=(reg%6)<<4;

  // --- A fragments (tap-major K'), 15 x 16B per lane from L2 ---
  bf16x8 af[3][5];
  {
    const unsigned short* ag = apre + (size_t)g*30720;
    #pragma unroll
    for (int oo=0;oo<3;oo++){
      const int row=(wv*3+oo)*16+lr;
      #pragma unroll
      for (int ks=0;ks<5;ks++)
        af[oo][ks] = *(const bf16x8*)(ag + row*160 + ks*32 + g4*8);
    }
  }
  // --- stage halo: 18x18 px, 12 real ch -> 16 bf16 (4 zero), 48B stride ---
  for (int idx=tid; idx<324; idx+=256){
    int hy = idx/18, hx = idx - hy*18;
    int gy = rh+hy-1, gx = rw+hx-1;
    float4 a=make_float4(0,0,0,0), c=a, d=a;
    if ((unsigned)gy<IH && (unsigned)gx<IW){
      const float* src = x2 + ((size_t)b*HW_ + gy*IW + gx)*192 + g*12;
      a=*(const float4*)(src); c=*(const float4*)(src+4); d=*(const float4*)(src+8);
    }
    uint4 lov, hiv;
    lov.x=(unsigned)f2bf(a.x)|((unsigned)f2bf(a.y)<<16);
    lov.y=(unsigned)f2bf(a.z)|((unsigned)f2bf(a.w)<<16);
    lov.z=(unsigned)f2bf(c.x)|((unsigned)f2bf(c.y)<<16);
    lov.w=(unsigned)f2bf(c.z)|((unsigned)f2bf(c.w)<<16);
    hiv.x=(unsigned)f2bf(d.x)|((unsigned)f2bf(d.y)<<16);
    hiv.y=(unsigned)f2bf(d.z)|((unsigned)f2bf(d.w)<<16);
    hiv.z=0; hiv.w=0;
    *(uint4*)(HB + idx*48)      = lov;
    *(uint4*)(HB + idx*48 + 16) = hiv;
  }
  // --- stage ALL 4 para subtiles (1024 float4 tasks) ---
  #pragma unroll
  for (int it=0; it<4; ++it){
    int idx = tid + (it<<8);
    int sub = idx >> 8;
    int p = (idx>>2)&63, q = idx&3;
    int gy = rh + ((sub>>1)<<3) + (p>>3), gx = rw + ((sub&1)<<3) + (p&7);
    float4 v = *(const float4*)(para + ((size_t)b*HW_+gy*IW+gx)*16 + q*4);
    *(float4*)&PS[sub*1280 + p*20 + q*4] = v;
  }
  __syncthreads();

  // per-lane tap offsets: tap = ks*2 + hi (tap 9 clamped to 8; A pads are 0)
  int tapoff[5];
  tapoff[0] = hi ? 48   : 0;
  tapoff[1] = hi ? 864  : 96;
  tapoff[2] = hi ? 960  : 912;
  tapoff[3] = hi ? 1776 : 1728;
  tapoff[4] = 1824;

  #pragma unroll 1
  for (int sub=0; sub<4; ++sub){
    const int sy=(sub>>1)<<3, sx=(sub&1)<<3;
    const int base0 = ((sy + (lr>>3))*18 + sx + (lr&7))*48 + lo16*16;

    f32x4 acc[3][4];
    #pragma unroll
    for (int oo=0;oo<3;oo++)
      #pragma unroll
      for (int n=0;n<4;n++) acc[oo][n]=(f32x4){0.f,0.f,0.f,0.f};

    #pragma unroll
    for (int ks=0;ks<5;ks++){
      bf16x8 bfr[4];
      #pragma unroll
      for (int n=0;n<4;n++)
        bfr[n] = *(const bf16x8*)(HB + base0 + n*1728 + tapoff[ks]);
      #pragma unroll
      for (int oo=0;oo<3;oo++)
        #pragma unroll
        for (int n=0;n<4;n++)
          acc[oo][n]=__builtin_amdgcn_mfma_f32_16x16x32_bf16(af[oo][ks], bfr[n], acc[oo][n],0,0,0);
    }

    // epilogue: r-reduce with para -> gelu -> OS, then coalesced store
    const float* ps = &PS[sub*1280];
    #pragma unroll
    for (int oo=0;oo<3;oo++){
      const int o=wv*3+oo;
      #pragma unroll
      for (int n=0;n<4;n++){
        const int p=(n<<4)+lr;
        const f32x4 prv = *(const f32x4*)&ps[p*20+(g4<<2)];
        float s=acc[oo][n].x*prv.x+acc[oo][n].y*prv.y+acc[oo][n].z*prv.z+acc[oo][n].w*prv.w;
        s += __shfl_xor(s,16); s += __shfl_xor(s,32);
        if (g4==n) OS[p*12+o] = gelu_f(s);
      }
    }
    __syncthreads();
    if (tid < 192){
      int p = tid/3, q = tid - p*3;
      float4 v = *(float4*)&OS[p*12 + q*4];
      *(float4*)(outb2 + ((size_t)b*HW_ + (rh+sy+(p>>3))*IW + (rw+sx+(p&7)))*192 + g*12 + q*4) = v;
    }
    __syncthreads();
  }
}

// ---------------------------------------------------------------------------
// K7: shifted-window attention, 1 wave per (window, head).
// ---------------------------------------------------------------------------
__global__ __launch_bounds__(64) void attn_k(const float* __restrict__ qkv,
                                             const float* __restrict__ relpos,
                                             float* __restrict__ outa){
  __shared__ float k_s[2048];
  __shared__ float v_s[2048];
  __shared__ float rel_s[225];
  const int win = blockIdx.x, head = blockIdx.y, b = blockIdx.z;
  const int wi = win/12, wj = win%12;
  const int lane = threadIdx.x;
  for (int i=lane;i<225;i+=64) rel_s[i] = relpos[i*3+head];
  const int pi = lane>>3, pj = lane&7;
  const int hr = wi*8+pi, wr = wj*8+pj;
  const int sh = (hr+4)%96, sw = (wr+4)%96;
  const size_t pix = (size_t)b*HW_ + sh*96 + sw;
  const float* qrow = qkv + pix*288 + head*32;
  const float* krow = qkv + pix*288 + 96 + head*32;
  const float* vrow = qkv + pix*288 + 192 + head*32;
  const float SC = 0.17677669529663687f; // 1/sqrt(32)
  float q[32];
  #pragma unroll
  for (int i=0;i<32;i+=4){
    const float4 t4 = *(const float4*)(qrow+i);
    q[i]=t4.x*SC; q[i+1]=t4.y*SC; q[i+2]=t4.z*SC; q[i+3]=t4.w*SC;
  }
  #pragma unroll
  for (int i=0;i<32;i+=4){
    *(float4*)&k_s[(lane<<5)+i] = *(const float4*)(krow+i);
    *(float4*)&v_s[(lane<<5)+i] = *(const float4*)(vrow+i);
  }
  __syncthreads();
  const bool mi = (wi==11), mj = (wj==11);
  float sc[64];
  #pragma unroll
  for (int qq=0; qq<64; qq++){
    const float4* kr4 = (const float4*)&k_s[qq<<5];
    float s = 0.f;
    #pragma unroll
    for (int i=0;i<8;i++){
      const float4 kv = kr4[i];
      s += q[4*i]*kv.x + q[4*i+1]*kv.y + q[4*i+2]*kv.z + q[4*i+3]*kv.w;
    }
    const int qi = qq>>3, qj = qq&7;
    s += rel_s[(pi-qi+7)*15 + (pj-qj+7)];
    const bool msk = (mi && ((pi<4)!=(qi<4))) || (mj && ((pj<4)!=(qj<4)));
    sc[qq] = msk ? -1e30f : s;
  }
  float m = sc[0];
  #pragma unroll
  for (int qq=1;qq<64;qq++) m = fmaxf(m, sc[qq]);
  float sum = 0.f;
  #pragma unroll
  for (int qq=0;qq<64;qq++){ float e = __expf(sc[qq]-m); sc[qq]=e; sum+=e; }
  const float inv = 1.f/sum;
  float acc[32];
  #pragma unroll
  for (int i=0;i<32;i++) acc[i]=0.f;
  #pragma unroll
  for (int qq=0;qq<64;qq++){
    const float a = sc[qq]*inv;
    const float4* vr4 = (const float4*)&v_s[qq<<5];
    #pragma unroll
    for (int i=0;i<8;i++){
      const float4 vv = vr4[i];
      acc[4*i]+=a*vv.x; acc[4*i+1]+=a*vv.y; acc[4*i+2]+=a*vv.z; acc[4*i+3]+=a*vv.w;
    }
  }
  float* orow = outa + pix*96 + head*32;
  #pragma unroll
  for (int i=0;i<32;i+=4)
    *(float4*)(orow+i) = make_float4(acc[i],acc[i+1],acc[i+2],acc[i+3]);
}

// ---------------------------------------------------------------------------
extern "C" void kernel_launch(void* const* d_in, const int* in_sizes, int n_in,
                              void* d_out, int out_size, void* d_ws, size_t ws_size,
                              hipStream_t stream)
{
  (void)in_sizes; (void)n_in; (void)out_size; (void)ws_size;
  const float* x        = (const float*)d_in[0];
  const float* cb_ln_g  = (const float*)d_in[1];
  const float* cb_ln_b  = (const float*)d_in[2];
  const float* cb_c1_pw = (const float*)d_in[3];
  const float* cb_c1_dw = (const float*)d_in[4];
  const float* cb_c2_pw = (const float*)d_in[5];
  const float* ada_w    = (const float*)d_in[6];
  const float* ada_p1_w = (const float*)d_in[7];
  const float* ada_p1_b = (const float*)d_in[8];
  const float* ada_p2_w = (const float*)d_in[9];
  const float* ada_p2_b = (const float*)d_in[10];
  const float* cb_c3_w  = (const float*)d_in[11];
  const float* ln1_g    = (const float*)d_in[12];
  const float* ln1_b    = (const float*)d_in[13];
  const float* qkv_w    = (const float*)d_in[14];
  const float* qkv_b    = (const float*)d_in[15];
  const float* rel_pos  = (const float*)d_in[16];
  const float* proj_w   = (const float*)d_in[17];
  const float* proj_b   = (const float*)d_in[18];
  const float* ln2_g    = (const float*)d_in[19];
  const float* ln2_b    = (const float*)d_in[20];
  const float* ffn_w1   = (const float*)d_in[21];
  const float* ffn_b1   = (const float*)d_in[22];
  const float* ffn_dw   = (const float*)d_in[23];
  const float* ffn_db   = (const float*)d_in[24];
  const float* ffn_w2   = (const float*)d_in[25];
  const float* ffn_b2   = (const float*)d_in[26];
  const float* out_w    = (const float*)d_in[27];
  const float* out_b    = (const float*)d_in[28];

  float* ws = (float*)d_ws;
  const size_t C192S = (size_t)ST*192;
  const size_t C96S  = (size_t)ST*96;
  const size_t C16S  = (size_t)ST*16;
  float* xcl = ws;                 // (B,HW,192) input channel-last
  float* R1  = ws + C192S;         // x1 -> x2 -> (qkv lower) -> y1
  float* R2  = ws + 2*C192S;       // b1 -> (qkv upper) -> y2
  float* B2b = ws + 3*C192S;       // b2 (adaconv+gelu out)
  float* R4  = ws + 4*C192S;       // r -> convout (96 ch)
  float* XT  = R4 + C96S;          // transformer residual stream (96 ch)
  float* R6  = XT + C96S;          // Apre (bf16) then ln outs / attn out
  float* PA1 = R6 + C96S;          // para1 (16 ch)
  float* PA2 = PA1 + C16S;         // para2 (16 ch)
  float* QKV = R1;                 // spans R1..R1+ST*288
  unsigned short* Apre = (unsigned short*)R6;      // consumed before ln1 writes R6
  unsigned short* Wbf  = (unsigned short*)(PA2 + C16S);  // 166K bf16 elems (332KB)
  const unsigned short* W_qkv  = Wbf + 0;
  const unsigned short* W_c1   = Wbf + 27648;
  const unsigned short* W_c2   = Wbf + 46080;
  const unsigned short* W_c3   = Wbf + 64512;
  const unsigned short* W_proj = Wbf + 82944;
  const unsigned short* W_ffn1 = Wbf + 92160;
  const unsigned short* W_ffn2 = Wbf + 110592;
  const unsigned short* W_fin  = Wbf + 129024;

  // weight preps
  wprep_k<<<dim3(144, 8), 256, 0, stream>>>(qkv_w, cb_c1_pw, cb_c2_pw, cb_c3_w,
                                            proj_w, ffn_w1, ffn_w2, out_w, Wbf);
  ada_prep_k<<<dim3(120, 16), 256, 0, stream>>>(ada_w, Apre);

  // conv branch
  transpose_in_k<<<dim3(HW_/32, 6, NB), 256, 0, stream>>>(x, xcl);
  ln_k<<<ST/4, 256, 0, stream>>>(xcl, 192, 0, cb_ln_g, cb_ln_b, R4, nullptr);
  conv_mfma_k<false,false,false,false,false><<<dim3(ST/128, 3), 256, 0, stream>>>(R4, nullptr, 96, W_c1, nullptr, nullptr, 0, R1, 192, 96, 192);
  dw3x3_k<false,false><<<(ST*48)/256, 256, 0, stream>>>(R1, cb_c1_dw, nullptr, R2, 192);
  conv_mfma_k<false,false,false,false,false><<<dim3(ST/128, 3), 256, 0, stream>>>(R4, nullptr, 96, W_c2, nullptr, nullptr, 0, R1, 192, 96, 192);
  conv1x1_k<1,false,false,false><<<dim3(ST/128, 1), 256, 0, stream>>>(R1, nullptr, 192, ada_p1_w, ada_p1_b, nullptr, 0, PA1, 16, 192, 16);
  p2conv_k<<<ST/256, 256, 0, stream>>>(PA1, ada_p2_w, ada_p2_b, PA2);
  adaconv_mfma_k<<<dim3(36, 16, NB), 256, 0, stream>>>(R1, PA2, Apre, B2b);
  conv_mfma_k<true,false,false,false,true><<<dim3(ST/128, 2), 256, 0, stream>>>(R2, B2b, 192, W_c3, nullptr, xcl, 192, R4, 96, 192, 96);

  // transformer branch
  ln_k<<<ST/4, 256, 0, stream>>>(xcl, 192, 96, ln1_g, ln1_b, R6, XT);
  conv_mfma_k<false,false,false,true,false><<<dim3(ST/128, 5), 256, 0, stream>>>(R6, nullptr, 96, W_qkv, qkv_b, nullptr, 0, QKV, 288, 96, 288);
  attn_k<<<dim3(144, 3, NB), 64, 0, stream>>>(QKV, rel_pos, R6);
  conv_mfma_k<false,false,false,true,true><<<dim3(ST/128, 2), 256, 0, stream>>>(R6, nullptr, 96, W_proj, proj_b, XT, 96, XT, 96, 96, 96);
  ln_k<<<ST/4, 256, 0, stream>>>(XT, 96, 0, ln2_g, ln2_b, R6, nullptr);
  conv_mfma_k<false,false,false,true,false><<<dim3(ST/128, 3), 256, 0, stream>>>(R6, nullptr, 96, W_ffn1, ffn_b1, nullptr, 0, R1, 192, 96, 192);
  dw3x3_k<true,true><<<(ST*48)/256, 256, 0, stream>>>(R1, ffn_dw, ffn_db, R2, 192);
  conv_mfma_k<false,false,false,true,true><<<dim3(ST/128, 2), 256, 0, stream>>>(R2, nullptr, 192, W_ffn2, ffn_b2, XT, 96, XT, 96, 192, 96);

  // fuse: out = x + conv1x1(concat(convout, xt), out_w) + out_b  (channel-first)
  conv_mfma_k<false,true,true,true,true><<<dim3(ST/128, 3), 256, 0, stream>>>(R4, XT, 96, W_fin, out_b, x, 0, (float*)d_out, 0, 192, 192);
}

// Round 5
// 269.027 us; speedup vs baseline: 1.8346x; 1.0877x over previous
//
#include <hip/hip_runtime.h>
#include <math.h>

#define HW_ 9216
#define IH 96
#define IW 96
#define NB 2
#define ST (NB*HW_)   // 18432 pixels total

typedef __attribute__((ext_vector_type(8))) short bf16x8;
typedef __attribute__((ext_vector_type(4))) float f32x4;

__device__ __forceinline__ float gelu_f(float v){
  return 0.5f*v*(1.0f+erff(v*0.70710678118654752440f));
}

__device__ __forceinline__ unsigned short f2bf(float f){
  unsigned u = __float_as_uint(f);
  unsigned r = (u + 0x7FFF + ((u>>16)&1)) >> 16;
  return (unsigned short)r;
}

// ---------------------------------------------------------------------------
// K1: NCHW -> NHWC transpose (x (B,192,HW) -> xcl (B,HW,192))
// ---------------------------------------------------------------------------
__global__ __launch_bounds__(256) void transpose_in_k(const float* __restrict__ x,
                                                      float* __restrict__ xcl){
  __shared__ float t[32][33];
  int b  = blockIdx.z;
  int c0 = blockIdx.y << 5;
  int p0 = blockIdx.x << 5;
  int tx = threadIdx.x & 31;
  int ty = threadIdx.x >> 5;   // 0..7
  const float* xb = x + (size_t)b*192*HW_;
  #pragma unroll
  for (int k=0;k<4;k++){
    int c = ty + k*8;
    t[c][tx] = xb[(size_t)(c0+c)*HW_ + p0 + tx];
  }
  __syncthreads();
  float* ob = xcl + (size_t)b*HW_*192;
  #pragma unroll
  for (int k=0;k<4;k++){
    int p = ty + k*8;
    ob[(size_t)(p0+p)*192 + c0 + tx] = t[tx][p];
  }
}

// ---------------------------------------------------------------------------
// K2: LayerNorm over 96 channels (1 wave per pixel).
// ---------------------------------------------------------------------------
__global__ __launch_bounds__(256) void ln_k(const float* __restrict__ in, int istride, int ioff,
                                            const float* __restrict__ gam, const float* __restrict__ bet,
                                            float* __restrict__ out, float* __restrict__ raw){
  int lane = threadIdx.x & 63;
  int wv   = threadIdx.x >> 6;
  int p    = (blockIdx.x << 2) + wv;
  const float* row = in + (size_t)p*istride + ioff;
  float v0 = row[lane];
  float v1 = (lane < 32) ? row[64+lane] : 0.0f;
  float s = v0 + v1;
  #pragma unroll
  for (int o=32;o;o>>=1) s += __shfl_xor(s,o);
  float mu = s * (1.0f/96.0f);
  float d0 = v0 - mu;
  float d1 = v1 - mu;
  float qv = d0*d0 + ((lane<32)? d1*d1 : 0.0f);
  #pragma unroll
  for (int o=32;o;o>>=1) qv += __shfl_xor(qv,o);
  float rstd = rsqrtf(qv*(1.0f/96.0f) + 1e-5f);
  float* orow = out + (size_t)p*96;
  orow[lane] = d0*rstd*gam[lane] + bet[lane];
  if (lane < 32) orow[64+lane] = d1*rstd*gam[64+lane] + bet[64+lane];
  if (raw){
    float* rrow = raw + (size_t)p*96;
    rrow[lane] = v0;
    if (lane < 32) rrow[64+lane] = v1;
  }
}

// ---------------------------------------------------------------------------
// K3b: bf16-MFMA conv1x1.  Block: 128 px x 64 couts, 4 waves (2M x 2N).
// ACT=1: relu in epilogue (non-FINAL path).
// ---------------------------------------------------------------------------
template<int ACT, bool PROD, bool CONCAT, bool FINAL, bool HASB, bool HASR>
__global__ __launch_bounds__(256) void conv_mfma_k(
    const float* __restrict__ in1, const float* __restrict__ in2, int istride,
    const unsigned short* __restrict__ wbf, const float* __restrict__ bias,
    const float* __restrict__ res, int rstride,
    float* __restrict__ out, int ostride, int Cin, int Cout)
{
  __shared__ __align__(16) unsigned char smem[39936];
  unsigned char* actl = smem;          // [128][208B]
  unsigned char* wl   = smem + 26624;  // [64][208B]
  const int tid=threadIdx.x, lane=tid&63, wv=tid>>6;
  const int lr=lane&15, g4=lane>>4, wm=wv>>1, wn=wv&1;
  const int p0=blockIdx.x<<7, co0=blockIdx.y<<6;

  f32x4 acc[2][4];
  #pragma unroll
  for (int m=0;m<2;m++)
    #pragma unroll
    for (int n=0;n<4;n++) acc[m][n]=(f32x4){0.f,0.f,0.f,0.f};

  for (int kc=0; kc<Cin; kc+=96){
    {
      const int row=tid>>1, half=tid&1;
      const float* src = (CONCAT && kc) ? in2 : in1;
      const int koff = CONCAT ? 0 : kc;
      const float* rp = src + (size_t)(p0+row)*istride + koff + half*48;
      const float* rp2 = PROD ? (in2 + (size_t)(p0+row)*istride + koff + half*48) : nullptr;
      #pragma unroll
      for (int s=0;s<6;s++){
        float4 a=*(const float4*)(rp+s*8), b=*(const float4*)(rp+s*8+4);
        if (PROD){
          const float4 c=*(const float4*)(rp2+s*8), d=*(const float4*)(rp2+s*8+4);
          a.x*=c.x; a.y*=c.y; a.z*=c.z; a.w*=c.w;
          b.x*=d.x; b.y*=d.y; b.z*=d.z; b.w*=d.w;
        }
        uint4 pk;
        pk.x=(unsigned)f2bf(a.x)|((unsigned)f2bf(a.y)<<16);
        pk.y=(unsigned)f2bf(a.z)|((unsigned)f2bf(a.w)<<16);
        pk.z=(unsigned)f2bf(b.x)|((unsigned)f2bf(b.y)<<16);
        pk.w=(unsigned)f2bf(b.z)|((unsigned)f2bf(b.w)<<16);
        *(uint4*)(actl + row*208 + (half*6+s)*16) = pk;
      }
    }
    {
      const int row=tid&63, grp=tid>>6;
      const int co=co0+row;
      const unsigned short* wr = wbf + (size_t)co*Cin + kc;
      #pragma unroll
      for (int s=0;s<3;s++){
        int sl=grp*3+s;
        uint4 v={0,0,0,0};
        if (co<Cout) v=*(const uint4*)(wr + sl*8);
        *(uint4*)(wl + row*208 + sl*16)=v;
      }
    }
    __syncthreads();
    #pragma unroll
    for (int ks=0;ks<3;ks++){
      const int sl=ks*4+g4;
      bf16x8 afr[2], bfr[4];
      #pragma unroll
      for (int m=0;m<2;m++) afr[m]=*(const bf16x8*)(wl + ((wm*2+m)*16+lr)*208 + sl*16);
      #pragma unroll
      for (int n=0;n<4;n++) bfr[n]=*(const bf16x8*)(actl + (wn*64+n*16+lr)*208 + sl*16);
      #pragma unroll
      for (int m=0;m<2;m++)
        #pragma unroll
        for (int n=0;n<4;n++)
          acc[m][n]=__builtin_amdgcn_mfma_f32_16x16x32_bf16(afr[m], bfr[n], acc[m][n],0,0,0);
    }
    __syncthreads();
  }

  if (FINAL){
    #pragma unroll
    for (int m=0;m<2;m++){
      const int cb=co0+(wm*2+m)*16+(g4<<2);
      float4 bv = make_float4(0.f,0.f,0.f,0.f);
      if (HASB) bv = *(const float4*)(bias+cb);
      #pragma unroll
      for (int n=0;n<4;n++){
        const int p=p0+wn*64+n*16+lr;
        const int bb=p/HW_, hw=p-bb*HW_;
        const float av[4]={acc[m][n].x,acc[m][n].y,acc[m][n].z,acc[m][n].w};
        const float bvv[4]={bv.x,bv.y,bv.z,bv.w};
        #pragma unroll
        for (int j=0;j<4;j++){
          size_t oi=((size_t)bb*192+cb+j)*HW_+hw;
          out[oi]=av[j]+bvv[j]+res[oi];
        }
      }
    }
    return;
  }
  float* lt=(float*)smem;
  #pragma unroll
  for (int m=0;m<2;m++)
    #pragma unroll
    for (int n=0;n<4;n++){
      int px=wn*64+n*16+lr;
      int c=(wm*2+m)*16+(g4<<2);
      *(f32x4*)&lt[px*68+c]=acc[m][n];
    }
  __syncthreads();
  {
    const int pr=tid>>1, half=tid&1;
    const int p=p0+pr;
    #pragma unroll
    for (int s=0;s<8;s++){
      int cl=half*32+s*4;
      int co=co0+cl;
      if (co<Cout){
        float4 v=*(float4*)&lt[pr*68+cl];
        if (HASB){ const float4 bv=*(const float4*)(bias+co); v.x+=bv.x;v.y+=bv.y;v.z+=bv.z;v.w+=bv.w; }
        if (ACT==1){
          v.x=fmaxf(v.x,0.f); v.y=fmaxf(v.y,0.f); v.z=fmaxf(v.z,0.f); v.w=fmaxf(v.w,0.f);
        }
        if (HASR){ const float4 rv=*(const float4*)(res+(size_t)p*rstride+co); v.x+=rv.x;v.y+=rv.y;v.z+=rv.z;v.w+=rv.w; }
        *(float4*)(out+(size_t)p*ostride+co)=v;
      }
    }
  }
}

// ---------------------------------------------------------------------------
// K4: depthwise 3x3 (channel-last), input stride param, optional bias+gelu
// ---------------------------------------------------------------------------
template<bool HASB, bool DOGELU>
__global__ __launch_bounds__(256) void dw3x3_k(const float* __restrict__ in, int istride,
                                               const float* __restrict__ w,
                                               const float* __restrict__ bias,
                                               float* __restrict__ out, int C){
  int t = blockIdx.x*256 + threadIdx.x;
  int cg = C >> 2;
  int p = t / cg;
  if (p >= ST) return;
  int c4 = (t - p*cg) << 2;
  int bb = p / HW_, hw = p - bb*HW_;
  int hy = hw / IW, wx = hw - hy*IW;
  float w0[9], w1[9], w2[9], w3[9];
  #pragma unroll
  for (int tp=0;tp<9;tp++){
    w0[tp]=w[(c4+0)*9+tp]; w1[tp]=w[(c4+1)*9+tp]; w2[tp]=w[(c4+2)*9+tp]; w3[tp]=w[(c4+3)*9+tp];
  }
  float ax=0.f, ay=0.f, az=0.f, aw=0.f;
  #pragma unroll
  for (int i=0;i<3;i++){
    int y = hy+i-1;
    if ((unsigned)y >= IH) continue;
    #pragma unroll
    for (int j=0;j<3;j++){
      int x2 = wx+j-1;
      if ((unsigned)x2 >= IW) continue;
      const float4 v = *(const float4*)(in + ((size_t)bb*HW_ + y*IW + x2)*istride + c4);
      int tp=i*3+j;
      ax += v.x*w0[tp]; ay += v.y*w1[tp]; az += v.z*w2[tp]; aw += v.w*w3[tp];
    }
  }
  if (HASB){ ax+=bias[c4]; ay+=bias[c4+1]; az+=bias[c4+2]; aw+=bias[c4+3]; }
  if (DOGELU){ ax=gelu_f(ax); ay=gelu_f(ay); az=gelu_f(az); aw=gelu_f(aw); }
  *(float4*)(out + (size_t)p*C + c4) = make_float4(ax,ay,az,aw);
}

// ---------------------------------------------------------------------------
// K5: full 3x3 conv 16->16 (para branch). 4 threads per pixel (4 couts each).
// ---------------------------------------------------------------------------
__global__ __launch_bounds__(256) void p2conv_k(const float* __restrict__ in, const float* __restrict__ w,
                                                const float* __restrict__ bias, float* __restrict__ out){
  __shared__ float ws[2304];
  int tid = threadIdx.x;
  for (int i=tid;i<2304;i+=256) ws[i]=w[i];
  __syncthreads();
  int gidx = blockIdx.x*256 + tid;
  int p = gidx >> 2, qq = gidx & 3;
  int bb = p / HW_, hw = p - bb*HW_;
  int hy = hw / IW, wx = hw - hy*IW;
  const int cb = qq<<2;
  float a0=bias[cb], a1=bias[cb+1], a2=bias[cb+2], a3=bias[cb+3];
  #pragma unroll
  for (int i=0;i<3;i++){
    int y=hy+i-1; if ((unsigned)y>=IH) continue;
    #pragma unroll
    for (int j=0;j<3;j++){
      int x2=wx+j-1; if ((unsigned)x2>=IW) continue;
      int tap=i*3+j;
      const float* prow = in + ((size_t)bb*HW_ + y*IW + x2)*16;
      #pragma unroll
      for (int ci=0;ci<16;ci++){
        float v = prow[ci];
        a0 += ws[(cb+0)*144 + ci*9 + tap]*v;
        a1 += ws[(cb+1)*144 + ci*9 + tap]*v;
        a2 += ws[(cb+2)*144 + ci*9 + tap]*v;
        a3 += ws[(cb+3)*144 + ci*9 + tap]*v;
      }
    }
  }
  *(float4*)(out + (size_t)p*16 + cb) = make_float4(a0,a1,a2,a3);
}

// ---------------------------------------------------------------------------
// K6a: prep ada_w -> bf16 Amat[g][row=o*16+r][k'=tap*16+cl], K'=160.
// ---------------------------------------------------------------------------
__global__ __launch_bounds__(256) void ada_prep_k(const float* __restrict__ aw,
                                                  unsigned short* __restrict__ apre){
  int g = blockIdx.y;
  int e = blockIdx.x*256 + threadIdx.x;    // 0..30719
  int row = e / 160, kp = e - row*160;
  int tap = kp >> 4, cl = kp & 15;
  int o = row >> 4, r = row & 15;
  float v = 0.f;
  if (tap < 9 && cl < 12)
    v = aw[(((size_t)(g*12+o)*108) + cl*9 + tap)*16 + r];
  apre[(size_t)g*30720 + e] = f2bf(v);
}

// ---------------------------------------------------------------------------
// K6c: fp32 -> bf16 weight prep (9 matrices incl. p1)
// ---------------------------------------------------------------------------
__global__ __launch_bounds__(256) void wprep_k(
    const float* __restrict__ s0, const float* __restrict__ s1,
    const float* __restrict__ s2, const float* __restrict__ s3,
    const float* __restrict__ s4, const float* __restrict__ s5,
    const float* __restrict__ s6, const float* __restrict__ s7,
    const float* __restrict__ s8,
    unsigned short* __restrict__ dst)
{
  const int sz[9]  = {27648,18432,18432,18432,9216,18432,18432,36864,3072};
  const int off[9] = {0,27648,46080,64512,82944,92160,110592,129024,165888};
  int m = blockIdx.y;
  int i = blockIdx.x*256 + threadIdx.x;
  const float* s = (m==0)?s0:(m==1)?s1:(m==2)?s2:(m==3)?s3:(m==4)?s4:(m==5)?s5:(m==6)?s6:(m==7)?s7:s8;
  if (i < sz[m]) dst[off[m]+i] = f2bf(s[i]);
}

// ---------------------------------------------------------------------------
// K6b v4: adaconv MFMA. Block: (b, g, 16x8 region) = 2304 blocks.
// Halo 18x10 px bf16 (48B slots); para both subs staged upfront; direct
// scatter epilogue; single barrier total. LDS ~18.9KB.
// x2 has row stride 384 (c2-out region of the fused c1c2 buffer).
// ---------------------------------------------------------------------------
__global__ __launch_bounds__(256) void adaconv_mfma_k(
    const float* __restrict__ x2, const float* __restrict__ para,
    const unsigned short* __restrict__ apre, float* __restrict__ outb2)
{
  __shared__ __align__(16) unsigned char smem[18880];
  unsigned char* HB = smem;             // 18 rows x 10 cols x 48B = 8640
  float* PS = (float*)(smem + 8640);    // [2 sub][64 px][20] f32 = 10240

  const int tid=threadIdx.x, lane=tid&63, wv=tid>>6;
  const int lr=lane&15, g4=lane>>4;
  const int hi=(lane>>5)&1, lo16=(lane>>4)&1;
  const int b=blockIdx.z, g=blockIdx.y, reg=blockIdx.x;
  const int rh=(reg/12)<<4, rw=(reg%12)<<3;    // 6x12 regions of 16x8 px

  // --- A fragments (tap-major K'=160), 15 x 16B per lane from L2 ---
  bf16x8 af[3][5];
  {
    const unsigned short* ag = apre + (size_t)g*30720;
    #pragma unroll
    for (int oo=0;oo<3;oo++){
      const int row=(wv*3+oo)*16+lr;
      #pragma unroll
      for (int ks=0;ks<5;ks++)
        af[oo][ks] = *(const bf16x8*)(ag + row*160 + ks*32 + g4*8);
    }
  }
  // --- stage halo: 18x10 px, 12 ch -> bf16 in 48B slots ---
  if (tid < 180){
    int hy = tid/10, hx = tid - hy*10;
    int gy = rh+hy-1, gx = rw+hx-1;
    float4 a=make_float4(0,0,0,0), c=a, d=a;
    if ((unsigned)gy<IH && (unsigned)gx<IW){
      const float* src = x2 + ((size_t)b*HW_ + gy*IW + gx)*384 + g*12;
      a=*(const float4*)(src); c=*(const float4*)(src+4); d=*(const float4*)(src+8);
    }
    uint4 lov, hiv;
    lov.x=(unsigned)f2bf(a.x)|((unsigned)f2bf(a.y)<<16);
    lov.y=(unsigned)f2bf(a.z)|((unsigned)f2bf(a.w)<<16);
    lov.z=(unsigned)f2bf(c.x)|((unsigned)f2bf(c.y)<<16);
    lov.w=(unsigned)f2bf(c.z)|((unsigned)f2bf(c.w)<<16);
    hiv.x=(unsigned)f2bf(d.x)|((unsigned)f2bf(d.y)<<16);
    hiv.y=(unsigned)f2bf(d.z)|((unsigned)f2bf(d.w)<<16);
    hiv.z=0; hiv.w=0;
    *(uint4*)(HB + tid*48)      = lov;
    *(uint4*)(HB + tid*48 + 16) = hiv;
  }
  // --- stage para for both subtiles ---
  #pragma unroll
  for (int it=0; it<2; ++it){
    int idx = tid + (it<<8);          // 0..511
    int sub = idx >> 8;
    int p = (idx>>2)&63, q = idx&3;
    int gy = rh + (sub<<3) + (p>>3), gx = rw + (p&7);
    float4 v = *(const float4*)(para + ((size_t)b*HW_+gy*IW+gx)*16 + q*4);
    *(float4*)&PS[sub*1280 + p*20 + q*4] = v;
  }
  __syncthreads();

  // per-lane tap offsets (halo width 10): tap = ks*2+hi, tap9 -> clamp 8
  int tapoff[5];
  tapoff[0] = hi ? 48   : 0;      // (0,1) / (0,0)
  tapoff[1] = hi ? 480  : 96;     // (1,0) / (0,2)
  tapoff[2] = hi ? 576  : 528;    // (1,2) / (1,1)
  tapoff[3] = hi ? 1008 : 960;    // (2,1) / (2,0)
  tapoff[4] = 1056;               // (2,2) both (A pad zero for tap9)

  #pragma unroll
  for (int sub=0; sub<2; ++sub){
    const int sy = sub<<3;
    const int base0 = ((sy + (lr>>3))*10 + (lr&7))*48 + lo16*16;

    f32x4 acc[3][4];
    #pragma unroll
    for (int oo=0;oo<3;oo++)
      #pragma unroll
      for (int n=0;n<4;n++) acc[oo][n]=(f32x4){0.f,0.f,0.f,0.f};

    #pragma unroll
    for (int ks=0;ks<5;ks++){
      bf16x8 bfr[4];
      #pragma unroll
      for (int n=0;n<4;n++)
        bfr[n] = *(const bf16x8*)(HB + base0 + n*960 + tapoff[ks]);
      #pragma unroll
      for (int oo=0;oo<3;oo++)
        #pragma unroll
        for (int n=0;n<4;n++)
          acc[oo][n]=__builtin_amdgcn_mfma_f32_16x16x32_bf16(af[oo][ks], bfr[n], acc[oo][n],0,0,0);
    }

    // epilogue: r-reduce with para -> gelu -> scatter store
    const float* ps = &PS[sub*1280];
    #pragma unroll
    for (int oo=0;oo<3;oo++){
      const int o=wv*3+oo;
      #pragma unroll
      for (int n=0;n<4;n++){
        const int p=(n<<4)+lr;
        const f32x4 prv = *(const f32x4*)&ps[p*20+(g4<<2)];
        float s=acc[oo][n].x*prv.x+acc[oo][n].y*prv.y+acc[oo][n].z*prv.z+acc[oo][n].w*prv.w;
        s += __shfl_xor(s,16); s += __shfl_xor(s,32);
        if (g4==n){
          const int py=p>>3, px=p&7;
          outb2[((size_t)b*HW_+(rh+sy+py)*IW+(rw+px))*192 + g*12 + o] = gelu_f(s);
        }
      }
    }
  }
}

// ---------------------------------------------------------------------------
// K7: shifted-window attention, 1 wave per (window, head).
// ---------------------------------------------------------------------------
__global__ __launch_bounds__(64) void attn_k(const float* __restrict__ qkv,
                                             const float* __restrict__ relpos,
                                             float* __restrict__ outa){
  __shared__ float k_s[2048];
  __shared__ float v_s[2048];
  __shared__ float rel_s[225];
  const int win = blockIdx.x, head = blockIdx.y, b = blockIdx.z;
  const int wi = win/12, wj = win%12;
  const int lane = threadIdx.x;
  for (int i=lane;i<225;i+=64) rel_s[i] = relpos[i*3+head];
  const int pi = lane>>3, pj = lane&7;
  const int hr = wi*8+pi, wr = wj*8+pj;
  const int sh = (hr+4)%96, sw = (wr+4)%96;
  const size_t pix = (size_t)b*HW_ + sh*96 + sw;
  const float* qrow = qkv + pix*288 + head*32;
  const float* krow = qkv + pix*288 + 96 + head*32;
  const float* vrow = qkv + pix*288 + 192 + head*32;
  const float SC = 0.17677669529663687f; // 1/sqrt(32)
  float q[32];
  #pragma unroll
  for (int i=0;i<32;i+=4){
    const float4 t4 = *(const float4*)(qrow+i);
    q[i]=t4.x*SC; q[i+1]=t4.y*SC; q[i+2]=t4.z*SC; q[i+3]=t4.w*SC;
  }
  #pragma unroll
  for (int i=0;i<32;i+=4){
    *(float4*)&k_s[(lane<<5)+i] = *(const float4*)(krow+i);
    *(float4*)&v_s[(lane<<5)+i] = *(const float4*)(vrow+i);
  }
  __syncthreads();
  const bool mi = (wi==11), mj = (wj==11);
  float sc[64];
  #pragma unroll
  for (int qq=0; qq<64; qq++){
    const float4* kr4 = (const float4*)&k_s[qq<<5];
    float s = 0.f;
    #pragma unroll
    for (int i=0;i<8;i++){
      const float4 kv = kr4[i];
      s += q[4*i]*kv.x + q[4*i+1]*kv.y + q[4*i+2]*kv.z + q[4*i+3]*kv.w;
    }
    const int qi = qq>>3, qj = qq&7;
    s += rel_s[(pi-qi+7)*15 + (pj-qj+7)];
    const bool msk = (mi && ((pi<4)!=(qi<4))) || (mj && ((pj<4)!=(qj<4)));
    sc[qq] = msk ? -1e30f : s;
  }
  float m = sc[0];
  #pragma unroll
  for (int qq=1;qq<64;qq++) m = fmaxf(m, sc[qq]);
  float sum = 0.f;
  #pragma unroll
  for (int qq=0;qq<64;qq++){ float e = __expf(sc[qq]-m); sc[qq]=e; sum+=e; }
  const float inv = 1.f/sum;
  float acc[32];
  #pragma unroll
  for (int i=0;i<32;i++) acc[i]=0.f;
  #pragma unroll
  for (int qq=0;qq<64;qq++){
    const float a = sc[qq]*inv;
    const float4* vr4 = (const float4*)&v_s[qq<<5];
    #pragma unroll
    for (int i=0;i<8;i++){
      const float4 vv = vr4[i];
      acc[4*i]+=a*vv.x; acc[4*i+1]+=a*vv.y; acc[4*i+2]+=a*vv.z; acc[4*i+3]+=a*vv.w;
    }
  }
  float* orow = outa + pix*96 + head*32;
  #pragma unroll
  for (int i=0;i<32;i+=4)
    *(float4*)(orow+i) = make_float4(acc[i],acc[i+1],acc[i+2],acc[i+3]);
}

// ---------------------------------------------------------------------------
extern "C" void kernel_launch(void* const* d_in, const int* in_sizes, int n_in,
                              void* d_out, int out_size, void* d_ws, size_t ws_size,
                              hipStream_t stream)
{
  (void)in_sizes; (void)n_in; (void)out_size; (void)ws_size;
  const float* x        = (const float*)d_in[0];
  const float* cb_ln_g  = (const float*)d_in[1];
  const float* cb_ln_b  = (const float*)d_in[2];
  const float* cb_c1_pw = (const float*)d_in[3];
  const float* cb_c1_dw = (const float*)d_in[4];
  const float* cb_c2_pw = (const float*)d_in[5];
  const float* ada_w    = (const float*)d_in[6];
  const float* ada_p1_w = (const float*)d_in[7];
  const float* ada_p1_b = (const float*)d_in[8];
  const float* ada_p2_w = (const float*)d_in[9];
  const float* ada_p2_b = (const float*)d_in[10];
  const float* cb_c3_w  = (const float*)d_in[11];
  const float* ln1_g    = (const float*)d_in[12];
  const float* ln1_b    = (const float*)d_in[13];
  const float* qkv_w    = (const float*)d_in[14];
  const float* qkv_b    = (const float*)d_in[15];
  const float* rel_pos  = (const float*)d_in[16];
  const float* proj_w   = (const float*)d_in[17];
  const float* proj_b   = (const float*)d_in[18];
  const float* ln2_g    = (const float*)d_in[19];
  const float* ln2_b    = (const float*)d_in[20];
  const float* ffn_w1   = (const float*)d_in[21];
  const float* ffn_b1   = (const float*)d_in[22];
  const float* ffn_dw   = (const float*)d_in[23];
  const float* ffn_db   = (const float*)d_in[24];
  const float* ffn_w2   = (const float*)d_in[25];
  const float* ffn_b2   = (const float*)d_in[26];
  const float* out_w    = (const float*)d_in[27];
  const float* out_b    = (const float*)d_in[28];

  float* ws = (float*)d_ws;
  const size_t C192S = (size_t)ST*192;
  const size_t C96S  = (size_t)ST*96;
  const size_t C16S  = (size_t)ST*16;
  // A0: xcl (1)  A1: X12 (2, later QKV / dw2-out)  A2: DW (1, later R6+XT)
  // A3: B2b / ffn1-out (1)  A4: LNC / R4 (0.5)  + PA + weights
  float* xcl = ws;
  float* X12 = ws + C192S;
  float* DW  = ws + 3*C192S;
  float* A3  = ws + 4*C192S;
  float* LNC = ws + 5*C192S;          // cb-ln out, then c3 out (R4)
  float* PA1 = LNC + C96S;
  float* PA2 = PA1 + C16S;
  unsigned short* Wbf  = (unsigned short*)(PA2 + C16S);   // 168960 bf16
  unsigned short* Apre = Wbf + 168960;                    // 491520 bf16
  float* QKV = X12;
  float* R6  = DW;             // after c3: ln1 out / attn out / ln2 out
  float* XT  = DW + C96S;      // transformer residual stream
  float* R4  = LNC;            // conv branch output
  float* FF1 = A3;             // ffn1 out (after B2b dead)
  float* DWO = X12;            // dw2 out (after QKV dead)
  float* B2b = A3;

  const unsigned short* W_c12  = Wbf + 27648;   // c1 rows then c2 rows: [384][96]
  const unsigned short* W_qkv  = Wbf + 0;
  const unsigned short* W_c3   = Wbf + 64512;
  const unsigned short* W_proj = Wbf + 82944;
  const unsigned short* W_ffn1 = Wbf + 92160;
  const unsigned short* W_ffn2 = Wbf + 110592;
  const unsigned short* W_fin  = Wbf + 129024;
  const unsigned short* W_p1   = Wbf + 165888;

  // weight preps
  wprep_k<<<dim3(144, 9), 256, 0, stream>>>(qkv_w, cb_c1_pw, cb_c2_pw, cb_c3_w,
                                            proj_w, ffn_w1, ffn_w2, out_w, ada_p1_w, Wbf);
  ada_prep_k<<<dim3(120, 16), 256, 0, stream>>>(ada_w, Apre);

  // conv branch
  transpose_in_k<<<dim3(HW_/32, 6, NB), 256, 0, stream>>>(x, xcl);
  ln_k<<<ST/4, 256, 0, stream>>>(xcl, 192, 0, cb_ln_g, cb_ln_b, LNC, nullptr);
  // fused c1+c2: 96 -> 384 (rows 0-191 = c1, 192-383 = c2)
  conv_mfma_k<0,false,false,false,false,false><<<dim3(ST/128, 6), 256, 0, stream>>>(LNC, nullptr, 96, W_c12, nullptr, nullptr, 0, X12, 384, 96, 384);
  dw3x3_k<false,false><<<(ST*48)/256, 256, 0, stream>>>(X12, 384, cb_c1_dw, nullptr, DW, 192);
  conv_mfma_k<1,false,false,false,true,false><<<dim3(ST/128, 1), 256, 0, stream>>>(X12+192, nullptr, 384, W_p1, ada_p1_b, nullptr, 0, PA1, 16, 192, 16);
  p2conv_k<<<(ST*4)/256, 256, 0, stream>>>(PA1, ada_p2_w, ada_p2_b, PA2);
  adaconv_mfma_k<<<dim3(72, 16, NB), 256, 0, stream>>>(X12+192, PA2, Apre, B2b);
  conv_mfma_k<0,true,false,false,false,true><<<dim3(ST/128, 2), 256, 0, stream>>>(DW, B2b, 192, W_c3, nullptr, xcl, 192, R4, 96, 192, 96);

  // transformer branch
  ln_k<<<ST/4, 256, 0, stream>>>(xcl, 192, 96, ln1_g, ln1_b, R6, XT);
  conv_mfma_k<0,false,false,false,true,false><<<dim3(ST/128, 5), 256, 0, stream>>>(R6, nullptr, 96, W_qkv, qkv_b, nullptr, 0, QKV, 288, 96, 288);
  attn_k<<<dim3(144, 3, NB), 64, 0, stream>>>(QKV, rel_pos, R6);
  conv_mfma_k<0,false,false,false,true,true><<<dim3(ST/128, 2), 256, 0, stream>>>(R6, nullptr, 96, W_proj, proj_b, XT, 96, XT, 96, 96, 96);
  ln_k<<<ST/4, 256, 0, stream>>>(XT, 96, 0, ln2_g, ln2_b, R6, nullptr);
  conv_mfma_k<0,false,false,false,true,false><<<dim3(ST/128, 3), 256, 0, stream>>>(R6, nullptr, 96, W_ffn1, ffn_b1, nullptr, 0, FF1, 192, 96, 192);
  dw3x3_k<true,true><<<(ST*48)/256, 256, 0, stream>>>(FF1, 192, ffn_dw, ffn_db, DWO, 192);
  conv_mfma_k<0,false,false,false,true,true><<<dim3(ST/128, 2), 256, 0, stream>>>(DWO, nullptr, 192, W_ffn2, ffn_b2, XT, 96, XT, 96, 192, 96);

  // fuse: out = x + conv1x1(concat(convout, xt), out_w) + out_b  (channel-first)
  conv_mfma_k<0,false,true,true,true,true><<<dim3(ST/128, 3), 256, 0, stream>>>(R4, XT, 96, W_fin, out_b, x, 0, (float*)d_out, 0, 192, 192);
}

// Round 6
// 264.088 us; speedup vs baseline: 1.8689x; 1.0187x over previous
//
#include <hip/hip_runtime.h>
#include <math.h>

#define HW_ 9216
#define IH 96
#define IW 96
#define NB 2
#define ST (NB*HW_)   // 18432 pixels total

typedef __attribute__((ext_vector_type(8))) short bf16x8;
typedef __attribute__((ext_vector_type(4))) float f32x4;
typedef unsigned short u16;

__device__ __forceinline__ float gelu_f(float v){
  return 0.5f*v*(1.0f+erff(v*0.70710678118654752440f));
}
__device__ __forceinline__ unsigned f2bf(float f){
  unsigned u = __float_as_uint(f);
  return (u + 0x7FFF + ((u>>16)&1)) >> 16;
}
__device__ __forceinline__ float bfl(unsigned u){ return __uint_as_float(u<<16); }
__device__ __forceinline__ float bfh(unsigned u){ return __uint_as_float(u & 0xffff0000u); }

// ---------------------------------------------------------------------------
// K1: NCHW -> NHWC transpose (x (B,192,HW) -> xcl (B,HW,192)) fp32
// ---------------------------------------------------------------------------
__global__ __launch_bounds__(256) void transpose_in_k(const float* __restrict__ x,
                                                      float* __restrict__ xcl){
  __shared__ float t[32][33];
  int b  = blockIdx.z;
  int c0 = blockIdx.y << 5;
  int p0 = blockIdx.x << 5;
  int tx = threadIdx.x & 31;
  int ty = threadIdx.x >> 5;
  const float* xb = x + (size_t)b*192*HW_;
  #pragma unroll
  for (int k=0;k<4;k++){
    int c = ty + k*8;
    t[c][tx] = xb[(size_t)(c0+c)*HW_ + p0 + tx];
  }
  __syncthreads();
  float* ob = xcl + (size_t)b*HW_*192;
  #pragma unroll
  for (int k=0;k<4;k++){
    int p = ty + k*8;
    ob[(size_t)(p0+p)*192 + c0 + tx] = t[tx][p];
  }
}

// ---------------------------------------------------------------------------
// K2: LayerNorm over 96 channels (1 wave per pixel). bf16 out; raw fp32 copy.
// ---------------------------------------------------------------------------
__global__ __launch_bounds__(256) void ln_k(const float* __restrict__ in, int istride, int ioff,
                                            const float* __restrict__ gam, const float* __restrict__ bet,
                                            u16* __restrict__ out, float* __restrict__ raw){
  int lane = threadIdx.x & 63;
  int wv   = threadIdx.x >> 6;
  int p    = (blockIdx.x << 2) + wv;
  const float* row = in + (size_t)p*istride + ioff;
  float v0 = row[lane];
  float v1 = (lane < 32) ? row[64+lane] : 0.0f;
  float s = v0 + v1;
  #pragma unroll
  for (int o=32;o;o>>=1) s += __shfl_xor(s,o);
  float mu = s * (1.0f/96.0f);
  float d0 = v0 - mu;
  float d1 = v1 - mu;
  float qv = d0*d0 + ((lane<32)? d1*d1 : 0.0f);
  #pragma unroll
  for (int o=32;o;o>>=1) qv += __shfl_xor(qv,o);
  float rstd = rsqrtf(qv*(1.0f/96.0f) + 1e-5f);
  u16* orow = out + (size_t)p*96;
  orow[lane] = (u16)f2bf(d0*rstd*gam[lane] + bet[lane]);
  if (lane < 32) orow[64+lane] = (u16)f2bf(d1*rstd*gam[64+lane] + bet[64+lane]);
  if (raw){
    float* rrow = raw + (size_t)p*96;
    rrow[lane] = v0;
    if (lane < 32) rrow[64+lane] = v1;
  }
}

// ---------------------------------------------------------------------------
// K3b: bf16-MFMA conv1x1.  Block: 128 px x 64 couts, 4 waves (2M x 2N).
// in1 = bf16 (pure-copy staging). CONCAT: chunk0 = in1 bf16, chunk1 = in2f f32.
// OUTBF: bf16 packed output.  FINAL: channel-first fp32 + NCHW residual.
// ---------------------------------------------------------------------------
template<int ACT, bool CONCAT, bool FINAL, bool HASB, bool HASR, bool OUTBF>
__global__ __launch_bounds__(256) void conv_mfma_k(
    const u16* __restrict__ in1, const float* __restrict__ in2f, int istride,
    const u16* __restrict__ wbf, const float* __restrict__ bias,
    const float* __restrict__ res, int rstride,
    void* __restrict__ out, int ostride, int Cin, int Cout)
{
  __shared__ __align__(16) unsigned char smem[39936];
  unsigned char* actl = smem;          // [128][208B]
  unsigned char* wl   = smem + 26624;  // [64][208B]
  const int tid=threadIdx.x, lane=tid&63, wv=tid>>6;
  const int lr=lane&15, g4=lane>>4, wm=wv>>1, wn=wv&1;
  const int p0=blockIdx.x<<7, co0=blockIdx.y<<6;

  f32x4 acc[2][4];
  #pragma unroll
  for (int m=0;m<2;m++)
    #pragma unroll
    for (int n=0;n<4;n++) acc[m][n]=(f32x4){0.f,0.f,0.f,0.f};

  for (int kc=0; kc<Cin; kc+=96){
    {
      const int row=tid>>1, half=tid&1;
      if (!CONCAT || kc==0){
        const u16* rp = in1 + (size_t)(p0+row)*istride + (CONCAT?0:kc) + half*48;
        #pragma unroll
        for (int s=0;s<6;s++)
          *(uint4*)(actl + row*208 + (half*6+s)*16) = *(const uint4*)(rp + s*8);
      } else {
        const float* rp = in2f + (size_t)(p0+row)*96 + half*48;
        #pragma unroll
        for (int s=0;s<6;s++){
          float4 a=*(const float4*)(rp+s*8), b=*(const float4*)(rp+s*8+4);
          uint4 pk;
          pk.x=f2bf(a.x)|(f2bf(a.y)<<16);
          pk.y=f2bf(a.z)|(f2bf(a.w)<<16);
          pk.z=f2bf(b.x)|(f2bf(b.y)<<16);
          pk.w=f2bf(b.z)|(f2bf(b.w)<<16);
          *(uint4*)(actl + row*208 + (half*6+s)*16) = pk;
        }
      }
    }
    {
      const int row=tid&63, grp=tid>>6;
      const int co=co0+row;
      const u16* wr = wbf + (size_t)co*Cin + kc;
      #pragma unroll
      for (int s=0;s<3;s++){
        int sl=grp*3+s;
        uint4 v={0,0,0,0};
        if (co<Cout) v=*(const uint4*)(wr + sl*8);
        *(uint4*)(wl + row*208 + sl*16)=v;
      }
    }
    __syncthreads();
    #pragma unroll
    for (int ks=0;ks<3;ks++){
      const int sl=ks*4+g4;
      bf16x8 afr[2], bfr[4];
      #pragma unroll
      for (int m=0;m<2;m++) afr[m]=*(const bf16x8*)(wl + ((wm*2+m)*16+lr)*208 + sl*16);
      #pragma unroll
      for (int n=0;n<4;n++) bfr[n]=*(const bf16x8*)(actl + (wn*64+n*16+lr)*208 + sl*16);
      #pragma unroll
      for (int m=0;m<2;m++)
        #pragma unroll
        for (int n=0;n<4;n++)
          acc[m][n]=__builtin_amdgcn_mfma_f32_16x16x32_bf16(afr[m], bfr[n], acc[m][n],0,0,0);
    }
    __syncthreads();
  }

  if (FINAL){
    float* outf = (float*)out;
    #pragma unroll
    for (int m=0;m<2;m++){
      const int cb=co0+(wm*2+m)*16+(g4<<2);
      float4 bv = make_float4(0.f,0.f,0.f,0.f);
      if (HASB) bv = *(const float4*)(bias+cb);
      #pragma unroll
      for (int n=0;n<4;n++){
        const int p=p0+wn*64+n*16+lr;
        const int bb=p/HW_, hw=p-bb*HW_;
        const float av[4]={acc[m][n].x,acc[m][n].y,acc[m][n].z,acc[m][n].w};
        const float bvv[4]={bv.x,bv.y,bv.z,bv.w};
        #pragma unroll
        for (int j=0;j<4;j++){
          size_t oi=((size_t)bb*192+cb+j)*HW_+hw;
          outf[oi]=av[j]+bvv[j]+res[oi];
        }
      }
    }
    return;
  }
  float* lt=(float*)smem;
  #pragma unroll
  for (int m=0;m<2;m++)
    #pragma unroll
    for (int n=0;n<4;n++){
      int px=wn*64+n*16+lr;
      int c=(wm*2+m)*16+(g4<<2);
      *(f32x4*)&lt[px*68+c]=acc[m][n];
    }
  __syncthreads();
  {
    const int pr=tid>>1, half=tid&1;
    const int p=p0+pr;
    #pragma unroll
    for (int s=0;s<8;s++){
      int cl=half*32+s*4;
      int co=co0+cl;
      if (co<Cout){
        float4 v=*(float4*)&lt[pr*68+cl];
        if (HASB){ const float4 bv=*(const float4*)(bias+co); v.x+=bv.x;v.y+=bv.y;v.z+=bv.z;v.w+=bv.w; }
        if (ACT==1){
          v.x=fmaxf(v.x,0.f); v.y=fmaxf(v.y,0.f); v.z=fmaxf(v.z,0.f); v.w=fmaxf(v.w,0.f);
        }
        if (HASR){ const float4 rv=*(const float4*)(res+(size_t)p*rstride+co); v.x+=rv.x;v.y+=rv.y;v.z+=rv.z;v.w+=rv.w; }
        if (OUTBF){
          uint2 pk;
          pk.x = f2bf(v.x)|(f2bf(v.y)<<16);
          pk.y = f2bf(v.z)|(f2bf(v.w)<<16);
          *(uint2*)((u16*)out + (size_t)p*ostride + co) = pk;
        } else {
          *(float4*)((float*)out + (size_t)p*ostride + co) = v;
        }
      }
    }
  }
}

// ---------------------------------------------------------------------------
// K4: depthwise 3x3, bf16 in/out, optional bias + exact gelu
// ---------------------------------------------------------------------------
template<bool HASB, bool DOGELU>
__global__ __launch_bounds__(256) void dw3x3_k(const u16* __restrict__ in, int istride,
                                               const float* __restrict__ w,
                                               const float* __restrict__ bias,
                                               u16* __restrict__ out, int C){
  int t = blockIdx.x*256 + threadIdx.x;
  int cg = C >> 2;
  int p = t / cg;
  if (p >= ST) return;
  int c4 = (t - p*cg) << 2;
  int bb = p / HW_, hw = p - bb*HW_;
  int hy = hw / IW, wx = hw - hy*IW;
  float w0[9], w1[9], w2[9], w3[9];
  #pragma unroll
  for (int tp=0;tp<9;tp++){
    w0[tp]=w[(c4+0)*9+tp]; w1[tp]=w[(c4+1)*9+tp]; w2[tp]=w[(c4+2)*9+tp]; w3[tp]=w[(c4+3)*9+tp];
  }
  float ax=0.f, ay=0.f, az=0.f, aw=0.f;
  #pragma unroll
  for (int i=0;i<3;i++){
    int y = hy+i-1;
    if ((unsigned)y >= IH) continue;
    #pragma unroll
    for (int j=0;j<3;j++){
      int x2 = wx+j-1;
      if ((unsigned)x2 >= IW) continue;
      const uint2 r = *(const uint2*)(in + ((size_t)bb*HW_ + y*IW + x2)*istride + c4);
      int tp=i*3+j;
      ax += bfl(r.x)*w0[tp]; ay += bfh(r.x)*w1[tp];
      az += bfl(r.y)*w2[tp]; aw += bfh(r.y)*w3[tp];
    }
  }
  if (HASB){ ax+=bias[c4]; ay+=bias[c4+1]; az+=bias[c4+2]; aw+=bias[c4+3]; }
  if (DOGELU){ ax=gelu_f(ax); ay=gelu_f(ay); az=gelu_f(az); aw=gelu_f(aw); }
  uint2 pk;
  pk.x = f2bf(ax)|(f2bf(ay)<<16);
  pk.y = f2bf(az)|(f2bf(aw)<<16);
  *(uint2*)(out + (size_t)p*C + c4) = pk;
}

// ---------------------------------------------------------------------------
// K5: full 3x3 conv 16->16 (para branch), fp32. 4 threads per pixel.
// ---------------------------------------------------------------------------
__global__ __launch_bounds__(256) void p2conv_k(const float* __restrict__ in, const float* __restrict__ w,
                                                const float* __restrict__ bias, float* __restrict__ out){
  __shared__ float ws[2304];
  int tid = threadIdx.x;
  for (int i=tid;i<2304;i+=256) ws[i]=w[i];
  __syncthreads();
  int gidx = blockIdx.x*256 + tid;
  int p = gidx >> 2, qq = gidx & 3;
  int bb = p / HW_, hw = p - bb*HW_;
  int hy = hw / IW, wx = hw - hy*IW;
  const int cb = qq<<2;
  float a0=bias[cb], a1=bias[cb+1], a2=bias[cb+2], a3=bias[cb+3];
  #pragma unroll
  for (int i=0;i<3;i++){
    int y=hy+i-1; if ((unsigned)y>=IH) continue;
    #pragma unroll
    for (int j=0;j<3;j++){
      int x2=wx+j-1; if ((unsigned)x2>=IW) continue;
      int tap=i*3+j;
      const float* prow = in + ((size_t)bb*HW_ + y*IW + x2)*16;
      #pragma unroll
      for (int ci=0;ci<16;ci++){
        float v = prow[ci];
        a0 += ws[(cb+0)*144 + ci*9 + tap]*v;
        a1 += ws[(cb+1)*144 + ci*9 + tap]*v;
        a2 += ws[(cb+2)*144 + ci*9 + tap]*v;
        a3 += ws[(cb+3)*144 + ci*9 + tap]*v;
      }
    }
  }
  *(float4*)(out + (size_t)p*16 + cb) = make_float4(a0,a1,a2,a3);
}

// ---------------------------------------------------------------------------
// K6a: prep ada_w -> bf16 Amat[g][row=o*16+r][k'=tap*16+cl], K'=160.
// ---------------------------------------------------------------------------
__global__ __launch_bounds__(256) void ada_prep_k(const float* __restrict__ aw,
                                                  u16* __restrict__ apre){
  int g = blockIdx.y;
  int e = blockIdx.x*256 + threadIdx.x;
  int row = e / 160, kp = e - row*160;
  int tap = kp >> 4, cl = kp & 15;
  int o = row >> 4, r = row & 15;
  float v = 0.f;
  if (tap < 9 && cl < 12)
    v = aw[(((size_t)(g*12+o)*108) + cl*9 + tap)*16 + r];
  apre[(size_t)g*30720 + e] = (u16)f2bf(v);
}

// ---------------------------------------------------------------------------
// K6c: fp32 -> bf16 weight prep (9 matrices incl. p1)
// ---------------------------------------------------------------------------
__global__ __launch_bounds__(256) void wprep_k(
    const float* __restrict__ s0, const float* __restrict__ s1,
    const float* __restrict__ s2, const float* __restrict__ s3,
    const float* __restrict__ s4, const float* __restrict__ s5,
    const float* __restrict__ s6, const float* __restrict__ s7,
    const float* __restrict__ s8,
    u16* __restrict__ dst)
{
  const int sz[9]  = {27648,18432,18432,18432,9216,18432,18432,36864,3072};
  const int off[9] = {0,27648,46080,64512,82944,92160,110592,129024,165888};
  int m = blockIdx.y;
  int i = blockIdx.x*256 + threadIdx.x;
  const float* s = (m==0)?s0:(m==1)?s1:(m==2)?s2:(m==3)?s3:(m==4)?s4:(m==5)?s5:(m==6)?s6:(m==7)?s7:s8;
  if (i < sz[m]) dst[off[m]+i] = (u16)f2bf(s[i]);
}

// ---------------------------------------------------------------------------
// K6b v5: adaconv MFMA, bf16 in/out.  Block: (b, g, 16x8 region) = 2304 blocks.
// Halo staging = pure copies (x2 already bf16).  Epilogue fuses b1 (dw1 out)
// multiply and writes bf16.
// ---------------------------------------------------------------------------
__global__ __launch_bounds__(256) void adaconv_mfma_k(
    const u16* __restrict__ x2, const float* __restrict__ para,
    const u16* __restrict__ apre, const u16* __restrict__ dw1,
    u16* __restrict__ outb2)
{
  __shared__ __align__(16) unsigned char smem[18880];
  unsigned char* HB = smem;             // 18 rows x 10 cols x 48B = 8640
  float* PS = (float*)(smem + 8640);    // [2 sub][64 px][20] f32 = 10240

  const int tid=threadIdx.x, lane=tid&63, wv=tid>>6;
  const int lr=lane&15, g4=lane>>4;
  const int hi=(lane>>5)&1, lo16=(lane>>4)&1;
  const int b=blockIdx.z, g=blockIdx.y, reg=blockIdx.x;
  const int rh=(reg/12)<<4, rw=(reg%12)<<3;

  // --- A fragments (tap-major K'=160), 15 x 16B per lane from L2 ---
  bf16x8 af[3][5];
  {
    const u16* ag = apre + (size_t)g*30720;
    #pragma unroll
    for (int oo=0;oo<3;oo++){
      const int row=(wv*3+oo)*16+lr;
      #pragma unroll
      for (int ks=0;ks<5;ks++)
        af[oo][ks] = *(const bf16x8*)(ag + row*160 + ks*32 + g4*8);
    }
  }
  // --- stage halo: 18x10 px, 12 bf16 ch -> 48B slots (pure copies) ---
  if (tid < 180){
    int hy = tid/10, hx = tid - hy*10;
    int gy = rh+hy-1, gx = rw+hx-1;
    uint2 a={0,0}, c={0,0}, d={0,0};
    if ((unsigned)gy<IH && (unsigned)gx<IW){
      const uint2* s2 = (const uint2*)(x2 + ((size_t)b*HW_ + gy*IW + gx)*384 + g*12);
      a=s2[0]; c=s2[1]; d=s2[2];
    }
    *(uint4*)(HB + tid*48)      = make_uint4(a.x,a.y,c.x,c.y);
    *(uint4*)(HB + tid*48 + 16) = make_uint4(d.x,d.y,0,0);
  }
  // --- stage para for both subtiles ---
  #pragma unroll
  for (int it=0; it<2; ++it){
    int idx = tid + (it<<8);
    int sub = idx >> 8;
    int p = (idx>>2)&63, q = idx&3;
    int gy = rh + (sub<<3) + (p>>3), gx = rw + (p&7);
    float4 v = *(const float4*)(para + ((size_t)b*HW_+gy*IW+gx)*16 + q*4);
    *(float4*)&PS[sub*1280 + p*20 + q*4] = v;
  }
  __syncthreads();

  int tapoff[5];
  tapoff[0] = hi ? 48   : 0;
  tapoff[1] = hi ? 480  : 96;
  tapoff[2] = hi ? 576  : 528;
  tapoff[3] = hi ? 1008 : 960;
  tapoff[4] = 1056;

  #pragma unroll
  for (int sub=0; sub<2; ++sub){
    const int sy = sub<<3;
    const int base0 = ((sy + (lr>>3))*10 + (lr&7))*48 + lo16*16;

    f32x4 acc[3][4];
    #pragma unroll
    for (int oo=0;oo<3;oo++)
      #pragma unroll
      for (int n=0;n<4;n++) acc[oo][n]=(f32x4){0.f,0.f,0.f,0.f};

    #pragma unroll
    for (int ks=0;ks<5;ks++){
      bf16x8 bfr[4];
      #pragma unroll
      for (int n=0;n<4;n++)
        bfr[n] = *(const bf16x8*)(HB + base0 + n*960 + tapoff[ks]);
      #pragma unroll
      for (int oo=0;oo<3;oo++)
        #pragma unroll
        for (int n=0;n<4;n++)
          acc[oo][n]=__builtin_amdgcn_mfma_f32_16x16x32_bf16(af[oo][ks], bfr[n], acc[oo][n],0,0,0);
    }

    const float* ps = &PS[sub*1280];
    #pragma unroll
    for (int oo=0;oo<3;oo++){
      const int o=wv*3+oo;
      #pragma unroll
      for (int n=0;n<4;n++){
        const int p=(n<<4)+lr;
        const f32x4 prv = *(const f32x4*)&ps[p*20+(g4<<2)];
        float s=acc[oo][n].x*prv.x+acc[oo][n].y*prv.y+acc[oo][n].z*prv.z+acc[oo][n].w*prv.w;
        s += __shfl_xor(s,16); s += __shfl_xor(s,32);
        if (g4==n){
          const int py=p>>3, px=p&7;
          size_t idx = ((size_t)b*HW_+(rh+sy+py)*IW+(rw+px))*192 + g*12 + o;
          float b1v = bfl(dw1[idx]);
          outb2[idx] = (u16)f2bf(gelu_f(s)*b1v);
        }
      }
    }
  }
}

// ---------------------------------------------------------------------------
// K7: shifted-window attention, 1 wave per (window, head). fp32 in, bf16 out.
// ---------------------------------------------------------------------------
__global__ __launch_bounds__(64) void attn_k(const float* __restrict__ qkv,
                                             const float* __restrict__ relpos,
                                             u16* __restrict__ outa){
  __shared__ float k_s[2048];
  __shared__ float v_s[2048];
  __shared__ float rel_s[225];
  const int win = blockIdx.x, head = blockIdx.y, b = blockIdx.z;
  const int wi = win/12, wj = win%12;
  const int lane = threadIdx.x;
  for (int i=lane;i<225;i+=64) rel_s[i] = relpos[i*3+head];
  const int pi = lane>>3, pj = lane&7;
  const int hr = wi*8+pi, wr = wj*8+pj;
  const int sh = (hr+4)%96, sw = (wr+4)%96;
  const size_t pix = (size_t)b*HW_ + sh*96 + sw;
  const float* qrow = qkv + pix*288 + head*32;
  const float* krow = qkv + pix*288 + 96 + head*32;
  const float* vrow = qkv + pix*288 + 192 + head*32;
  const float SC = 0.17677669529663687f;
  float q[32];
  #pragma unroll
  for (int i=0;i<32;i+=4){
    const float4 t4 = *(const float4*)(qrow+i);
    q[i]=t4.x*SC; q[i+1]=t4.y*SC; q[i+2]=t4.z*SC; q[i+3]=t4.w*SC;
  }
  #pragma unroll
  for (int i=0;i<32;i+=4){
    *(float4*)&k_s[(lane<<5)+i] = *(const float4*)(krow+i);
    *(float4*)&v_s[(lane<<5)+i] = *(const float4*)(vrow+i);
  }
  __syncthreads();
  const bool mi = (wi==11), mj = (wj==11);
  float sc[64];
  #pragma unroll
  for (int qq=0; qq<64; qq++){
    const float4* kr4 = (const float4*)&k_s[qq<<5];
    float s = 0.f;
    #pragma unroll
    for (int i=0;i<8;i++){
      const float4 kv = kr4[i];
      s += q[4*i]*kv.x + q[4*i+1]*kv.y + q[4*i+2]*kv.z + q[4*i+3]*kv.w;
    }
    const int qi = qq>>3, qj = qq&7;
    s += rel_s[(pi-qi+7)*15 + (pj-qj+7)];
    const bool msk = (mi && ((pi<4)!=(qi<4))) || (mj && ((pj<4)!=(qj<4)));
    sc[qq] = msk ? -1e30f : s;
  }
  float m = sc[0];
  #pragma unroll
  for (int qq=1;qq<64;qq++) m = fmaxf(m, sc[qq]);
  float sum = 0.f;
  #pragma unroll
  for (int qq=0;qq<64;qq++){ float e = __expf(sc[qq]-m); sc[qq]=e; sum+=e; }
  const float inv = 1.f/sum;
  float acc[32];
  #pragma unroll
  for (int i=0;i<32;i++) acc[i]=0.f;
  #pragma unroll
  for (int qq=0;qq<64;qq++){
    const float a = sc[qq]*inv;
    const float4* vr4 = (const float4*)&v_s[qq<<5];
    #pragma unroll
    for (int i=0;i<8;i++){
      const float4 vv = vr4[i];
      acc[4*i]+=a*vv.x; acc[4*i+1]+=a*vv.y; acc[4*i+2]+=a*vv.z; acc[4*i+3]+=a*vv.w;
    }
  }
  u16* orow = outa + pix*96 + head*32;
  #pragma unroll
  for (int i=0;i<4;i++){
    uint4 pk;
    pk.x = f2bf(acc[i*8+0])|(f2bf(acc[i*8+1])<<16);
    pk.y = f2bf(acc[i*8+2])|(f2bf(acc[i*8+3])<<16);
    pk.z = f2bf(acc[i*8+4])|(f2bf(acc[i*8+5])<<16);
    pk.w = f2bf(acc[i*8+6])|(f2bf(acc[i*8+7])<<16);
    *(uint4*)(orow + i*8) = pk;
  }
}

// ---------------------------------------------------------------------------
extern "C" void kernel_launch(void* const* d_in, const int* in_sizes, int n_in,
                              void* d_out, int out_size, void* d_ws, size_t ws_size,
                              hipStream_t stream)
{
  (void)in_sizes; (void)n_in; (void)out_size; (void)ws_size;
  const float* x        = (const float*)d_in[0];
  const float* cb_ln_g  = (const float*)d_in[1];
  const float* cb_ln_b  = (const float*)d_in[2];
  const float* cb_c1_pw = (const float*)d_in[3];
  const float* cb_c1_dw = (const float*)d_in[4];
  const float* cb_c2_pw = (const float*)d_in[5];
  const float* ada_w    = (const float*)d_in[6];
  const float* ada_p1_w = (const float*)d_in[7];
  const float* ada_p1_b = (const float*)d_in[8];
  const float* ada_p2_w = (const float*)d_in[9];
  const float* ada_p2_b = (const float*)d_in[10];
  const float* cb_c3_w  = (const float*)d_in[11];
  const float* ln1_g    = (const float*)d_in[12];
  const float* ln1_b    = (const float*)d_in[13];
  const float* qkv_w    = (const float*)d_in[14];
  const float* qkv_b    = (const float*)d_in[15];
  const float* rel_pos  = (const float*)d_in[16];
  const float* proj_w   = (const float*)d_in[17];
  const float* proj_b   = (const float*)d_in[18];
  const float* ln2_g    = (const float*)d_in[19];
  const float* ln2_b    = (const float*)d_in[20];
  const float* ffn_w1   = (const float*)d_in[21];
  const float* ffn_b1   = (const float*)d_in[22];
  const float* ffn_dw   = (const float*)d_in[23];
  const float* ffn_db   = (const float*)d_in[24];
  const float* ffn_w2   = (const float*)d_in[25];
  const float* ffn_b2   = (const float*)d_in[26];
  const float* out_w    = (const float*)d_in[27];
  const float* out_b    = (const float*)d_in[28];

  char* wsb = (char*)d_ws;
  const size_t F = sizeof(float);
  // fp32 regions
  float* xcl = (float*)wsb;                                   // ST*192 f32
  float* U0f = (float*)(wsb + (size_t)ST*192*F);              // ST*288 f32 region (QKV overlay)
  float* XT  = (float*)(wsb + (size_t)ST*480*F);              // ST*96 f32
  float* PA1 = (float*)(wsb + (size_t)ST*576*F);              // ST*16
  float* PA2 = (float*)(wsb + (size_t)ST*592*F);              // ST*16
  // u16 regions
  u16* B2b  = (u16*)(wsb + (size_t)ST*608*F);                 // ST*192 u16
  u16* LNCb = (u16*)(wsb + (size_t)ST*608*F + (size_t)ST*192*2);
  u16* R4b  = (u16*)(wsb + (size_t)ST*608*F + (size_t)ST*288*2);
  u16* R6b  = (u16*)(wsb + (size_t)ST*608*F + (size_t)ST*384*2);
  u16* Wbf  = (u16*)(wsb + (size_t)ST*608*F + (size_t)ST*480*2);
  u16* Apre = Wbf + 168960;
  // overlays on U0f (ST*288 f32 = ST*576 u16)
  u16* X12b = (u16*)U0f;            // ST*384 u16 (c12 out, stride 384)
  u16* DWb  = (u16*)U0f + (size_t)ST*384;  // ST*192 u16 (dw1 out)
  float* QKV = U0f;                 // ST*288 f32 (after conv branch dead)
  u16* FF1b  = (u16*)U0f;           // ST*192 u16 (after QKV dead)
  u16* DWOb  = (u16*)U0f + (size_t)ST*192;

  const u16* W_qkv  = Wbf + 0;
  const u16* W_c12  = Wbf + 27648;
  const u16* W_c3   = Wbf + 64512;
  const u16* W_proj = Wbf + 82944;
  const u16* W_ffn1 = Wbf + 92160;
  const u16* W_ffn2 = Wbf + 110592;
  const u16* W_fin  = Wbf + 129024;
  const u16* W_p1   = Wbf + 165888;

  // weight preps
  wprep_k<<<dim3(144, 9), 256, 0, stream>>>(qkv_w, cb_c1_pw, cb_c2_pw, cb_c3_w,
                                            proj_w, ffn_w1, ffn_w2, out_w, ada_p1_w, Wbf);
  ada_prep_k<<<dim3(120, 16), 256, 0, stream>>>(ada_w, Apre);

  // conv branch
  transpose_in_k<<<dim3(HW_/32, 6, NB), 256, 0, stream>>>(x, xcl);
  ln_k<<<ST/4, 256, 0, stream>>>(xcl, 192, 0, cb_ln_g, cb_ln_b, LNCb, nullptr);
  // fused c1+c2: 96 -> 384 bf16 (rows 0-191 = c1, 192-383 = c2)
  conv_mfma_k<0,false,false,false,false,true><<<dim3(ST/128, 6), 256, 0, stream>>>(LNCb, nullptr, 96, W_c12, nullptr, nullptr, 0, X12b, 384, 96, 384);
  dw3x3_k<false,false><<<(ST*48)/256, 256, 0, stream>>>(X12b, 384, cb_c1_dw, nullptr, DWb, 192);
  conv_mfma_k<1,false,false,true,false,false><<<dim3(ST/128, 1), 256, 0, stream>>>(X12b+192, nullptr, 384, W_p1, ada_p1_b, nullptr, 0, PA1, 16, 192, 16);
  p2conv_k<<<(ST*4)/256, 256, 0, stream>>>(PA1, ada_p2_w, ada_p2_b, PA2);
  adaconv_mfma_k<<<dim3(72, 16, NB), 256, 0, stream>>>(X12b+192, PA2, Apre, DWb, B2b);
  conv_mfma_k<0,false,false,false,true,true><<<dim3(ST/128, 2), 256, 0, stream>>>(B2b, nullptr, 192, W_c3, nullptr, xcl, 192, R4b, 96, 192, 96);

  // transformer branch
  ln_k<<<ST/4, 256, 0, stream>>>(xcl, 192, 96, ln1_g, ln1_b, R6b, XT);
  conv_mfma_k<0,false,false,true,false,false><<<dim3(ST/128, 5), 256, 0, stream>>>(R6b, nullptr, 96, W_qkv, qkv_b, nullptr, 0, QKV, 288, 96, 288);
  attn_k<<<dim3(144, 3, NB), 64, 0, stream>>>(QKV, rel_pos, R6b);
  conv_mfma_k<0,false,false,true,true,false><<<dim3(ST/128, 2), 256, 0, stream>>>(R6b, nullptr, 96, W_proj, proj_b, XT, 96, XT, 96, 96, 96);
  ln_k<<<ST/4, 256, 0, stream>>>(XT, 96, 0, ln2_g, ln2_b, R6b, nullptr);
  conv_mfma_k<0,false,false,true,false,true><<<dim3(ST/128, 3), 256, 0, stream>>>(R6b, nullptr, 96, W_ffn1, ffn_b1, nullptr, 0, FF1b, 192, 96, 192);
  dw3x3_k<true,true><<<(ST*48)/256, 256, 0, stream>>>(FF1b, 192, ffn_dw, ffn_db, DWOb, 192);
  conv_mfma_k<0,false,false,true,true,false><<<dim3(ST/128, 2), 256, 0, stream>>>(DWOb, nullptr, 192, W_ffn2, ffn_b2, XT, 96, XT, 96, 192, 96);

  // fuse: out = x + conv1x1(concat(convout bf16, xt f32), out_w) + out_b  (channel-first)
  conv_mfma_k<0,true,true,true,true,false><<<dim3(ST/128, 3), 256, 0, stream>>>(R4b, XT, 96, W_fin, out_b, x, 0, (float*)d_out, 0, 192, 192);
}

// Round 7
// 245.727 us; speedup vs baseline: 2.0086x; 1.0747x over previous
//
#include <hip/hip_runtime.h>
#include <math.h>

#define HW_ 9216
#define IH 96
#define IW 96
#define NB 2
#define ST (NB*HW_)   // 18432 pixels total

typedef __attribute__((ext_vector_type(8))) short bf16x8;
typedef __attribute__((ext_vector_type(4))) float f32x4;
typedef unsigned short u16;

__device__ __forceinline__ float gelu_f(float v){
  return 0.5f*v*(1.0f+erff(v*0.70710678118654752440f));
}
__device__ __forceinline__ unsigned f2bf(float f){
  unsigned u = __float_as_uint(f);
  return (u + 0x7FFF + ((u>>16)&1)) >> 16;
}
__device__ __forceinline__ float bfl(unsigned u){ return __uint_as_float(u<<16); }
__device__ __forceinline__ float bfh(unsigned u){ return __uint_as_float(u & 0xffff0000u); }

// ---------------------------------------------------------------------------
// K2: fused dual LayerNorm from NCHW input. Block: 32 px x 192 ch via LDS.
// Writes: lnc = LN(ch0-95) bf16, ln1o = LN(ch96-191) bf16,
//         xc = raw ch0-95 f32, xt = raw ch96-191 f32.
// ---------------------------------------------------------------------------
__global__ __launch_bounds__(256) void ln12_k(const float* __restrict__ x,
    const float* __restrict__ g1, const float* __restrict__ b1,
    const float* __restrict__ g2, const float* __restrict__ b2,
    u16* __restrict__ lnc, u16* __restrict__ ln1o,
    float* __restrict__ xc, float* __restrict__ xt)
{
  __shared__ float t[192][33];
  const int p0 = blockIdx.x<<5;
  const int bb = p0/HW_, hw0 = p0 - bb*HW_;
  const int tid = threadIdx.x;
  const int px = tid & 31, cr = tid >> 5;
  const float* xb = x + (size_t)bb*192*HW_ + hw0;
  #pragma unroll
  for (int k=0;k<24;k++){
    int c = cr + k*8;
    t[c][px] = xb[(size_t)c*HW_ + px];
  }
  __syncthreads();
  const int lane = tid&63, wv = tid>>6;
  #pragma unroll 1
  for (int i=0;i<8;i++){
    const int lp = wv*8+i;
    const size_t p = p0 + lp;
    float a0 = t[lane][lp];
    float a1 = (lane<32)? t[64+lane][lp] : 0.f;
    float c0 = t[96+lane][lp];
    float c1 = (lane<32)? t[160+lane][lp] : 0.f;
    float s1=a0+a1, s2=c0+c1;
    #pragma unroll
    for (int o=32;o;o>>=1){ s1+=__shfl_xor(s1,o); s2+=__shfl_xor(s2,o); }
    const float mu1=s1*(1.f/96.f), mu2=s2*(1.f/96.f);
    const float d0=a0-mu1, d1=a1-mu1, e0=c0-mu2, e1=c1-mu2;
    float q1=d0*d0+((lane<32)?d1*d1:0.f), q2=e0*e0+((lane<32)?e1*e1:0.f);
    #pragma unroll
    for (int o=32;o;o>>=1){ q1+=__shfl_xor(q1,o); q2+=__shfl_xor(q2,o); }
    const float r1=rsqrtf(q1*(1.f/96.f)+1e-5f), r2=rsqrtf(q2*(1.f/96.f)+1e-5f);
    lnc [p*96+lane] = (u16)f2bf(d0*r1*g1[lane]+b1[lane]);
    ln1o[p*96+lane] = (u16)f2bf(e0*r2*g2[lane]+b2[lane]);
    xc  [p*96+lane] = a0;
    xt  [p*96+lane] = c0;
    if (lane<32){
      lnc [p*96+64+lane] = (u16)f2bf(d1*r1*g1[64+lane]+b1[64+lane]);
      ln1o[p*96+64+lane] = (u16)f2bf(e1*r2*g2[64+lane]+b2[64+lane]);
      xc  [p*96+64+lane] = a1;
      xt  [p*96+64+lane] = c1;
    }
  }
}

// ---------------------------------------------------------------------------
// K2b: single LayerNorm (fp32 in, bf16 out) — used for ln2.
// ---------------------------------------------------------------------------
__global__ __launch_bounds__(256) void ln_k(const float* __restrict__ in, int istride,
                                            const float* __restrict__ gam, const float* __restrict__ bet,
                                            u16* __restrict__ out){
  int lane = threadIdx.x & 63;
  int wv   = threadIdx.x >> 6;
  int p    = (blockIdx.x << 2) + wv;
  const float* row = in + (size_t)p*istride;
  float v0 = row[lane];
  float v1 = (lane < 32) ? row[64+lane] : 0.0f;
  float s = v0 + v1;
  #pragma unroll
  for (int o=32;o;o>>=1) s += __shfl_xor(s,o);
  float mu = s * (1.0f/96.0f);
  float d0 = v0 - mu;
  float d1 = v1 - mu;
  float qv = d0*d0 + ((lane<32)? d1*d1 : 0.0f);
  #pragma unroll
  for (int o=32;o;o>>=1) qv += __shfl_xor(qv,o);
  float rstd = rsqrtf(qv*(1.0f/96.0f) + 1e-5f);
  u16* orow = out + (size_t)p*96;
  orow[lane] = (u16)f2bf(d0*rstd*gam[lane] + bet[lane]);
  if (lane < 32) orow[64+lane] = (u16)f2bf(d1*rstd*gam[64+lane] + bet[64+lane]);
}

// ---------------------------------------------------------------------------
// K3b: bf16-MFMA conv1x1.  Block: 128 px x 64 couts, 4 waves (2M x 2N).
// ---------------------------------------------------------------------------
template<int ACT, bool CONCAT, bool FINAL, bool HASB, bool HASR, bool OUTBF>
__global__ __launch_bounds__(256) void conv_mfma_k(
    const u16* __restrict__ in1, const float* __restrict__ in2f, int istride,
    const u16* __restrict__ wbf, const float* __restrict__ bias,
    const float* __restrict__ res, int rstride,
    void* __restrict__ out, int ostride, int Cin, int Cout)
{
  __shared__ __align__(16) unsigned char smem[39936];
  unsigned char* actl = smem;          // [128][208B]
  unsigned char* wl   = smem + 26624;  // [64][208B]
  const int tid=threadIdx.x, lane=tid&63, wv=tid>>6;
  const int lr=lane&15, g4=lane>>4, wm=wv>>1, wn=wv&1;
  const int p0=blockIdx.x<<7, co0=blockIdx.y<<6;

  f32x4 acc[2][4];
  #pragma unroll
  for (int m=0;m<2;m++)
    #pragma unroll
    for (int n=0;n<4;n++) acc[m][n]=(f32x4){0.f,0.f,0.f,0.f};

  for (int kc=0; kc<Cin; kc+=96){
    {
      const int row=tid>>1, half=tid&1;
      if (!CONCAT || kc==0){
        const u16* rp = in1 + (size_t)(p0+row)*istride + (CONCAT?0:kc) + half*48;
        #pragma unroll
        for (int s=0;s<6;s++)
          *(uint4*)(actl + row*208 + (half*6+s)*16) = *(const uint4*)(rp + s*8);
      } else {
        const float* rp = in2f + (size_t)(p0+row)*96 + half*48;
        #pragma unroll
        for (int s=0;s<6;s++){
          float4 a=*(const float4*)(rp+s*8), b=*(const float4*)(rp+s*8+4);
          uint4 pk;
          pk.x=f2bf(a.x)|(f2bf(a.y)<<16);
          pk.y=f2bf(a.z)|(f2bf(a.w)<<16);
          pk.z=f2bf(b.x)|(f2bf(b.y)<<16);
          pk.w=f2bf(b.z)|(f2bf(b.w)<<16);
          *(uint4*)(actl + row*208 + (half*6+s)*16) = pk;
        }
      }
    }
    {
      const int row=tid&63, grp=tid>>6;
      const int co=co0+row;
      const u16* wr = wbf + (size_t)co*Cin + kc;
      #pragma unroll
      for (int s=0;s<3;s++){
        int sl=grp*3+s;
        uint4 v={0,0,0,0};
        if (co<Cout) v=*(const uint4*)(wr + sl*8);
        *(uint4*)(wl + row*208 + sl*16)=v;
      }
    }
    __syncthreads();
    #pragma unroll
    for (int ks=0;ks<3;ks++){
      const int sl=ks*4+g4;
      bf16x8 afr[2], bfr[4];
      #pragma unroll
      for (int m=0;m<2;m++) afr[m]=*(const bf16x8*)(wl + ((wm*2+m)*16+lr)*208 + sl*16);
      #pragma unroll
      for (int n=0;n<4;n++) bfr[n]=*(const bf16x8*)(actl + (wn*64+n*16+lr)*208 + sl*16);
      #pragma unroll
      for (int m=0;m<2;m++)
        #pragma unroll
        for (int n=0;n<4;n++)
          acc[m][n]=__builtin_amdgcn_mfma_f32_16x16x32_bf16(afr[m], bfr[n], acc[m][n],0,0,0);
    }
    __syncthreads();
  }

  if (FINAL){
    float* outf = (float*)out;
    #pragma unroll
    for (int m=0;m<2;m++){
      const int cb=co0+(wm*2+m)*16+(g4<<2);
      float4 bv = make_float4(0.f,0.f,0.f,0.f);
      if (HASB) bv = *(const float4*)(bias+cb);
      #pragma unroll
      for (int n=0;n<4;n++){
        const int p=p0+wn*64+n*16+lr;
        const int bb=p/HW_, hw=p-bb*HW_;
        const float av[4]={acc[m][n].x,acc[m][n].y,acc[m][n].z,acc[m][n].w};
        const float bvv[4]={bv.x,bv.y,bv.z,bv.w};
        #pragma unroll
        for (int j=0;j<4;j++){
          size_t oi=((size_t)bb*192+cb+j)*HW_+hw;
          outf[oi]=av[j]+bvv[j]+res[oi];
        }
      }
    }
    return;
  }
  float* lt=(float*)smem;
  #pragma unroll
  for (int m=0;m<2;m++)
    #pragma unroll
    for (int n=0;n<4;n++){
      int px=wn*64+n*16+lr;
      int c=(wm*2+m)*16+(g4<<2);
      *(f32x4*)&lt[px*68+c]=acc[m][n];
    }
  __syncthreads();
  {
    const int pr=tid>>1, half=tid&1;
    const int p=p0+pr;
    #pragma unroll
    for (int s=0;s<8;s++){
      int cl=half*32+s*4;
      int co=co0+cl;
      if (co<Cout){
        float4 v=*(float4*)&lt[pr*68+cl];
        if (HASB){ const float4 bv=*(const float4*)(bias+co); v.x+=bv.x;v.y+=bv.y;v.z+=bv.z;v.w+=bv.w; }
        if (ACT==1){
          v.x=fmaxf(v.x,0.f); v.y=fmaxf(v.y,0.f); v.z=fmaxf(v.z,0.f); v.w=fmaxf(v.w,0.f);
        }
        if (HASR){ const float4 rv=*(const float4*)(res+(size_t)p*rstride+co); v.x+=rv.x;v.y+=rv.y;v.z+=rv.z;v.w+=rv.w; }
        if (OUTBF){
          uint2 pk;
          pk.x = f2bf(v.x)|(f2bf(v.y)<<16);
          pk.y = f2bf(v.z)|(f2bf(v.w)<<16);
          *(uint2*)((u16*)out + (size_t)p*ostride + co) = pk;
        } else {
          *(float4*)((float*)out + (size_t)p*ostride + co) = v;
        }
      }
    }
  }
}

// ---------------------------------------------------------------------------
// K4: depthwise 3x3, bf16 in/out, optional bias + exact gelu
// ---------------------------------------------------------------------------
template<bool HASB, bool DOGELU>
__global__ __launch_bounds__(256) void dw3x3_k(const u16* __restrict__ in, int istride,
                                               const float* __restrict__ w,
                                               const float* __restrict__ bias,
                                               u16* __restrict__ out, int C){
  int t = blockIdx.x*256 + threadIdx.x;
  int cg = C >> 2;
  int p = t / cg;
  if (p >= ST) return;
  int c4 = (t - p*cg) << 2;
  int bb = p / HW_, hw = p - bb*HW_;
  int hy = hw / IW, wx = hw - hy*IW;
  float w0[9], w1[9], w2[9], w3[9];
  #pragma unroll
  for (int tp=0;tp<9;tp++){
    w0[tp]=w[(c4+0)*9+tp]; w1[tp]=w[(c4+1)*9+tp]; w2[tp]=w[(c4+2)*9+tp]; w3[tp]=w[(c4+3)*9+tp];
  }
  float ax=0.f, ay=0.f, az=0.f, aw=0.f;
  #pragma unroll
  for (int i=0;i<3;i++){
    int y = hy+i-1;
    if ((unsigned)y >= IH) continue;
    #pragma unroll
    for (int j=0;j<3;j++){
      int x2 = wx+j-1;
      if ((unsigned)x2 >= IW) continue;
      const uint2 r = *(const uint2*)(in + ((size_t)bb*HW_ + y*IW + x2)*istride + c4);
      int tp=i*3+j;
      ax += bfl(r.x)*w0[tp]; ay += bfh(r.x)*w1[tp];
      az += bfl(r.y)*w2[tp]; aw += bfh(r.y)*w3[tp];
    }
  }
  if (HASB){ ax+=bias[c4]; ay+=bias[c4+1]; az+=bias[c4+2]; aw+=bias[c4+3]; }
  if (DOGELU){ ax=gelu_f(ax); ay=gelu_f(ay); az=gelu_f(az); aw=gelu_f(aw); }
  uint2 pk;
  pk.x = f2bf(ax)|(f2bf(ay)<<16);
  pk.y = f2bf(az)|(f2bf(aw)<<16);
  *(uint2*)(out + (size_t)p*C + c4) = pk;
}

// ---------------------------------------------------------------------------
// K5: full 3x3 conv 16->16 (para branch), fp32. 4 threads per pixel.
// ---------------------------------------------------------------------------
__global__ __launch_bounds__(256) void p2conv_k(const float* __restrict__ in, const float* __restrict__ w,
                                                const float* __restrict__ bias, float* __restrict__ out){
  __shared__ float ws[2304];
  int tid = threadIdx.x;
  for (int i=tid;i<2304;i+=256) ws[i]=w[i];
  __syncthreads();
  int gidx = blockIdx.x*256 + tid;
  int p = gidx >> 2, qq = gidx & 3;
  int bb = p / HW_, hw = p - bb*HW_;
  int hy = hw / IW, wx = hw - hy*IW;
  const int cb = qq<<2;
  float a0=bias[cb], a1=bias[cb+1], a2=bias[cb+2], a3=bias[cb+3];
  #pragma unroll
  for (int i=0;i<3;i++){
    int y=hy+i-1; if ((unsigned)y>=IH) continue;
    #pragma unroll
    for (int j=0;j<3;j++){
      int x2=wx+j-1; if ((unsigned)x2>=IW) continue;
      int tap=i*3+j;
      const float* prow = in + ((size_t)bb*HW_ + y*IW + x2)*16;
      #pragma unroll
      for (int ci=0;ci<16;ci++){
        float v = prow[ci];
        a0 += ws[(cb+0)*144 + ci*9 + tap]*v;
        a1 += ws[(cb+1)*144 + ci*9 + tap]*v;
        a2 += ws[(cb+2)*144 + ci*9 + tap]*v;
        a3 += ws[(cb+3)*144 + ci*9 + tap]*v;
      }
    }
  }
  *(float4*)(out + (size_t)p*16 + cb) = make_float4(a0,a1,a2,a3);
}

// ---------------------------------------------------------------------------
// K6a: prep ada_w -> bf16 Amat[g][row=o*16+r][k'=tap*16+cl], K'=160.
// ---------------------------------------------------------------------------
__global__ __launch_bounds__(256) void ada_prep_k(const float* __restrict__ aw,
                                                  u16* __restrict__ apre){
  int g = blockIdx.y;
  int e = blockIdx.x*256 + threadIdx.x;
  int row = e / 160, kp = e - row*160;
  int tap = kp >> 4, cl = kp & 15;
  int o = row >> 4, r = row & 15;
  float v = 0.f;
  if (tap < 9 && cl < 12)
    v = aw[(((size_t)(g*12+o)*108) + cl*9 + tap)*16 + r];
  apre[(size_t)g*30720 + e] = (u16)f2bf(v);
}

// ---------------------------------------------------------------------------
// K6c: fp32 -> bf16 weight prep (9 matrices incl. p1)
// ---------------------------------------------------------------------------
__global__ __launch_bounds__(256) void wprep_k(
    const float* __restrict__ s0, const float* __restrict__ s1,
    const float* __restrict__ s2, const float* __restrict__ s3,
    const float* __restrict__ s4, const float* __restrict__ s5,
    const float* __restrict__ s6, const float* __restrict__ s7,
    const float* __restrict__ s8,
    u16* __restrict__ dst)
{
  const int sz[9]  = {27648,18432,18432,18432,9216,18432,18432,36864,3072};
  const int off[9] = {0,27648,46080,64512,82944,92160,110592,129024,165888};
  int m = blockIdx.y;
  int i = blockIdx.x*256 + threadIdx.x;
  const float* s = (m==0)?s0:(m==1)?s1:(m==2)?s2:(m==3)?s3:(m==4)?s4:(m==5)?s5:(m==6)?s6:(m==7)?s7:s8;
  if (i < sz[m]) dst[off[m]+i] = (u16)f2bf(s[i]);
}

// ---------------------------------------------------------------------------
// K6b v6: adaconv MFMA, bf16 in/out.  Block: (b, g, 16x8 region) = 2304 blocks.
// LDS-collected epilogue: both subtiles' gelu outputs staged in OS, then one
// barrier + coalesced uint2 read(dw1)/mul/write pass.
// ---------------------------------------------------------------------------
__global__ __launch_bounds__(256) void adaconv_mfma_k(
    const u16* __restrict__ x2, const float* __restrict__ para,
    const u16* __restrict__ apre, const u16* __restrict__ dw1,
    u16* __restrict__ outb2)
{
  __shared__ __align__(16) unsigned char smem[25024];
  unsigned char* HB = smem;             // 18 rows x 10 cols x 48B = 8640
  float* PS = (float*)(smem + 8640);    // [2 sub][64 px][20] f32 = 10240
  float* OS = (float*)(smem + 18880);   // [2 sub][64 px][12] f32 = 6144

  const int tid=threadIdx.x, lane=tid&63, wv=tid>>6;
  const int lr=lane&15, g4=lane>>4;
  const int hi=(lane>>5)&1, lo16=(lane>>4)&1;
  const int b=blockIdx.z, g=blockIdx.y, reg=blockIdx.x;
  const int rh=(reg/12)<<4, rw=(reg%12)<<3;

  // --- A fragments (tap-major K'=160), 15 x 16B per lane from L2 ---
  bf16x8 af[3][5];
  {
    const u16* ag = apre + (size_t)g*30720;
    #pragma unroll
    for (int oo=0;oo<3;oo++){
      const int row=(wv*3+oo)*16+lr;
      #pragma unroll
      for (int ks=0;ks<5;ks++)
        af[oo][ks] = *(const bf16x8*)(ag + row*160 + ks*32 + g4*8);
    }
  }
  // --- stage halo: 18x10 px, 12 bf16 ch -> 48B slots (pure copies) ---
  if (tid < 180){
    int hy = tid/10, hx = tid - hy*10;
    int gy = rh+hy-1, gx = rw+hx-1;
    uint2 a={0,0}, c={0,0}, d={0,0};
    if ((unsigned)gy<IH && (unsigned)gx<IW){
      const uint2* s2 = (const uint2*)(x2 + ((size_t)b*HW_ + gy*IW + gx)*384 + g*12);
      a=s2[0]; c=s2[1]; d=s2[2];
    }
    *(uint4*)(HB + tid*48)      = make_uint4(a.x,a.y,c.x,c.y);
    *(uint4*)(HB + tid*48 + 16) = make_uint4(d.x,d.y,0,0);
  }
  // --- stage para for both subtiles ---
  #pragma unroll
  for (int it=0; it<2; ++it){
    int idx = tid + (it<<8);
    int sub = idx >> 8;
    int p = (idx>>2)&63, q = idx&3;
    int gy = rh + (sub<<3) + (p>>3), gx = rw + (p&7);
    float4 v = *(const float4*)(para + ((size_t)b*HW_+gy*IW+gx)*16 + q*4);
    *(float4*)&PS[sub*1280 + p*20 + q*4] = v;
  }
  __syncthreads();

  int tapoff[5];
  tapoff[0] = hi ? 48   : 0;
  tapoff[1] = hi ? 480  : 96;
  tapoff[2] = hi ? 576  : 528;
  tapoff[3] = hi ? 1008 : 960;
  tapoff[4] = 1056;

  #pragma unroll
  for (int sub=0; sub<2; ++sub){
    const int sy = sub<<3;
    const int base0 = ((sy + (lr>>3))*10 + (lr&7))*48 + lo16*16;

    f32x4 acc[3][4];
    #pragma unroll
    for (int oo=0;oo<3;oo++)
      #pragma unroll
      for (int n=0;n<4;n++) acc[oo][n]=(f32x4){0.f,0.f,0.f,0.f};

    #pragma unroll
    for (int ks=0;ks<5;ks++){
      bf16x8 bfr[4];
      #pragma unroll
      for (int n=0;n<4;n++)
        bfr[n] = *(const bf16x8*)(HB + base0 + n*960 + tapoff[ks]);
      #pragma unroll
      for (int oo=0;oo<3;oo++)
        #pragma unroll
        for (int n=0;n<4;n++)
          acc[oo][n]=__builtin_amdgcn_mfma_f32_16x16x32_bf16(af[oo][ks], bfr[n], acc[oo][n],0,0,0);
    }

    const float* ps = &PS[sub*1280];
    #pragma unroll
    for (int oo=0;oo<3;oo++){
      const int o=wv*3+oo;
      #pragma unroll
      for (int n=0;n<4;n++){
        const int p=(n<<4)+lr;
        const f32x4 prv = *(const f32x4*)&ps[p*20+(g4<<2)];
        float s=acc[oo][n].x*prv.x+acc[oo][n].y*prv.y+acc[oo][n].z*prv.z+acc[oo][n].w*prv.w;
        s += __shfl_xor(s,16); s += __shfl_xor(s,32);
        if (g4==n) OS[((sub<<6)+p)*12+o] = gelu_f(s);
      }
    }
  }
  __syncthreads();
  // coalesced b1-multiply + write: 384 tasks of 4 channels
  {
    const size_t gb = (size_t)b*HW_;
    for (int idx=tid; idx<384; idx+=256){
      const int cq = idx % 3;
      const int rest = idx / 3;
      const int p = rest & 63, sub = rest >> 6;
      const int py = p>>3, px = p&7;
      const size_t gi = (gb + (rh+(sub<<3)+py)*IW + (rw+px))*192 + g*12 + cq*4;
      const uint2 d = *(const uint2*)(dw1 + gi);
      const float* os = &OS[((sub<<6)+p)*12 + cq*4];
      uint2 pk;
      pk.x = f2bf(os[0]*bfl(d.x)) | (f2bf(os[1]*bfh(d.x))<<16);
      pk.y = f2bf(os[2]*bfl(d.y)) | (f2bf(os[3]*bfh(d.y))<<16);
      *(uint2*)(outb2 + gi) = pk;
    }
  }
}

// ---------------------------------------------------------------------------
// K7: shifted-window attention, 1 wave per (window, head). bf16 in/out.
// ---------------------------------------------------------------------------
__global__ __launch_bounds__(64) void attn_k(const u16* __restrict__ qkv,
                                             const float* __restrict__ relpos,
                                             u16* __restrict__ outa){
  __shared__ float k_s[2048];
  __shared__ float v_s[2048];
  __shared__ float rel_s[225];
  const int win = blockIdx.x, head = blockIdx.y, b = blockIdx.z;
  const int wi = win/12, wj = win%12;
  const int lane = threadIdx.x;
  for (int i=lane;i<225;i+=64) rel_s[i] = relpos[i*3+head];
  const int pi = lane>>3, pj = lane&7;
  const int hr = wi*8+pi, wr = wj*8+pj;
  const int sh = (hr+4)%96, sw = (wr+4)%96;
  const size_t pix = (size_t)b*HW_ + sh*96 + sw;
  const u16* base = qkv + pix*288;
  const float SC = 0.17677669529663687f;
  float q[32];
  #pragma unroll
  for (int i=0;i<4;i++){
    const uint4 r = *(const uint4*)(base + head*32 + i*8);
    q[i*8+0]=bfl(r.x)*SC; q[i*8+1]=bfh(r.x)*SC;
    q[i*8+2]=bfl(r.y)*SC; q[i*8+3]=bfh(r.y)*SC;
    q[i*8+4]=bfl(r.z)*SC; q[i*8+5]=bfh(r.z)*SC;
    q[i*8+6]=bfl(r.w)*SC; q[i*8+7]=bfh(r.w)*SC;
  }
  #pragma unroll
  for (int i=0;i<4;i++){
    const uint4 rk = *(const uint4*)(base + 96 + head*32 + i*8);
    const uint4 rv = *(const uint4*)(base + 192 + head*32 + i*8);
    *(float4*)&k_s[(lane<<5)+i*8]   = make_float4(bfl(rk.x),bfh(rk.x),bfl(rk.y),bfh(rk.y));
    *(float4*)&k_s[(lane<<5)+i*8+4] = make_float4(bfl(rk.z),bfh(rk.z),bfl(rk.w),bfh(rk.w));
    *(float4*)&v_s[(lane<<5)+i*8]   = make_float4(bfl(rv.x),bfh(rv.x),bfl(rv.y),bfh(rv.y));
    *(float4*)&v_s[(lane<<5)+i*8+4] = make_float4(bfl(rv.z),bfh(rv.z),bfl(rv.w),bfh(rv.w));
  }
  __syncthreads();
  const bool mi = (wi==11), mj = (wj==11);
  float sc[64];
  #pragma unroll
  for (int qq=0; qq<64; qq++){
    const float4* kr4 = (const float4*)&k_s[qq<<5];
    float s = 0.f;
    #pragma unroll
    for (int i=0;i<8;i++){
      const float4 kv = kr4[i];
      s += q[4*i]*kv.x + q[4*i+1]*kv.y + q[4*i+2]*kv.z + q[4*i+3]*kv.w;
    }
    const int qi = qq>>3, qj = qq&7;
    s += rel_s[(pi-qi+7)*15 + (pj-qj+7)];
    const bool msk = (mi && ((pi<4)!=(qi<4))) || (mj && ((pj<4)!=(qj<4)));
    sc[qq] = msk ? -1e30f : s;
  }
  float m = sc[0];
  #pragma unroll
  for (int qq=1;qq<64;qq++) m = fmaxf(m, sc[qq]);
  float sum = 0.f;
  #pragma unroll
  for (int qq=0;qq<64;qq++){ float e = __expf(sc[qq]-m); sc[qq]=e; sum+=e; }
  const float inv = 1.f/sum;
  float acc[32];
  #pragma unroll
  for (int i=0;i<32;i++) acc[i]=0.f;
  #pragma unroll
  for (int qq=0;qq<64;qq++){
    const float a = sc[qq]*inv;
    const float4* vr4 = (const float4*)&v_s[qq<<5];
    #pragma unroll
    for (int i=0;i<8;i++){
      const float4 vv = vr4[i];
      acc[4*i]+=a*vv.x; acc[4*i+1]+=a*vv.y; acc[4*i+2]+=a*vv.z; acc[4*i+3]+=a*vv.w;
    }
  }
  u16* orow = outa + pix*96 + head*32;
  #pragma unroll
  for (int i=0;i<4;i++){
    uint4 pk;
    pk.x = f2bf(acc[i*8+0])|(f2bf(acc[i*8+1])<<16);
    pk.y = f2bf(acc[i*8+2])|(f2bf(acc[i*8+3])<<16);
    pk.z = f2bf(acc[i*8+4])|(f2bf(acc[i*8+5])<<16);
    pk.w = f2bf(acc[i*8+6])|(f2bf(acc[i*8+7])<<16);
    *(uint4*)(orow + i*8) = pk;
  }
}

// ---------------------------------------------------------------------------
extern "C" void kernel_launch(void* const* d_in, const int* in_sizes, int n_in,
                              void* d_out, int out_size, void* d_ws, size_t ws_size,
                              hipStream_t stream)
{
  (void)in_sizes; (void)n_in; (void)out_size; (void)ws_size;
  const float* x        = (const float*)d_in[0];
  const float* cb_ln_g  = (const float*)d_in[1];
  const float* cb_ln_b  = (const float*)d_in[2];
  const float* cb_c1_pw = (const float*)d_in[3];
  const float* cb_c1_dw = (const float*)d_in[4];
  const float* cb_c2_pw = (const float*)d_in[5];
  const float* ada_w    = (const float*)d_in[6];
  const float* ada_p1_w = (const float*)d_in[7];
  const float* ada_p1_b = (const float*)d_in[8];
  const float* ada_p2_w = (const float*)d_in[9];
  const float* ada_p2_b = (const float*)d_in[10];
  const float* cb_c3_w  = (const float*)d_in[11];
  const float* ln1_g    = (const float*)d_in[12];
  const float* ln1_b    = (const float*)d_in[13];
  const float* qkv_w    = (const float*)d_in[14];
  const float* qkv_b    = (const float*)d_in[15];
  const float* rel_pos  = (const float*)d_in[16];
  const float* proj_w   = (const float*)d_in[17];
  const float* proj_b   = (const float*)d_in[18];
  const float* ln2_g    = (const float*)d_in[19];
  const float* ln2_b    = (const float*)d_in[20];
  const float* ffn_w1   = (const float*)d_in[21];
  const float* ffn_b1   = (const float*)d_in[22];
  const float* ffn_dw   = (const float*)d_in[23];
  const float* ffn_db   = (const float*)d_in[24];
  const float* ffn_w2   = (const float*)d_in[25];
  const float* ffn_b2   = (const float*)d_in[26];
  const float* out_w    = (const float*)d_in[27];
  const float* out_b    = (const float*)d_in[28];

  char* wsb = (char*)d_ws;
  // fp32 regions
  float* XC  = (float*)wsb;                                   // ST*96  raw conv residual
  float* U0f = (float*)(wsb + (size_t)ST*96*4);               // ST*288 f32 overlay region
  float* XT  = (float*)(wsb + (size_t)ST*384*4);              // ST*96  transformer residual
  float* PA1 = (float*)(wsb + (size_t)ST*480*4);              // ST*16
  float* PA2 = (float*)(wsb + (size_t)ST*496*4);              // ST*16
  // u16 regions
  u16* B2b  = (u16*)(wsb + (size_t)ST*512*4);                 // ST*192
  u16* LNCb = B2b  + (size_t)ST*192;                          // ST*96
  u16* R4b  = LNCb + (size_t)ST*96;                           // ST*96
  u16* R6b  = R4b  + (size_t)ST*96;                           // ST*96
  u16* Wbf  = R6b  + (size_t)ST*96;                           // 168960
  u16* Apre = Wbf + 168960;                                   // 491520
  // overlays on U0f (ST*288 f32 = ST*576 u16)
  u16* X12b = (u16*)U0f;                     // ST*384 u16 (c12 out, stride 384)
  u16* DWb  = (u16*)U0f + (size_t)ST*384;    // ST*192 u16 (dw1 out)
  u16* QKVb = (u16*)U0f;                     // ST*288 u16 (after conv branch dead)
  u16* FF1b = (u16*)U0f;                     // ST*192 u16 (after QKV dead)
  u16* DWOb = (u16*)U0f + (size_t)ST*192;

  const u16* W_qkv  = Wbf + 0;
  const u16* W_c12  = Wbf + 27648;
  const u16* W_c3   = Wbf + 64512;
  const u16* W_proj = Wbf + 82944;
  const u16* W_ffn1 = Wbf + 92160;
  const u16* W_ffn2 = Wbf + 110592;
  const u16* W_fin  = Wbf + 129024;
  const u16* W_p1   = Wbf + 165888;

  // weight preps
  wprep_k<<<dim3(144, 9), 256, 0, stream>>>(qkv_w, cb_c1_pw, cb_c2_pw, cb_c3_w,
                                            proj_w, ffn_w1, ffn_w2, out_w, ada_p1_w, Wbf);
  ada_prep_k<<<dim3(120, 16), 256, 0, stream>>>(ada_w, Apre);

  // fused dual LN from NCHW x (replaces transpose + 2 ln launches)
  ln12_k<<<ST/32, 256, 0, stream>>>(x, cb_ln_g, cb_ln_b, ln1_g, ln1_b, LNCb, R6b, XC, XT);

  // conv branch
  conv_mfma_k<0,false,false,false,false,true><<<dim3(ST/128, 6), 256, 0, stream>>>(LNCb, nullptr, 96, W_c12, nullptr, nullptr, 0, X12b, 384, 96, 384);
  dw3x3_k<false,false><<<(ST*48)/256, 256, 0, stream>>>(X12b, 384, cb_c1_dw, nullptr, DWb, 192);
  conv_mfma_k<1,false,false,true,false,false><<<dim3(ST/128, 1), 256, 0, stream>>>(X12b+192, nullptr, 384, W_p1, ada_p1_b, nullptr, 0, PA1, 16, 192, 16);
  p2conv_k<<<(ST*4)/256, 256, 0, stream>>>(PA1, ada_p2_w, ada_p2_b, PA2);
  adaconv_mfma_k<<<dim3(72, 16, NB), 256, 0, stream>>>(X12b+192, PA2, Apre, DWb, B2b);
  conv_mfma_k<0,false,false,false,true,true><<<dim3(ST/128, 2), 256, 0, stream>>>(B2b, nullptr, 192, W_c3, nullptr, XC, 96, R4b, 96, 192, 96);

  // transformer branch
  conv_mfma_k<0,false,false,true,false,true><<<dim3(ST/128, 5), 256, 0, stream>>>(R6b, nullptr, 96, W_qkv, qkv_b, nullptr, 0, QKVb, 288, 96, 288);
  attn_k<<<dim3(144, 3, NB), 64, 0, stream>>>(QKVb, rel_pos, R6b);
  conv_mfma_k<0,false,false,true,true,false><<<dim3(ST/128, 2), 256, 0, stream>>>(R6b, nullptr, 96, W_proj, proj_b, XT, 96, XT, 96, 96, 96);
  ln_k<<<ST/4, 256, 0, stream>>>(XT, 96, ln2_g, ln2_b, R6b);
  conv_mfma_k<0,false,false,true,false,true><<<dim3(ST/128, 3), 256, 0, stream>>>(R6b, nullptr, 96, W_ffn1, ffn_b1, nullptr, 0, FF1b, 192, 96, 192);
  dw3x3_k<true,true><<<(ST*48)/256, 256, 0, stream>>>(FF1b, 192, ffn_dw, ffn_db, DWOb, 192);
  conv_mfma_k<0,false,false,true,true,false><<<dim3(ST/128, 2), 256, 0, stream>>>(DWOb, nullptr, 192, W_ffn2, ffn_b2, XT, 96, XT, 96, 192, 96);

  // fuse: out = x + conv1x1(concat(convout bf16, xt f32), out_w) + out_b  (channel-first)
  conv_mfma_k<0,true,true,true,true,false><<<dim3(ST/128, 3), 256, 0, stream>>>(R4b, XT, 96, W_fin, out_b, x, 0, (float*)d_out, 0, 192, 192);
}